// Round 7
// baseline (14777.194 us; speedup 1.0000x reference)
//
#include <hip/hip_runtime.h>
#include <math.h>

// Problem sizes (fixed)
#define VSZ 32000
#define Hh  768
#define Cc  256
#define HCd 1024
#define G4  4096
#define NSE 2046   // encoder steps
#define NSD 2047   // decoder steps

// Scan: 64 blocks x 512 threads (8 waves) = 512 waves, 2 outputs/wave.
#define EB 64
#define ET 512

// Fused decoder: blocks 0..63 scan, 64..255 logits-GEMM+CE helpers.
#define FGRID 256
#define NHELP 192
#define NRC 32      // row chunks of 64 rows
#define NCS 10      // col splits
#define CSW 3200    // cols per split (10*3200=32000)

typedef __attribute__((ext_vector_type(4))) unsigned uint4v;
typedef __attribute__((ext_vector_type(2))) unsigned uint2v;
typedef __attribute__((ext_vector_type(8))) short bf16x8;
typedef __attribute__((ext_vector_type(4))) float f32x4;

__device__ __forceinline__ float sigmoidf_(float x){ return 1.0f/(1.0f+expf(-x)); }

__device__ __forceinline__ float wave_reduce(float v){
#pragma unroll
  for(int o=32;o;o>>=1) v += __shfl_xor(v,o,64);
  return v;
}
__device__ __forceinline__ unsigned wave_min_u(unsigned v){
#pragma unroll
  for(int o=32;o;o>>=1){ unsigned x=__shfl_xor(v,o,64); v=(x<v)?x:v; }
  return v;
}
// Reduce 64 lanes; total valid in lane 0.
__device__ __forceinline__ float redl0(float v){
  int x;
  x=__builtin_amdgcn_update_dpp(0,__float_as_int(v),0xB1,0xf,0xf,true); v+=__int_as_float(x); // ^1
  x=__builtin_amdgcn_update_dpp(0,__float_as_int(v),0x4E,0xf,0xf,true); v+=__int_as_float(x); // ^2
  v+=__int_as_float(__builtin_amdgcn_ds_swizzle(__float_as_int(v),0x101F)); // ^4
  v+=__int_as_float(__builtin_amdgcn_ds_swizzle(__float_as_int(v),0x201F)); // ^8
  v+=__int_as_float(__builtin_amdgcn_ds_swizzle(__float_as_int(v),0x401F)); // ^16
  v+=__int_as_float(__builtin_amdgcn_readlane(__float_as_int(v),32));
  return v;
}

// Device-scope (coherence-point) ops. Per-dword LSB parity self-validates.
__device__ __forceinline__ unsigned ld_uc1(const unsigned* p){
  unsigned r;
  asm volatile("global_load_dword %0, %1, off sc0 sc1\n\ts_waitcnt vmcnt(0)"
               : "=v"(r) : "v"(p) : "memory");
  return r;
}
__device__ __forceinline__ uint2v ld_uc2(const unsigned* p){
  uint2v r;
  asm volatile("global_load_dwordx2 %0, %1, off sc0 sc1\n\ts_waitcnt vmcnt(0)"
               : "=v"(r) : "v"(p) : "memory");
  return r;
}
__device__ __forceinline__ void st_uc1(unsigned* p, unsigned v){
  asm volatile("global_store_dword %0, %1, off sc0 sc1" :: "v"(p), "v"(v) : "memory");
}
__device__ __forceinline__ void st_uc2(unsigned* p, uint2v v){
  asm volatile("global_store_dwordx2 %0, %1, off sc0 sc1" :: "v"(p), "v"(v) : "memory");
}

// fp32->bf16 RNE, pack two per dword
__device__ __forceinline__ unsigned pk_bf16(float a, float b){
  unsigned ua=__float_as_uint(a); ua += 0x7fffu + ((ua>>16)&1u);
  unsigned ub=__float_as_uint(b); ub += 0x7fffu + ((ub>>16)&1u);
  return (ua>>16) | (ub & 0xffff0000u);
}
__device__ __forceinline__ float bf_lo(unsigned u){ return __uint_as_float(u<<16); }
__device__ __forceinline__ float bf_hi(unsigned u){ return __uint_as_float(u&0xffff0000u); }

// init: zero progress; seed enc S0 (bf16-packed, parity0; stale slot parity1);
// seed dec slot0 parity0 (stale for its first expected parity 1).
__global__ void k_init7(unsigned* prog, unsigned* estate, unsigned* dstate,
                        const float* __restrict__ cemb, const int* __restrict__ condp){
  int tid=threadIdx.x;
  int cond=condp[0];
  for(int i=tid;i<4096;i+=256) prog[i]=0u;
  for(int P=tid;P<512;P+=256){
    int j0=2*P, j1=2*P+1;
    float h0=(j0<Hh)?0.f:cemb[cond*Cc+(j0-Hh)];
    float h1=(j1<Hh)?0.f:cemb[cond*Cc+(j1-Hh)];
    estate[P]=pk_bf16(h0,h1)&~1u;   // slot0: S0, parity 0
    estate[512+P]=1u;               // slot1: stale parity 1
  }
  for(int i=tid;i<1024;i+=256) dstate[i]=0u;   // dec slot0 stale (parity 0; first exp=1)
}

// dec_const[r] = dec_W_hh[r,0:768]·fc_h_b + dec_W_hh[r,768:1024]·cd
__global__ __launch_bounds__(256) void k_dconst(const float* __restrict__ Whh,
    const float* __restrict__ fhb, const float* __restrict__ cemb,
    const int* __restrict__ condp, float* __restrict__ cvec){
  int lane=threadIdx.x&63, wv=threadIdx.x>>6;
  int wgid=blockIdx.x*4+wv;
  int cond=condp[0];
  for(int r=wgid;r<G4;r+=256){
    const float* row=Whh+(size_t)r*HCd;
    float s=0.f;
    for(int k=lane;k<Hh;k+=64) s+=row[k]*fhb[k];
    for(int k=lane;k<Cc;k+=64) s+=row[Hh+k]*cemb[cond*Cc+k];
    s=wave_reduce(s);
    if(lane==0) cvec[r]=s;
  }
}

#define GBM 128
#define GBN 128
#define GBK 16

// Weff[r,k] = sum_{i<768} dec_W_hh[r,i]*fc_h_w[i,k]
__global__ __launch_bounds__(256) void k_weff(const float* __restrict__ A,
    const float* __restrict__ B, float* __restrict__ Cm){
  __shared__ float As[GBK][GBM];
  __shared__ float Bs[GBK][GBN];
  int tid=threadIdx.x;
  int m0=blockIdx.x*GBM, n0=blockIdx.y*GBN;
  int tm=tid>>4, tn=tid&15;
  float acc[8][8]={};
  for(int k0=0;k0<Hh;k0+=GBK){
#pragma unroll
    for(int u=0;u<2;u++){
      int idx=tid*2+u;
      int row=idx>>2, q=idx&3;
      float4 v=*(const float4*)(A+(size_t)(m0+row)*HCd + k0+q*4);
      As[q*4+0][row]=v.x; As[q*4+1][row]=v.y; As[q*4+2][row]=v.z; As[q*4+3][row]=v.w;
      int kk=idx>>5, nc=idx&31;
      float4 w=*(const float4*)(B+(size_t)(k0+kk)*HCd + n0+nc*4);
      *(float4*)&Bs[kk][nc*4]=w;
    }
    __syncthreads();
#pragma unroll
    for(int kk=0;kk<GBK;kk++){
      float a[8],b[8];
      *(float4*)&a[0]=*(float4*)&As[kk][tm*8]; *(float4*)&a[4]=*(float4*)&As[kk][tm*8+4];
      *(float4*)&b[0]=*(float4*)&Bs[kk][tn*8]; *(float4*)&b[4]=*(float4*)&Bs[kk][tn*8+4];
#pragma unroll
      for(int i=0;i<8;i++)
#pragma unroll
        for(int j=0;j<8;j++) acc[i][j]+=a[i]*b[j];
    }
    __syncthreads();
  }
#pragma unroll
  for(int i=0;i<8;i++)
#pragma unroll
    for(int j=0;j<8;j++)
      Cm[(size_t)(m0+tm*8+i)*HCd + n0+tn*8+j]=acc[i][j];
}

// Encoder X (fp32 — kl precision headroom is thin)
__global__ __launch_bounds__(256) void k_xgemm(
    const float* __restrict__ emb, const float* __restrict__ Wih,
    const float* __restrict__ b1, const float* __restrict__ b2,
    const int* __restrict__ tok, int tshift, int M,
    float* __restrict__ X)
{
  __shared__ float As[GBK][GBM];
  __shared__ float Bs[GBK][GBN];
  int tid=threadIdx.x;
  int m0=blockIdx.x*GBM, n0=blockIdx.y*GBN;
  int tm=tid>>4, tn=tid&15;
  int arow=m0+(tid>>1);
  int atok=(arow<M)?tok[arow+tshift]:0;
  const float* abase=emb+(size_t)atok*HCd+(tid&1)*8;
  const float* bbase=Wih+(size_t)(n0+(tid>>1))*HCd+(tid&1)*8;
  int srow=tid>>1;
  float acc[8][8]={};
  for(int k0=0;k0<HCd;k0+=GBK){
#pragma unroll
    for(int u=0;u<2;u++){
      int q=2*(tid&1)+u;
      float4 v={0,0,0,0};
      if(arow<M) v=*(const float4*)(abase+k0+u*4);
      As[q*4+0][srow]=v.x; As[q*4+1][srow]=v.y; As[q*4+2][srow]=v.z; As[q*4+3][srow]=v.w;
      float4 w=*(const float4*)(bbase+k0+u*4);
      Bs[q*4+0][srow]=w.x; Bs[q*4+1][srow]=w.y; Bs[q*4+2][srow]=w.z; Bs[q*4+3][srow]=w.w;
    }
    __syncthreads();
#pragma unroll
    for(int kk=0;kk<GBK;kk++){
      float a[8],b[8];
      *(float4*)&a[0]=*(float4*)&As[kk][tm*8]; *(float4*)&a[4]=*(float4*)&As[kk][tm*8+4];
      *(float4*)&b[0]=*(float4*)&Bs[kk][tn*8]; *(float4*)&b[4]=*(float4*)&Bs[kk][tn*8+4];
#pragma unroll
      for(int i=0;i<8;i++)
#pragma unroll
        for(int j=0;j<8;j++) acc[i][j]+=a[i]*b[j];
    }
    __syncthreads();
  }
#pragma unroll
  for(int i=0;i<8;i++){
    int m=m0+tm*8+i; if(m>=M) continue;
#pragma unroll
    for(int j=0;j<8;j++){
      int n=n0+tn*8+j;
      X[(size_t)m*G4+n]=acc[i][j]+b1[n]+b2[n];
    }
  }
}

#define TBM 128
#define TBN 128
#define TBK 32

// Decoder X via bf16 MFMA
__global__ __launch_bounds__(256) void k_xgemm_mfma(
    const float* __restrict__ emb, const float* __restrict__ Wih,
    const float* __restrict__ b1, const float* __restrict__ b2,
    const int* __restrict__ tok, int M, float* __restrict__ X)
{
  __shared__ ushort As[TBM*TBK];
  __shared__ ushort Bs[TBN*TBK];
  int tid=threadIdx.x;
  int m0=blockIdx.x*TBM, n0=blockIdx.y*TBN;
  int wid=tid>>6, lane=tid&63;
  int wm=wid>>1, wn=wid&1;
  int r15=lane&15, g=lane>>4;
  f32x4 acc[4][4]={};
  int srow=tid>>1, shalf=tid&1;
  int arow=m0+srow;
  int atok=(arow<M)?tok[arow]:0;
  const float* aptr=emb+(size_t)atok*HCd + shalf*16;
  const float* bptr=Wih+(size_t)(n0+srow)*HCd + shalf*16;
  bool aok=arow<M;
  float bj[4];
#pragma unroll
  for(int j=0;j<4;j++){ int n=n0+wn*64+j*16+r15; bj[j]=b1[n]+b2[n]; }

  for(int k0=0;k0<HCd;k0+=TBK){
    float4 va0={0,0,0,0},va1={0,0,0,0},va2={0,0,0,0},va3={0,0,0,0};
    if(aok){
      va0=*(const float4*)(aptr+k0);   va1=*(const float4*)(aptr+k0+4);
      va2=*(const float4*)(aptr+k0+8); va3=*(const float4*)(aptr+k0+12);
    }
    float4 vb0=*(const float4*)(bptr+k0),   vb1=*(const float4*)(bptr+k0+4);
    float4 vb2=*(const float4*)(bptr+k0+8), vb3=*(const float4*)(bptr+k0+12);
    uint4v pa0={pk_bf16(va0.x,va0.y),pk_bf16(va0.z,va0.w),pk_bf16(va1.x,va1.y),pk_bf16(va1.z,va1.w)};
    uint4v pa1={pk_bf16(va2.x,va2.y),pk_bf16(va2.z,va2.w),pk_bf16(va3.x,va3.y),pk_bf16(va3.z,va3.w)};
    uint4v pb0={pk_bf16(vb0.x,vb0.y),pk_bf16(vb0.z,vb0.w),pk_bf16(vb1.x,vb1.y),pk_bf16(vb1.z,vb1.w)};
    uint4v pb1={pk_bf16(vb2.x,vb2.y),pk_bf16(vb2.z,vb2.w),pk_bf16(vb3.x,vb3.y),pk_bf16(vb3.z,vb3.w)};
    int sx=(srow>>1)&3;
    int u0=(shalf*2+0)^sx, u1=(shalf*2+1)^sx;
    *(uint4v*)&As[srow*32+u0*8]=pa0; *(uint4v*)&As[srow*32+u1*8]=pa1;
    *(uint4v*)&Bs[srow*32+u0*8]=pb0; *(uint4v*)&Bs[srow*32+u1*8]=pb1;
    __syncthreads();
    bf16x8 af[4], bf[4];
#pragma unroll
    for(int i=0;i<4;i++){
      int ra=wm*64+i*16+r15;
      af[i]=*(const bf16x8*)&As[ra*32+((g^((ra>>1)&3))<<3)];
      int rb=wn*64+i*16+r15;
      bf[i]=*(const bf16x8*)&Bs[rb*32+((g^((rb>>1)&3))<<3)];
    }
#pragma unroll
    for(int i=0;i<4;i++)
#pragma unroll
      for(int j=0;j<4;j++)
        acc[i][j]=__builtin_amdgcn_mfma_f32_16x16x32_bf16(af[i],bf[j],acc[i][j],0,0,0);
    __syncthreads();
  }
#pragma unroll
  for(int i=0;i<4;i++){
    int grow0=m0+wm*64+i*16+g*4;
#pragma unroll
    for(int j=0;j<4;j++){
      int gcol=n0+wn*64+j*16+r15;
#pragma unroll
      for(int r=0;r<4;r++){
        int grow=grow0+r;
        if(grow<M) X[(size_t)grow*G4+gcol]=acc[i][j][r]+bj[j];
      }
    }
  }
}

// ---------------- Encoder scan (bf16-packed seqlock, 1 dword poll/step) ----------------
__global__ __launch_bounds__(ET,2) void k_enc7(
    const float* __restrict__ Xg, const float* __restrict__ Whh,
    unsigned* estate,                 // [2][512] dwords: pk(h_2P,h_2P+1), LSB parity
    float* hT, float* cT)
{
  __shared__ float hlds[2][HCd];
  const int tid=threadIdx.x, lane=tid&63, wv=tid>>6;
  const int wid=blockIdx.x*8+wv;
  const int j0=wid*2, j1=j0+1;
  float w[8][16];
#pragma unroll
  for(int q=0;q<4;q++)
#pragma unroll
    for(int jj=0;jj<2;jj++){
      const float* p=Whh+(size_t)(q*HCd+j0+jj)*HCd+lane;
#pragma unroll
      for(int e=0;e<16;e++) w[q*2+jj][e]=p[(size_t)e*64];
    }
  float xg[8];
#pragma unroll
  for(int r=0;r<8;r++) xg[r]=Xg[(r>>1)*HCd+j0+(r&1)];
  float c0=0.f,c1=0.f;
  const int i0=tid*2, i1=i0+1;

  for(int s=1;s<=NSE;s++){
    unsigned u;
    unsigned* src=estate+((s-1)&1)*512;
    if(s==1) u=src[tid];
    else{
      const unsigned expp=(unsigned)(((s-1)>>1)&1);
      for(;;){
        u=ld_uc1(src+tid);
        if(((u^expp)&1u)==0u) break;
        __builtin_amdgcn_s_sleep(1);
      }
    }
    float* hl=hlds[(s-1)&1];
    hl[i0]=bf_lo(u); hl[i1]=bf_hi(u);
    __syncthreads();
    if(s==1){ c0=hl[j0]; c1=hl[j1]; }   // h0 == c0
    float hseg[16];
#pragma unroll
    for(int e=0;e<16;e++) hseg[e]=hl[lane+64*e];
    float d[8];
#pragma unroll
    for(int r=0;r<8;r++){ float sacc=0.f;
#pragma unroll
      for(int e=0;e<16;e++) sacc+=w[r][e]*hseg[e];
      d[r]=sacc; }
#pragma unroll
    for(int r=0;r<8;r++) d[r]=redl0(d[r]);
    float gi0=d[0]+xg[0], gi1=d[1]+xg[1];
    float gf0=d[2]+xg[2], gf1=d[3]+xg[3];
    float gg0=d[4]+xg[4], gg1=d[5]+xg[5];
    float go0=d[6]+xg[6], go1=d[7]+xg[7];
    if(s<NSE){
      const float* px=Xg+(size_t)s*G4;
#pragma unroll
      for(int r=0;r<8;r++) xg[r]=px[(r>>1)*HCd+j0+(r&1)];
    }
    c0=sigmoidf_(gf0)*c0+sigmoidf_(gi0)*tanhf(gg0);
    float h0=sigmoidf_(go0)*tanhf(c0);
    c1=sigmoidf_(gf1)*c1+sigmoidf_(gi1)*tanhf(gg1);
    float h1=sigmoidf_(go1)*tanhf(c1);
    if(lane==0){
      unsigned wpar=(unsigned)((s>>1)&1);
      st_uc1(estate+(s&1)*512+wid,(pk_bf16(h0,h1)&~1u)|wpar);
      if(s==NSE){ hT[j0]=h0; hT[j1]=h1; cT[j0]=c0; cT[j1]=c1; }
    }
  }
}

// ---------------- VAE heads (plain fp32 z vectors) ----------------
__global__ __launch_bounds__(256) void k_head(
    const float* __restrict__ hT, const float* __restrict__ cT,
    const float* __restrict__ mhw, const float* __restrict__ mhb,
    const float* __restrict__ lhw, const float* __restrict__ lhb,
    const float* __restrict__ mcw, const float* __restrict__ mcb,
    const float* __restrict__ lcw, const float* __restrict__ lcb,
    const float* __restrict__ eps_h, const float* __restrict__ eps_c,
    const float* __restrict__ cemb, const int* __restrict__ condp,
    float* zh, float* zc, float* klh, float* klc)
{
  int i=blockIdx.x;
  int tid=threadIdx.x, lane=tid&63, wv=tid>>6;
  __shared__ float sm[4];
  const float* Wm=(wv==0)?mhw:(wv==1)?lhw:(wv==2)?mcw:lcw;
  const float* vec=(wv<2)?hT:cT;
  const float* row=Wm+(size_t)i*HCd;
  float s=0.f;
  for(int k=lane;k<HCd;k+=64) s+=row[k]*vec[k];
  s=wave_reduce(s);
  if(lane==0) sm[wv]=s;
  __syncthreads();
  if(tid==0){
    float mh=sm[0]+mhb[i], lh=sm[1]+lhb[i];
    float mc=sm[2]+mcb[i], lc=sm[3]+lcb[i];
    zh[i]=eps_h[i]*expf(lh*0.5f)+mh;
    zc[i]=eps_c[i]*expf(lc*0.5f)+mc;
    klh[i]=0.5f*(mh*mh+expf(lh)-1.f-lh);
    klc[i]=0.5f*(mc*mc+expf(lc)-1.f-lc);
    if(i<Cc){
      float cd=cemb[condp[0]*Cc+i];
      zh[Hh+i]=cd; zc[Hh+i]=cd;
    }
  }
}

// decoder step 1: writes packed S1 (parity 0) + Hmat row 0
__global__ __launch_bounds__(256) void k_dec0(
    const float* __restrict__ Xg, const float* __restrict__ WhhO,
    const float* __restrict__ zh, const float* __restrict__ zc,
    unsigned* dstate, float* Hmat)
{
  int tid=threadIdx.x, lane=tid&63, wv=tid>>6;
  int j=blockIdx.x*4+wv;
  __shared__ float hcs[4][2];
  float hseg[16];
#pragma unroll
  for(int e=0;e<16;e++) hseg[e]=zh[lane+64*e];
  float g[4];
#pragma unroll
  for(int q=0;q<4;q++){
    const float* p=WhhO+(size_t)(q*HCd+j)*HCd+lane;
    float s=0.f;
#pragma unroll
    for(int e=0;e<16;e++) s+=p[(size_t)e*64]*hseg[e];
    s=wave_reduce(s);
    g[q]=s+Xg[q*HCd+j];
  }
  float cc=zc[j];
  float cn=sigmoidf_(g[1])*cc+sigmoidf_(g[0])*tanhf(g[2]);
  float hn=sigmoidf_(g[3])*tanhf(cn);
  if(lane==0){ hcs[wv][0]=hn; hcs[wv][1]=cn; Hmat[j]=hn; }
  __syncthreads();
  if(tid<2){
    int P=blockIdx.x*2+tid;
    unsigned dwh=pk_bf16(hcs[2*tid][0],hcs[2*tid+1][0])&~1u;
    unsigned dwc=pk_bf16(hcs[2*tid][1],hcs[2*tid+1][1])&~1u;
    dstate[1024+2*P]=dwh; dstate[1024+2*P+1]=dwc;   // slot 1
  }
}

// ---------------- Fused decoder scan + streaming logits/CE helpers ----------------
struct SmemT {
  union {
    struct { float hl[2][HCd]; float cl[2][HCd]; } scan;
    struct { ushort A[64*1024]; int tgt[64]; float wm[8][64]; float wl[8][64]; } help;
  } u;
};

__global__ __launch_bounds__(ET) void k_dec_fused(
    const float* __restrict__ Xg, const float* __restrict__ Weff,
    const float* __restrict__ cvec,
    const float* __restrict__ fccw, const float* __restrict__ fccb,
    const float* __restrict__ cemb, const int* __restrict__ condp,
    unsigned* dstate, float* __restrict__ Hmat, unsigned* prog,
    const float* __restrict__ outw, const float* __restrict__ outb,
    const int* __restrict__ tok,
    float* __restrict__ pm, float* __restrict__ pl, float* __restrict__ tgtlog)
{
  __shared__ SmemT smem;
  const int tid=threadIdx.x, lane=tid&63, wv=tid>>6;
  const int bid=blockIdx.x;

  if(bid<EB){
    // ================= scan =================
    const int wid=bid*8+wv;
    const int j0=wid*2, j1=j0+1;
    float w[8][16];
#pragma unroll
    for(int q=0;q<4;q++)
#pragma unroll
      for(int jj=0;jj<2;jj++){
        const float* p=Weff+(size_t)(q*HCd+j0+jj)*HCd+lane;
#pragma unroll
        for(int e=0;e<16;e++) w[q*2+jj][e]=p[(size_t)e*64];
      }
    const bool hasf=(j0<Hh);
    float fcc0[16], fcc1[16];
    if(hasf){
      const float* p0=fccw+(size_t)j0*HCd+lane;
      const float* p1=fccw+(size_t)j1*HCd+lane;
#pragma unroll
      for(int e=0;e<16;e++){ fcc0[e]=p0[(size_t)e*64]; fcc1[e]=p1[(size_t)e*64]; }
    } else {
#pragma unroll
      for(int e=0;e<16;e++){ fcc0[e]=0.f; fcc1[e]=0.f; }
    }
    float fb0=hasf?fccb[j0]:0.f, fb1=hasf?fccb[j1]:0.f;
    int cond=condp[0];
    float cd0=hasf?0.f:cemb[cond*Cc+(j0-Hh)];
    float cd1=hasf?0.f:cemb[cond*Cc+(j1-Hh)];
    float cv[8];
#pragma unroll
    for(int r=0;r<8;r++) cv[r]=cvec[(r>>1)*HCd+j0+(r&1)];
    float xg[8];
    { const float* px=Xg+(size_t)1*G4;
#pragma unroll
      for(int r=0;r<8;r++) xg[r]=px[(r>>1)*HCd+j0+(r&1)]; }
    const int i0=tid*2, i1=i0+1;

    for(int s=2;s<=NSD;s++){
      uint2v v;
      unsigned* sp=dstate+((s-1)&1)*1024;
      if(s==2){ v.x=sp[2*tid]; v.y=sp[2*tid+1]; }
      else{
        const unsigned expp=(unsigned)(((s-1)>>1)&1);
        for(;;){
          v=ld_uc2(sp+2*tid);
          if((((v.x^expp)|(v.y^expp))&1u)==0u) break;
          __builtin_amdgcn_s_sleep(1);
        }
      }
      float* hl=smem.u.scan.hl[(s-1)&1]; float* cl=smem.u.scan.cl[(s-1)&1];
      hl[i0]=bf_lo(v.x); hl[i1]=bf_hi(v.x);
      cl[i0]=bf_lo(v.y); cl[i1]=bf_hi(v.y);
      __syncthreads();
      // rows <= s-2 globally visible (every wave's step-(s-1) stores drained by its poll)
      if(tid==0) st_uc1(prog+bid*64,(unsigned)(s-2));
      float hseg[16], cseg[16];
#pragma unroll
      for(int e=0;e<16;e++){ hseg[e]=hl[lane+64*e]; cseg[e]=cl[lane+64*e]; }
      float d[8]; float s8=0.f, s9=0.f;
#pragma unroll
      for(int r=0;r<8;r++){ float sacc=0.f;
#pragma unroll
        for(int e=0;e<16;e++) sacc+=w[r][e]*hseg[e];
        d[r]=sacc; }
#pragma unroll
      for(int r=0;r<8;r++) d[r]=redl0(d[r]);
      if(hasf){
#pragma unroll
        for(int e=0;e<16;e++){ s8+=fcc0[e]*cseg[e]; s9+=fcc1[e]*cseg[e]; }
        s8=redl0(s8); s9=redl0(s9);
      }
      float gi0=d[0]+xg[0]+cv[0], gi1=d[1]+xg[1]+cv[1];
      float gf0=d[2]+xg[2]+cv[2], gf1=d[3]+xg[3]+cv[3];
      float gg0=d[4]+xg[4]+cv[4], gg1=d[5]+xg[5]+cv[5];
      float go0=d[6]+xg[6]+cv[6], go1=d[7]+xg[7]+cv[7];
      if(s<NSD){
        const float* px=Xg+(size_t)s*G4;
#pragma unroll
        for(int r=0;r<8;r++) xg[r]=px[(r>>1)*HCd+j0+(r&1)];
      }
      float cc0=hasf?(s8+fb0):cd0;
      float cc1=hasf?(s9+fb1):cd1;
      float cn0=sigmoidf_(gf0)*cc0+sigmoidf_(gi0)*tanhf(gg0);
      float hn0=sigmoidf_(go0)*tanhf(cn0);
      float cn1=sigmoidf_(gf1)*cc1+sigmoidf_(gi1)*tanhf(gg1);
      float hn1=sigmoidf_(go1)*tanhf(cn1);
      if(lane==0){
        unsigned wpar=(unsigned)((s>>1)&1);
        uint2v pk;
        pk.x=(pk_bf16(hn0,hn1)&~1u)|wpar;
        pk.y=(pk_bf16(cn0,cn1)&~1u)|wpar;
        st_uc2(dstate+(s&1)*1024+2*wid,pk);
        uint2v hm; hm.x=__float_as_uint(hn0); hm.y=__float_as_uint(hn1);
        st_uc2((unsigned*)(Hmat+(size_t)(s-1)*HCd+j0),hm);
      }
    }
    asm volatile("s_waitcnt vmcnt(0)");
    __syncthreads();
    if(tid==0) st_uc1(prog+bid*64,(unsigned)(NSD-1));   // all rows visible
    return;
  }

  // ================= helper: streaming logits GEMM + online softmax =================
  const int hb=bid-EB;
  const int g=lane>>4, r15=lane&15;
  for(int un=hb; un<NRC*NCS; un+=NHELP){
    int rC=un/NCS, cS=un%NCS;
    int rbase=rC*64;
    unsigned need=(unsigned)((rbase+63<NSD-1)?(rbase+63):(NSD-1));
    if(wv==0){
      for(;;){
        unsigned pv=ld_uc1(prog+lane*64);   // 64 scan blocks
        unsigned mn=wave_min_u(pv);
        if(mn>=need) break;
        __builtin_amdgcn_s_sleep(32);
      }
    }
    __syncthreads();
    // stage A: 64 rows x 1024 bf16, XOR-swizzled (byte ^= (row&7)<<4)
    for(int idx=tid; idx<64*128; idx+=ET){
      int row=idx>>7, ch=idx&127;
      int grow=rbase+row;
      float4 v0={0,0,0,0}, v1={0,0,0,0};
      if(grow<NSD){
        const float* hp=Hmat+(size_t)grow*HCd+ch*8;
        v0=*(const float4*)hp; v1=*(const float4*)(hp+4);
      }
      uint4v pk4={pk_bf16(v0.x,v0.y),pk_bf16(v0.z,v0.w),pk_bf16(v1.x,v1.y),pk_bf16(v1.z,v1.w)};
      int off=row*2048 + ((ch*16)^((row&7)<<4));
      *(uint4v*)((char*)smem.u.help.A+off)=pk4;
    }
    if(tid<64){
      int grow=rbase+tid;
      smem.u.help.tgt[tid]=(grow<NSD)?tok[grow+1]:-1;
    }
    __syncthreads();
    float m[16], l[16];
#pragma unroll
    for(int i=0;i<16;i++){ m[i]=-3e38f; l[i]=0.f; }
    for(int p=0;p<CSW/128;p++){
      int n0p=cS*CSW + p*128 + wv*16;
      int n=n0p+r15;
      float bcol=outb[n];
      f32x4 acc[4]={};
      for(int k0=0;k0<HCd;k0+=32){
        int kk=k0+g*8;
        const float* bp=outw+(size_t)n*HCd+kk;
        float4 b0=*(const float4*)bp, b1=*(const float4*)(bp+4);
        uint4v pb={pk_bf16(b0.x,b0.y),pk_bf16(b0.z,b0.w),pk_bf16(b1.x,b1.y),pk_bf16(b1.z,b1.w)};
        bf16x8 bf=*(bf16x8*)&pb;
#pragma unroll
        for(int fr=0;fr<4;fr++){
          int row=fr*16+r15;
          int off=row*2048 + ((kk*2)^((row&7)<<4));
          bf16x8 af=*(const bf16x8*)((const char*)smem.u.help.A+off);
          acc[fr]=__builtin_amdgcn_mfma_f32_16x16x32_bf16(af,bf,acc[fr],0,0,0);
        }
      }
#pragma unroll
      for(int fr=0;fr<4;fr++)
#pragma unroll
      for(int rg=0;rg<4;rg++){
        int i=fr*4+rg;
        int rowloc=fr*16+g*4+rg;
        float v=acc[fr][rg]+bcol;
        float mx=v;
        mx=fmaxf(mx,__shfl_xor(mx,1,64));
        mx=fmaxf(mx,__shfl_xor(mx,2,64));
        mx=fmaxf(mx,__shfl_xor(mx,4,64));
        mx=fmaxf(mx,__shfl_xor(mx,8,64));
        float mn_=fmaxf(m[i],mx);
        float e=__expf(v-mn_);
        float se=e;
        se+=__shfl_xor(se,1,64); se+=__shfl_xor(se,2,64);
        se+=__shfl_xor(se,4,64); se+=__shfl_xor(se,8,64);
        l[i]=l[i]*__expf(m[i]-mn_)+se;
        m[i]=mn_;
        if(n==smem.u.help.tgt[rowloc]) tgtlog[rbase+rowloc]=v;
      }
    }
    // merge the 8 waves' disjoint-column partials
    if(r15==0){
#pragma unroll
      for(int fr=0;fr<4;fr++)
#pragma unroll
      for(int rg=0;rg<4;rg++){
        int rowloc=fr*16+g*4+rg;
        smem.u.help.wm[wv][rowloc]=m[fr*4+rg];
        smem.u.help.wl[wv][rowloc]=l[fr*4+rg];
      }
    }
    __syncthreads();
    if(tid<64){
      float M=-3e38f,L=0.f;
#pragma unroll
      for(int w2=0;w2<8;w2++) M=fmaxf(M,smem.u.help.wm[w2][tid]);
#pragma unroll
      for(int w2=0;w2<8;w2++) L+=smem.u.help.wl[w2][tid]*__expf(smem.u.help.wm[w2][tid]-M);
      pm[(size_t)un*64+tid]=M;
      pl[(size_t)un*64+tid]=L;
    }
    __syncthreads();
  }
}

// merge col-split partials -> ce[row]
__global__ __launch_bounds__(256) void k_cemerge(const float* __restrict__ pm,
    const float* __restrict__ pl, const float* __restrict__ tgtlog,
    float* __restrict__ ce)
{
  int grow=blockIdx.x*256+threadIdx.x;
  if(grow>=NSD) return;
  int rC=grow>>6, row=grow&63;
  float M=-3e38f;
#pragma unroll
  for(int c=0;c<NCS;c++) M=fmaxf(M,pm[(size_t)(rC*NCS+c)*64+row]);
  float L=0.f;
#pragma unroll
  for(int c=0;c<NCS;c++) L+=pl[(size_t)(rC*NCS+c)*64+row]*__expf(pm[(size_t)(rC*NCS+c)*64+row]-M);
  ce[grow]=M+logf(L)-tgtlog[grow];
}

__global__ __launch_bounds__(256) void k_final(const float* __restrict__ ce,
    const float* __restrict__ klh, const float* __restrict__ klc,
    const float* __restrict__ kldw, float* __restrict__ outp)
{
  int tid=threadIdx.x, lane=tid&63, wv=tid>>6;
  float s0=0,s1=0,s2=0;
  for(int i=tid;i<NSD;i+=256) s0+=ce[i];
  for(int i=tid;i<Hh;i+=256){ s1+=klh[i]; s2+=klc[i]; }
  s0=wave_reduce(s0); s1=wave_reduce(s1); s2=wave_reduce(s2);
  __shared__ float sm[3][4];
  if(lane==0){ sm[0][wv]=s0; sm[1][wv]=s1; sm[2][wv]=s2; }
  __syncthreads();
  if(tid==0){
    float ces=sm[0][0]+sm[0][1]+sm[0][2]+sm[0][3];
    float kh =sm[1][0]+sm[1][1]+sm[1][2]+sm[1][3];
    float kc =sm[2][0]+sm[2][1]+sm[2][2]+sm[2][3];
    float rec=ces/(float)NSD;
    outp[0]=rec+(kh+kc)*kldw[0];
    outp[1]=rec; outp[2]=kh; outp[3]=kc;
  }
}

extern "C" void kernel_launch(void* const* d_in, const int* in_sizes, int n_in,
                              void* d_out, int out_size, void* d_ws, size_t ws_size,
                              hipStream_t stream) {
  const int*   tok   =(const int*)  d_in[0];
  const int*   cond  =(const int*)  d_in[1];
  const float* eps_h =(const float*)d_in[2];
  const float* eps_c =(const float*)d_in[3];
  const float* kldw  =(const float*)d_in[4];
  const float* enc_embed=(const float*)d_in[5];
  const float* enc_cemb =(const float*)d_in[6];
  const float* enc_Wih  =(const float*)d_in[7];
  const float* enc_Whh  =(const float*)d_in[8];
  const float* enc_bih  =(const float*)d_in[9];
  const float* enc_bhh  =(const float*)d_in[10];
  const float* fc_mh_w=(const float*)d_in[11];
  const float* fc_mh_b=(const float*)d_in[12];
  const float* fc_lh_w=(const float*)d_in[13];
  const float* fc_lh_b=(const float*)d_in[14];
  const float* fc_mc_w=(const float*)d_in[15];
  const float* fc_mc_b=(const float*)d_in[16];
  const float* fc_lc_w=(const float*)d_in[17];
  const float* fc_lc_b=(const float*)d_in[18];
  const float* dec_embed=(const float*)d_in[19];
  const float* dec_cemb =(const float*)d_in[20];
  const float* dec_Wih  =(const float*)d_in[21];
  const float* dec_Whh  =(const float*)d_in[22];
  const float* dec_bih  =(const float*)d_in[23];
  const float* dec_bhh  =(const float*)d_in[24];
  const float* fc_h_w=(const float*)d_in[25];
  const float* fc_h_b=(const float*)d_in[26];
  const float* fc_c_w=(const float*)d_in[27];
  const float* fc_c_b=(const float*)d_in[28];
  const float* out_w=(const float*)d_in[29];
  const float* out_b=(const float*)d_in[30];

  float* ws=(float*)d_ws;
  size_t off=0;
  unsigned* prog  =(unsigned*)(ws+off); off+=4096;   // 64 words, 256B apart
  unsigned* estate=(unsigned*)(ws+off); off+=1024;   // 2 x 512 dwords
  unsigned* dstate=(unsigned*)(ws+off); off+=2048;   // 2 x 1024 dwords
  float* cvec=ws+off; off+=G4;
  float* Weff=ws+off; off+=(size_t)G4*HCd;
  float* hT  =ws+off; off+=HCd;
  float* cT  =ws+off; off+=HCd;
  float* zh  =ws+off; off+=HCd;
  float* zc  =ws+off; off+=HCd;
  float* klh =ws+off; off+=Hh;
  float* klc =ws+off; off+=Hh;
  float* Hmat=ws+off; off+=(size_t)NSD*HCd;
  float* ce  =ws+off; off+=2048;
  float* tgtlog=ws+off; off+=2048;
  float* pm  =ws+off; off+=(size_t)NRC*NCS*64;
  float* pl  =ws+off; off+=(size_t)NRC*NCS*64;
  size_t avail=ws_size/4;
  size_t xa_sz=(size_t)NSE*G4, xb_sz=(size_t)NSD*G4;
  float* XA=ws+off;
  bool dual=(off+xa_sz+xb_sz)<=avail;
  float* XB=dual?(XA+xa_sz):XA;

  k_init7<<<1,256,0,stream>>>(prog,estate,dstate,enc_cemb,cond);
  k_dconst<<<64,256,0,stream>>>(dec_Whh,fc_h_b,dec_cemb,cond,cvec);
  { dim3 g(G4/GBM, HCd/GBN);
    k_weff<<<g,256,0,stream>>>(dec_Whh,fc_h_w,Weff); }
  { dim3 g((NSE+GBM-1)/GBM, G4/GBN);           // Xenc (fp32)
    k_xgemm<<<g,256,0,stream>>>(enc_embed,enc_Wih,enc_bih,enc_bhh,tok,1,NSE,XA); }
  if(dual){
    dim3 g((NSD+TBM-1)/TBM, G4/TBN);           // Xdec (bf16 MFMA)
    k_xgemm_mfma<<<g,256,0,stream>>>(dec_embed,dec_Wih,dec_bih,dec_bhh,tok,NSD,XB);
  }
  k_enc7<<<EB,ET,0,stream>>>(XA,enc_Whh,estate,hT,cT);
  k_head<<<Hh,256,0,stream>>>(hT,cT,fc_mh_w,fc_mh_b,fc_lh_w,fc_lh_b,
                              fc_mc_w,fc_mc_b,fc_lc_w,fc_lc_b,
                              eps_h,eps_c,dec_cemb,cond,zh,zc,klh,klc);
  if(!dual){
    dim3 g((NSD+TBM-1)/TBM, G4/TBN);           // Xdec overwrites Xenc (encoder done)
    k_xgemm_mfma<<<g,256,0,stream>>>(dec_embed,dec_Wih,dec_bih,dec_bhh,tok,NSD,XB);
  }
  k_dec0<<<256,256,0,stream>>>(XB,dec_Whh,zh,zc,dstate,Hmat);
  k_dec_fused<<<FGRID,ET,0,stream>>>(XB,Weff,cvec,fc_c_w,fc_c_b,dec_cemb,cond,
                                     dstate,Hmat,prog,out_w,out_b,tok,pm,pl,tgtlog);
  k_cemerge<<<(NSD+255)/256,256,0,stream>>>(pm,pl,tgtlog,ce);
  k_final<<<1,256,0,stream>>>(ce,klh,klc,kldw,(float*)d_out);
}

// Round 8
// 14699.701 us; speedup vs baseline: 1.0053x; 1.0053x over previous
//
#include <hip/hip_runtime.h>
#include <math.h>

// Problem sizes (fixed)
#define VSZ 32000
#define Hh  768
#define Cc  256
#define HCd 1024
#define G4  4096
#define NSE 2046   // encoder steps
#define NSD 2047   // decoder steps

// Scan: 64 blocks x 512 threads (8 waves) = 512 waves, 2 outputs/wave.
#define EB 64
#define ET 512

typedef __attribute__((ext_vector_type(4))) unsigned uint4v;
typedef __attribute__((ext_vector_type(2))) unsigned uint2v;
typedef __attribute__((ext_vector_type(8))) short bf16x8;
typedef __attribute__((ext_vector_type(4))) float f32x4;

__device__ __forceinline__ float sigmoidf_(float x){ return 1.0f/(1.0f+expf(-x)); }

__device__ __forceinline__ float wave_reduce(float v){
#pragma unroll
  for(int o=32;o;o>>=1) v += __shfl_xor(v,o,64);
  return v;
}
// Reduce 64 lanes; total valid in lane 0.
__device__ __forceinline__ float redl0(float v){
  int x;
  x=__builtin_amdgcn_update_dpp(0,__float_as_int(v),0xB1,0xf,0xf,true); v+=__int_as_float(x); // ^1
  x=__builtin_amdgcn_update_dpp(0,__float_as_int(v),0x4E,0xf,0xf,true); v+=__int_as_float(x); // ^2
  v+=__int_as_float(__builtin_amdgcn_ds_swizzle(__float_as_int(v),0x101F)); // ^4
  v+=__int_as_float(__builtin_amdgcn_ds_swizzle(__float_as_int(v),0x201F)); // ^8
  v+=__int_as_float(__builtin_amdgcn_ds_swizzle(__float_as_int(v),0x401F)); // ^16
  v+=__int_as_float(__builtin_amdgcn_readlane(__float_as_int(v),32));
  return v;
}

// Device-scope (coherence-point) ops. Per-dword LSB parity self-validates.
__device__ __forceinline__ unsigned ld_uc1(const unsigned* p){
  unsigned r;
  asm volatile("global_load_dword %0, %1, off sc0 sc1\n\ts_waitcnt vmcnt(0)"
               : "=v"(r) : "v"(p) : "memory");
  return r;
}
__device__ __forceinline__ uint2v ld_uc2(const unsigned* p){
  uint2v r;
  asm volatile("global_load_dwordx2 %0, %1, off sc0 sc1\n\ts_waitcnt vmcnt(0)"
               : "=v"(r) : "v"(p) : "memory");
  return r;
}
__device__ __forceinline__ void st_uc1(unsigned* p, unsigned v){
  asm volatile("global_store_dword %0, %1, off sc0 sc1" :: "v"(p), "v"(v) : "memory");
}
__device__ __forceinline__ void st_uc2(unsigned* p, uint2v v){
  asm volatile("global_store_dwordx2 %0, %1, off sc0 sc1" :: "v"(p), "v"(v) : "memory");
}

// fp32->bf16 RNE, pack two per dword
__device__ __forceinline__ unsigned pk_bf16(float a, float b){
  unsigned ua=__float_as_uint(a); ua += 0x7fffu + ((ua>>16)&1u);
  unsigned ub=__float_as_uint(b); ub += 0x7fffu + ((ub>>16)&1u);
  return (ua>>16) | (ub & 0xffff0000u);
}
__device__ __forceinline__ float bf_lo(unsigned u){ return __uint_as_float(u<<16); }
__device__ __forceinline__ float bf_hi(unsigned u){ return __uint_as_float(u&0xffff0000u); }

// init: seed enc S0 (bf16-packed, parity0; stale slot parity1);
// dec slot0 stale parity0 (its first expected parity is 1).
__global__ void k_init8(unsigned* estate, unsigned* dstate,
                        const float* __restrict__ cemb, const int* __restrict__ condp){
  int tid=threadIdx.x;
  int cond=condp[0];
  for(int P=tid;P<512;P+=256){
    int j0=2*P, j1=2*P+1;
    float h0=(j0<Hh)?0.f:cemb[cond*Cc+(j0-Hh)];
    float h1=(j1<Hh)?0.f:cemb[cond*Cc+(j1-Hh)];
    estate[P]=pk_bf16(h0,h1)&~1u;   // slot0: S0, parity 0
    estate[512+P]=1u;               // slot1: stale parity 1
  }
  for(int i=tid;i<1024;i+=256) dstate[i]=0u;
}

// dec_const[r] = dec_W_hh[r,0:768]·fc_h_b + dec_W_hh[r,768:1024]·cd
__global__ __launch_bounds__(256) void k_dconst(const float* __restrict__ Whh,
    const float* __restrict__ fhb, const float* __restrict__ cemb,
    const int* __restrict__ condp, float* __restrict__ cvec){
  int lane=threadIdx.x&63, wv=threadIdx.x>>6;
  int wgid=blockIdx.x*4+wv;
  int cond=condp[0];
  for(int r=wgid;r<G4;r+=256){
    const float* row=Whh+(size_t)r*HCd;
    float s=0.f;
    for(int k=lane;k<Hh;k+=64) s+=row[k]*fhb[k];
    for(int k=lane;k<Cc;k+=64) s+=row[Hh+k]*cemb[cond*Cc+k];
    s=wave_reduce(s);
    if(lane==0) cvec[r]=s;
  }
}

#define GBM 128
#define GBN 128
#define GBK 16

// Weff[r,k] = sum_{i<768} dec_W_hh[r,i]*fc_h_w[i,k]
__global__ __launch_bounds__(256) void k_weff(const float* __restrict__ A,
    const float* __restrict__ B, float* __restrict__ Cm){
  __shared__ float As[GBK][GBM];
  __shared__ float Bs[GBK][GBN];
  int tid=threadIdx.x;
  int m0=blockIdx.x*GBM, n0=blockIdx.y*GBN;
  int tm=tid>>4, tn=tid&15;
  float acc[8][8]={};
  for(int k0=0;k0<Hh;k0+=GBK){
#pragma unroll
    for(int u=0;u<2;u++){
      int idx=tid*2+u;
      int row=idx>>2, q=idx&3;
      float4 v=*(const float4*)(A+(size_t)(m0+row)*HCd + k0+q*4);
      As[q*4+0][row]=v.x; As[q*4+1][row]=v.y; As[q*4+2][row]=v.z; As[q*4+3][row]=v.w;
      int kk=idx>>5, nc=idx&31;
      float4 w=*(const float4*)(B+(size_t)(k0+kk)*HCd + n0+nc*4);
      *(float4*)&Bs[kk][nc*4]=w;
    }
    __syncthreads();
#pragma unroll
    for(int kk=0;kk<GBK;kk++){
      float a[8],b[8];
      *(float4*)&a[0]=*(float4*)&As[kk][tm*8]; *(float4*)&a[4]=*(float4*)&As[kk][tm*8+4];
      *(float4*)&b[0]=*(float4*)&Bs[kk][tn*8]; *(float4*)&b[4]=*(float4*)&Bs[kk][tn*8+4];
#pragma unroll
      for(int i=0;i<8;i++)
#pragma unroll
        for(int j=0;j<8;j++) acc[i][j]+=a[i]*b[j];
    }
    __syncthreads();
  }
#pragma unroll
  for(int i=0;i<8;i++)
#pragma unroll
    for(int j=0;j<8;j++)
      Cm[(size_t)(m0+tm*8+i)*HCd + n0+tn*8+j]=acc[i][j];
}

// Encoder X (fp32 — kl precision headroom is thin)
__global__ __launch_bounds__(256) void k_xgemm(
    const float* __restrict__ emb, const float* __restrict__ Wih,
    const float* __restrict__ b1, const float* __restrict__ b2,
    const int* __restrict__ tok, int tshift, int M,
    float* __restrict__ X)
{
  __shared__ float As[GBK][GBM];
  __shared__ float Bs[GBK][GBN];
  int tid=threadIdx.x;
  int m0=blockIdx.x*GBM, n0=blockIdx.y*GBN;
  int tm=tid>>4, tn=tid&15;
  int arow=m0+(tid>>1);
  int atok=(arow<M)?tok[arow+tshift]:0;
  const float* abase=emb+(size_t)atok*HCd+(tid&1)*8;
  const float* bbase=Wih+(size_t)(n0+(tid>>1))*HCd+(tid&1)*8;
  int srow=tid>>1;
  float acc[8][8]={};
  for(int k0=0;k0<HCd;k0+=GBK){
#pragma unroll
    for(int u=0;u<2;u++){
      int q=2*(tid&1)+u;
      float4 v={0,0,0,0};
      if(arow<M) v=*(const float4*)(abase+k0+u*4);
      As[q*4+0][srow]=v.x; As[q*4+1][srow]=v.y; As[q*4+2][srow]=v.z; As[q*4+3][srow]=v.w;
      float4 w=*(const float4*)(bbase+k0+u*4);
      Bs[q*4+0][srow]=w.x; Bs[q*4+1][srow]=w.y; Bs[q*4+2][srow]=w.z; Bs[q*4+3][srow]=w.w;
    }
    __syncthreads();
#pragma unroll
    for(int kk=0;kk<GBK;kk++){
      float a[8],b[8];
      *(float4*)&a[0]=*(float4*)&As[kk][tm*8]; *(float4*)&a[4]=*(float4*)&As[kk][tm*8+4];
      *(float4*)&b[0]=*(float4*)&Bs[kk][tn*8]; *(float4*)&b[4]=*(float4*)&Bs[kk][tn*8+4];
#pragma unroll
      for(int i=0;i<8;i++)
#pragma unroll
        for(int j=0;j<8;j++) acc[i][j]+=a[i]*b[j];
    }
    __syncthreads();
  }
#pragma unroll
  for(int i=0;i<8;i++){
    int m=m0+tm*8+i; if(m>=M) continue;
#pragma unroll
    for(int j=0;j<8;j++){
      int n=n0+tn*8+j;
      X[(size_t)m*G4+n]=acc[i][j]+b1[n]+b2[n];
    }
  }
}

#define TBM 128
#define TBN 128
#define TBK 32

// Decoder X via bf16 MFMA
__global__ __launch_bounds__(256) void k_xgemm_mfma(
    const float* __restrict__ emb, const float* __restrict__ Wih,
    const float* __restrict__ b1, const float* __restrict__ b2,
    const int* __restrict__ tok, int M, float* __restrict__ X)
{
  __shared__ ushort As[TBM*TBK];
  __shared__ ushort Bs[TBN*TBK];
  int tid=threadIdx.x;
  int m0=blockIdx.x*TBM, n0=blockIdx.y*TBN;
  int wid=tid>>6, lane=tid&63;
  int wm=wid>>1, wn=wid&1;
  int r15=lane&15, g=lane>>4;
  f32x4 acc[4][4]={};
  int srow=tid>>1, shalf=tid&1;
  int arow=m0+srow;
  int atok=(arow<M)?tok[arow]:0;
  const float* aptr=emb+(size_t)atok*HCd + shalf*16;
  const float* bptr=Wih+(size_t)(n0+srow)*HCd + shalf*16;
  bool aok=arow<M;
  float bj[4];
#pragma unroll
  for(int j=0;j<4;j++){ int n=n0+wn*64+j*16+r15; bj[j]=b1[n]+b2[n]; }

  for(int k0=0;k0<HCd;k0+=TBK){
    float4 va0={0,0,0,0},va1={0,0,0,0},va2={0,0,0,0},va3={0,0,0,0};
    if(aok){
      va0=*(const float4*)(aptr+k0);   va1=*(const float4*)(aptr+k0+4);
      va2=*(const float4*)(aptr+k0+8); va3=*(const float4*)(aptr+k0+12);
    }
    float4 vb0=*(const float4*)(bptr+k0),   vb1=*(const float4*)(bptr+k0+4);
    float4 vb2=*(const float4*)(bptr+k0+8), vb3=*(const float4*)(bptr+k0+12);
    uint4v pa0={pk_bf16(va0.x,va0.y),pk_bf16(va0.z,va0.w),pk_bf16(va1.x,va1.y),pk_bf16(va1.z,va1.w)};
    uint4v pa1={pk_bf16(va2.x,va2.y),pk_bf16(va2.z,va2.w),pk_bf16(va3.x,va3.y),pk_bf16(va3.z,va3.w)};
    uint4v pb0={pk_bf16(vb0.x,vb0.y),pk_bf16(vb0.z,vb0.w),pk_bf16(vb1.x,vb1.y),pk_bf16(vb1.z,vb1.w)};
    uint4v pb1={pk_bf16(vb2.x,vb2.y),pk_bf16(vb2.z,vb2.w),pk_bf16(vb3.x,vb3.y),pk_bf16(vb3.z,vb3.w)};
    int sx=(srow>>1)&3;
    int u0=(shalf*2+0)^sx, u1=(shalf*2+1)^sx;
    *(uint4v*)&As[srow*32+u0*8]=pa0; *(uint4v*)&As[srow*32+u1*8]=pa1;
    *(uint4v*)&Bs[srow*32+u0*8]=pb0; *(uint4v*)&Bs[srow*32+u1*8]=pb1;
    __syncthreads();
    bf16x8 af[4], bf[4];
#pragma unroll
    for(int i=0;i<4;i++){
      int ra=wm*64+i*16+r15;
      af[i]=*(const bf16x8*)&As[ra*32+((g^((ra>>1)&3))<<3)];
      int rb=wn*64+i*16+r15;
      bf[i]=*(const bf16x8*)&Bs[rb*32+((g^((rb>>1)&3))<<3)];
    }
#pragma unroll
    for(int i=0;i<4;i++)
#pragma unroll
      for(int j=0;j<4;j++)
        acc[i][j]=__builtin_amdgcn_mfma_f32_16x16x32_bf16(af[i],bf[j],acc[i][j],0,0,0);
    __syncthreads();
  }
#pragma unroll
  for(int i=0;i<4;i++){
    int grow0=m0+wm*64+i*16+g*4;
#pragma unroll
    for(int j=0;j<4;j++){
      int gcol=n0+wn*64+j*16+r15;
#pragma unroll
      for(int r=0;r<4;r++){
        int grow=grow0+r;
        if(grow<M) X[(size_t)grow*G4+gcol]=acc[i][j][r]+bj[j];
      }
    }
  }
}

// ---------------- Encoder scan (bf16-packed seqlock, 1 dword poll/step) ----------------
__global__ __launch_bounds__(ET,2) void k_enc8(
    const float* __restrict__ Xg, const float* __restrict__ Whh,
    unsigned* estate,                 // [2][512] dwords: pk(h_2P,h_2P+1), LSB parity
    float* hT, float* cT)
{
  __shared__ float hlds[2][HCd];
  const int tid=threadIdx.x, lane=tid&63, wv=tid>>6;
  const int wid=blockIdx.x*8+wv;
  const int j0=wid*2, j1=j0+1;
  float w[8][16];
#pragma unroll
  for(int q=0;q<4;q++)
#pragma unroll
    for(int jj=0;jj<2;jj++){
      const float* p=Whh+(size_t)(q*HCd+j0+jj)*HCd+lane;
#pragma unroll
      for(int e=0;e<16;e++) w[q*2+jj][e]=p[(size_t)e*64];
    }
  float xg[8];
#pragma unroll
  for(int r=0;r<8;r++) xg[r]=Xg[(r>>1)*HCd+j0+(r&1)];
  float c0=0.f,c1=0.f;
  const int i0=tid*2, i1=i0+1;

  for(int s=1;s<=NSE;s++){
    unsigned u;
    unsigned* src=estate+((s-1)&1)*512;
    if(s==1) u=src[tid];
    else{
      const unsigned expp=(unsigned)(((s-1)>>1)&1);
      for(;;){
        u=ld_uc1(src+tid);
        if(((u^expp)&1u)==0u) break;
        __builtin_amdgcn_s_sleep(1);
      }
    }
    float* hl=hlds[(s-1)&1];
    hl[i0]=bf_lo(u); hl[i1]=bf_hi(u);
    __syncthreads();
    if(s==1){ c0=hl[j0]; c1=hl[j1]; }   // h0 == c0
    float hseg[16];
#pragma unroll
    for(int e=0;e<16;e++) hseg[e]=hl[lane+64*e];
    float d[8];
#pragma unroll
    for(int r=0;r<8;r++){ float sacc=0.f;
#pragma unroll
      for(int e=0;e<16;e++) sacc+=w[r][e]*hseg[e];
      d[r]=sacc; }
#pragma unroll
    for(int r=0;r<8;r++) d[r]=redl0(d[r]);
    float gi0=d[0]+xg[0], gi1=d[1]+xg[1];
    float gf0=d[2]+xg[2], gf1=d[3]+xg[3];
    float gg0=d[4]+xg[4], gg1=d[5]+xg[5];
    float go0=d[6]+xg[6], go1=d[7]+xg[7];
    if(s<NSE){
      const float* px=Xg+(size_t)s*G4;
#pragma unroll
      for(int r=0;r<8;r++) xg[r]=px[(r>>1)*HCd+j0+(r&1)];
    }
    c0=sigmoidf_(gf0)*c0+sigmoidf_(gi0)*tanhf(gg0);
    float h0=sigmoidf_(go0)*tanhf(c0);
    c1=sigmoidf_(gf1)*c1+sigmoidf_(gi1)*tanhf(gg1);
    float h1=sigmoidf_(go1)*tanhf(c1);
    if(lane==0){
      unsigned wpar=(unsigned)((s>>1)&1);
      st_uc1(estate+(s&1)*512+wid,(pk_bf16(h0,h1)&~1u)|wpar);
      if(s==NSE){ hT[j0]=h0; hT[j1]=h1; cT[j0]=c0; cT[j1]=c1; }
    }
  }
}

// ---------------- VAE heads (fp32 z vectors) ----------------
__global__ __launch_bounds__(256) void k_head(
    const float* __restrict__ hT, const float* __restrict__ cT,
    const float* __restrict__ mhw, const float* __restrict__ mhb,
    const float* __restrict__ lhw, const float* __restrict__ lhb,
    const float* __restrict__ mcw, const float* __restrict__ mcb,
    const float* __restrict__ lcw, const float* __restrict__ lcb,
    const float* __restrict__ eps_h, const float* __restrict__ eps_c,
    const float* __restrict__ cemb, const int* __restrict__ condp,
    float* zh, float* zc, float* klh, float* klc)
{
  int i=blockIdx.x;
  int tid=threadIdx.x, lane=tid&63, wv=tid>>6;
  __shared__ float sm[4];
  const float* Wm=(wv==0)?mhw:(wv==1)?lhw:(wv==2)?mcw:lcw;
  const float* vec=(wv<2)?hT:cT;
  const float* row=Wm+(size_t)i*HCd;
  float s=0.f;
  for(int k=lane;k<HCd;k+=64) s+=row[k]*vec[k];
  s=wave_reduce(s);
  if(lane==0) sm[wv]=s;
  __syncthreads();
  if(tid==0){
    float mh=sm[0]+mhb[i], lh=sm[1]+lhb[i];
    float mc=sm[2]+mcb[i], lc=sm[3]+lcb[i];
    zh[i]=eps_h[i]*expf(lh*0.5f)+mh;
    zc[i]=eps_c[i]*expf(lc*0.5f)+mc;
    klh[i]=0.5f*(mh*mh+expf(lh)-1.f-lh);
    klc[i]=0.5f*(mc*mc+expf(lc)-1.f-lc);
    if(i<Cc){
      float cd=cemb[condp[0]*Cc+i];
      zh[Hh+i]=cd; zc[Hh+i]=cd;
    }
  }
}

// decoder step 1: writes packed S1 (parity 0) + Hmat row 0
__global__ __launch_bounds__(256) void k_dec0(
    const float* __restrict__ Xg, const float* __restrict__ WhhO,
    const float* __restrict__ zh, const float* __restrict__ zc,
    unsigned* dstate, float* Hmat)
{
  int tid=threadIdx.x, lane=tid&63, wv=tid>>6;
  int j=blockIdx.x*4+wv;
  __shared__ float hcs[4][2];
  float hseg[16];
#pragma unroll
  for(int e=0;e<16;e++) hseg[e]=zh[lane+64*e];
  float g[4];
#pragma unroll
  for(int q=0;q<4;q++){
    const float* p=WhhO+(size_t)(q*HCd+j)*HCd+lane;
    float s=0.f;
#pragma unroll
    for(int e=0;e<16;e++) s+=p[(size_t)e*64]*hseg[e];
    s=wave_reduce(s);
    g[q]=s+Xg[q*HCd+j];
  }
  float cc=zc[j];
  float cn=sigmoidf_(g[1])*cc+sigmoidf_(g[0])*tanhf(g[2]);
  float hn=sigmoidf_(g[3])*tanhf(cn);
  if(lane==0){ hcs[wv][0]=hn; hcs[wv][1]=cn; Hmat[j]=hn; }
  __syncthreads();
  if(tid<2){
    int P=blockIdx.x*2+tid;
    unsigned dwh=pk_bf16(hcs[2*tid][0],hcs[2*tid+1][0])&~1u;
    unsigned dwc=pk_bf16(hcs[2*tid][1],hcs[2*tid+1][1])&~1u;
    dstate[1024+2*P]=dwh; dstate[1024+2*P+1]=dwc;   // slot 1
  }
}

// ---------------- Decoder scan (bf16-packed seqlock, 1 ldx2 poll/step) ----------------
__global__ __launch_bounds__(ET,2) void k_dec8(
    const float* __restrict__ Xg, const float* __restrict__ Weff,
    const float* __restrict__ cvec,
    const float* __restrict__ fccw, const float* __restrict__ fccb,
    const float* __restrict__ cemb, const int* __restrict__ condp,
    unsigned* dstate, float* __restrict__ Hmat)
{
  __shared__ float hlds[2][HCd];
  __shared__ float clds[2][HCd];
  const int tid=threadIdx.x, lane=tid&63, wv=tid>>6;
  const int wid=blockIdx.x*8+wv;
  const int j0=wid*2, j1=j0+1;
  float w[8][16];
#pragma unroll
  for(int q=0;q<4;q++)
#pragma unroll
    for(int jj=0;jj<2;jj++){
      const float* p=Weff+(size_t)(q*HCd+j0+jj)*HCd+lane;
#pragma unroll
      for(int e=0;e<16;e++) w[q*2+jj][e]=p[(size_t)e*64];
    }
  const bool hasf=(j0<Hh);
  float fcc0[16], fcc1[16];
  if(hasf){
    const float* p0=fccw+(size_t)j0*HCd+lane;
    const float* p1=fccw+(size_t)j1*HCd+lane;
#pragma unroll
    for(int e=0;e<16;e++){ fcc0[e]=p0[(size_t)e*64]; fcc1[e]=p1[(size_t)e*64]; }
  } else {
#pragma unroll
    for(int e=0;e<16;e++){ fcc0[e]=0.f; fcc1[e]=0.f; }
  }
  float fb0=hasf?fccb[j0]:0.f, fb1=hasf?fccb[j1]:0.f;
  int cond=condp[0];
  float cd0=hasf?0.f:cemb[cond*Cc+(j0-Hh)];
  float cd1=hasf?0.f:cemb[cond*Cc+(j1-Hh)];
  float cv[8];
#pragma unroll
  for(int r=0;r<8;r++) cv[r]=cvec[(r>>1)*HCd+j0+(r&1)];
  float xg[8];
  { const float* px=Xg+(size_t)1*G4;
#pragma unroll
    for(int r=0;r<8;r++) xg[r]=px[(r>>1)*HCd+j0+(r&1)]; }
  const int i0=tid*2, i1=i0+1;

  for(int s=2;s<=NSD;s++){
    uint2v v;
    unsigned* sp=dstate+((s-1)&1)*1024;
    if(s==2){ v.x=sp[2*tid]; v.y=sp[2*tid+1]; }
    else{
      const unsigned expp=(unsigned)(((s-1)>>1)&1);
      for(;;){
        v=ld_uc2(sp+2*tid);
        if((((v.x^expp)|(v.y^expp))&1u)==0u) break;
        __builtin_amdgcn_s_sleep(1);
      }
    }
    float* hl=hlds[(s-1)&1]; float* cl=clds[(s-1)&1];
    hl[i0]=bf_lo(v.x); hl[i1]=bf_hi(v.x);
    cl[i0]=bf_lo(v.y); cl[i1]=bf_hi(v.y);
    __syncthreads();
    float hseg[16], cseg[16];
#pragma unroll
    for(int e=0;e<16;e++){ hseg[e]=hl[lane+64*e]; cseg[e]=cl[lane+64*e]; }
    float d[8]; float s8=0.f, s9=0.f;
#pragma unroll
    for(int r=0;r<8;r++){ float sacc=0.f;
#pragma unroll
      for(int e=0;e<16;e++) sacc+=w[r][e]*hseg[e];
      d[r]=sacc; }
#pragma unroll
    for(int r=0;r<8;r++) d[r]=redl0(d[r]);
    if(hasf){
#pragma unroll
      for(int e=0;e<16;e++){ s8+=fcc0[e]*cseg[e]; s9+=fcc1[e]*cseg[e]; }
      s8=redl0(s8); s9=redl0(s9);
    }
    float gi0=d[0]+xg[0]+cv[0], gi1=d[1]+xg[1]+cv[1];
    float gf0=d[2]+xg[2]+cv[2], gf1=d[3]+xg[3]+cv[3];
    float gg0=d[4]+xg[4]+cv[4], gg1=d[5]+xg[5]+cv[5];
    float go0=d[6]+xg[6]+cv[6], go1=d[7]+xg[7]+cv[7];
    if(s<NSD){
      const float* px=Xg+(size_t)s*G4;
#pragma unroll
      for(int r=0;r<8;r++) xg[r]=px[(r>>1)*HCd+j0+(r&1)];
    }
    float cc0=hasf?(s8+fb0):cd0;
    float cc1=hasf?(s9+fb1):cd1;
    float cn0=sigmoidf_(gf0)*cc0+sigmoidf_(gi0)*tanhf(gg0);
    float hn0=sigmoidf_(go0)*tanhf(cn0);
    float cn1=sigmoidf_(gf1)*cc1+sigmoidf_(gi1)*tanhf(gg1);
    float hn1=sigmoidf_(go1)*tanhf(cn1);
    if(lane==0){
      unsigned wpar=(unsigned)((s>>1)&1);
      uint2v pk;
      pk.x=(pk_bf16(hn0,hn1)&~1u)|wpar;
      pk.y=(pk_bf16(cn0,cn1)&~1u)|wpar;
      st_uc2(dstate+(s&1)*1024+2*wid,pk);
      Hmat[(size_t)(s-1)*HCd+j0]=hn0; Hmat[(size_t)(s-1)*HCd+j1]=hn1;
    }
  }
}

// out_w fp32 -> bf16 (RNE), packed 2/dword
__global__ __launch_bounds__(256) void k_cvtB(const float* __restrict__ B,
    unsigned* __restrict__ Bb){
  size_t idx=(size_t)blockIdx.x*256+threadIdx.x;
  size_t total=(size_t)VSZ*HCd/4;
  for(size_t i=idx;i<total;i+=(size_t)gridDim.x*256){
    float4 v=*(const float4*)(B+i*4);
    Bb[i*2]  =pk_bf16(v.x,v.y);
    Bb[i*2+1]=pk_bf16(v.z,v.w);
  }
}

// ---------------- logits GEMM, B pre-converted bf16 ----------------
__global__ __launch_bounds__(256) void k_gemm2(
    const float* __restrict__ A, const ushort* __restrict__ Bb,
    const float* __restrict__ bias, float* __restrict__ Cm, int M)
{
  __shared__ ushort As[TBM*TBK];
  __shared__ ushort Bs[TBN*TBK];
  int tid=threadIdx.x;
  int m0=blockIdx.x*TBM, n0=blockIdx.y*TBN;
  int wid=tid>>6, lane=tid&63;
  int wm=wid>>1, wn=wid&1;
  int r15=lane&15, g=lane>>4;
  f32x4 acc[4][4]={};
  int srow=tid>>1, shalf=tid&1;
  const float*  aptr=A +(size_t)(m0+srow)*HCd + shalf*16;
  const ushort* bptr=Bb+(size_t)(n0+srow)*HCd + shalf*16;
  bool aok=(m0+srow)<M;
  float bj[4];
#pragma unroll
  for(int j=0;j<4;j++) bj[j]=bias[n0+wn*64+j*16+r15];

  for(int k0=0;k0<HCd;k0+=TBK){
    float4 va0={0,0,0,0},va1={0,0,0,0},va2={0,0,0,0},va3={0,0,0,0};
    if(aok){
      va0=*(const float4*)(aptr+k0);   va1=*(const float4*)(aptr+k0+4);
      va2=*(const float4*)(aptr+k0+8); va3=*(const float4*)(aptr+k0+12);
    }
    uint4v qb0=*(const uint4v*)(bptr+k0);
    uint4v qb1=*(const uint4v*)(bptr+k0+8);
    uint4v pa0={pk_bf16(va0.x,va0.y),pk_bf16(va0.z,va0.w),pk_bf16(va1.x,va1.y),pk_bf16(va1.z,va1.w)};
    uint4v pa1={pk_bf16(va2.x,va2.y),pk_bf16(va2.z,va2.w),pk_bf16(va3.x,va3.y),pk_bf16(va3.z,va3.w)};
    int sx=(srow>>1)&3;
    int u0=(shalf*2+0)^sx, u1=(shalf*2+1)^sx;
    *(uint4v*)&As[srow*32+u0*8]=pa0; *(uint4v*)&As[srow*32+u1*8]=pa1;
    *(uint4v*)&Bs[srow*32+u0*8]=qb0; *(uint4v*)&Bs[srow*32+u1*8]=qb1;
    __syncthreads();
    bf16x8 af[4], bf[4];
#pragma unroll
    for(int i=0;i<4;i++){
      int ra=wm*64+i*16+r15;
      af[i]=*(const bf16x8*)&As[ra*32+((g^((ra>>1)&3))<<3)];
      int rb=wn*64+i*16+r15;
      bf[i]=*(const bf16x8*)&Bs[rb*32+((g^((rb>>1)&3))<<3)];
    }
#pragma unroll
    for(int i=0;i<4;i++)
#pragma unroll
      for(int j=0;j<4;j++)
        acc[i][j]=__builtin_amdgcn_mfma_f32_16x16x32_bf16(af[i],bf[j],acc[i][j],0,0,0);
    __syncthreads();
  }
#pragma unroll
  for(int i=0;i<4;i++){
    int grow0=m0+wm*64+i*16+g*4;
#pragma unroll
    for(int j=0;j<4;j++){
      int gcol=n0+wn*64+j*16+r15;
#pragma unroll
      for(int r=0;r<4;r++){
        int grow=grow0+r;
        if(grow<M) Cm[(size_t)grow*VSZ+gcol]=acc[i][j][r]+bj[j];
      }
    }
  }
}

// ---------------- logits GEMM fallback (in-kernel B conversion) ----------------
__global__ __launch_bounds__(256) void k_gemm_mfma(
    const float* __restrict__ A, const float* __restrict__ B,
    const float* __restrict__ bias, float* __restrict__ Cm, int M)
{
  __shared__ ushort As[TBM*TBK];
  __shared__ ushort Bs[TBN*TBK];
  int tid=threadIdx.x;
  int m0=blockIdx.x*TBM, n0=blockIdx.y*TBN;
  int wid=tid>>6, lane=tid&63;
  int wm=wid>>1, wn=wid&1;
  int r15=lane&15, g=lane>>4;
  f32x4 acc[4][4]={};
  int srow=tid>>1, shalf=tid&1;
  const float* aptr=A+(size_t)(m0+srow)*HCd + shalf*16;
  const float* bptr=B+(size_t)(n0+srow)*HCd + shalf*16;
  bool aok=(m0+srow)<M;
  float bj[4];
#pragma unroll
  for(int j=0;j<4;j++) bj[j]=bias[n0+wn*64+j*16+r15];

  for(int k0=0;k0<HCd;k0+=TBK){
    float4 va0={0,0,0,0},va1={0,0,0,0},va2={0,0,0,0},va3={0,0,0,0};
    if(aok){
      va0=*(const float4*)(aptr+k0);   va1=*(const float4*)(aptr+k0+4);
      va2=*(const float4*)(aptr+k0+8); va3=*(const float4*)(aptr+k0+12);
    }
    float4 vb0=*(const float4*)(bptr+k0),   vb1=*(const float4*)(bptr+k0+4);
    float4 vb2=*(const float4*)(bptr+k0+8), vb3=*(const float4*)(bptr+k0+12);
    uint4v pa0={pk_bf16(va0.x,va0.y),pk_bf16(va0.z,va0.w),pk_bf16(va1.x,va1.y),pk_bf16(va1.z,va1.w)};
    uint4v pa1={pk_bf16(va2.x,va2.y),pk_bf16(va2.z,va2.w),pk_bf16(va3.x,va3.y),pk_bf16(va3.z,va3.w)};
    uint4v pb0={pk_bf16(vb0.x,vb0.y),pk_bf16(vb0.z,vb0.w),pk_bf16(vb1.x,vb1.y),pk_bf16(vb1.z,vb1.w)};
    uint4v pb1={pk_bf16(vb2.x,vb2.y),pk_bf16(vb2.z,vb2.w),pk_bf16(vb3.x,vb3.y),pk_bf16(vb3.z,vb3.w)};
    int sx=(srow>>1)&3;
    int u0=(shalf*2+0)^sx, u1=(shalf*2+1)^sx;
    *(uint4v*)&As[srow*32+u0*8]=pa0; *(uint4v*)&As[srow*32+u1*8]=pa1;
    *(uint4v*)&Bs[srow*32+u0*8]=pb0; *(uint4v*)&Bs[srow*32+u1*8]=pb1;
    __syncthreads();
    bf16x8 af[4], bf[4];
#pragma unroll
    for(int i=0;i<4;i++){
      int ra=wm*64+i*16+r15;
      af[i]=*(const bf16x8*)&As[ra*32+((g^((ra>>1)&3))<<3)];
      int rb=wn*64+i*16+r15;
      bf[i]=*(const bf16x8*)&Bs[rb*32+((g^((rb>>1)&3))<<3)];
    }
#pragma unroll
    for(int i=0;i<4;i++)
#pragma unroll
      for(int j=0;j<4;j++)
        acc[i][j]=__builtin_amdgcn_mfma_f32_16x16x32_bf16(af[i],bf[j],acc[i][j],0,0,0);
    __syncthreads();
  }
#pragma unroll
  for(int i=0;i<4;i++){
    int grow0=m0+wm*64+i*16+g*4;
#pragma unroll
    for(int j=0;j<4;j++){
      int gcol=n0+wn*64+j*16+r15;
#pragma unroll
      for(int r=0;r<4;r++){
        int grow=grow0+r;
        if(grow<M) Cm[(size_t)grow*VSZ+gcol]=acc[i][j][r]+bj[j];
      }
    }
  }
}

// per-row cross-entropy, single-pass online softmax
__global__ __launch_bounds__(256) void k_ce(const float* __restrict__ logits,
    const int* __restrict__ tok, int base, float* __restrict__ ce)
{
  int r=blockIdx.x;
  const float* row=logits+(size_t)r*VSZ;
  int tid=threadIdx.x, lane=tid&63, wv=tid>>6;
  float m=-1e30f, s=0.f;
  for(int i=tid;i<VSZ;i+=256){
    float v=row[i];
    if(v>m){ s=s*__expf(m-v)+1.f; m=v; }
    else s+=__expf(v-m);
  }
#pragma unroll
  for(int o=32;o;o>>=1){
    float mo=__shfl_xor(m,o,64), so=__shfl_xor(s,o,64);
    float mn=fmaxf(m,mo);
    s=s*__expf(m-mn)+so*__expf(mo-mn);
    m=mn;
  }
  __shared__ float smm[4], sms[4];
  if(lane==0){ smm[wv]=m; sms[wv]=s; }
  __syncthreads();
  if(tid==0){
    float M2=fmaxf(fmaxf(smm[0],smm[1]),fmaxf(smm[2],smm[3]));
    float S2=sms[0]*__expf(smm[0]-M2)+sms[1]*__expf(smm[1]-M2)
            +sms[2]*__expf(smm[2]-M2)+sms[3]*__expf(smm[3]-M2);
    int tgt=tok[base+r+1];
    ce[base+r]=M2+logf(S2)-row[tgt];
  }
}

__global__ __launch_bounds__(256) void k_final(const float* __restrict__ ce,
    const float* __restrict__ klh, const float* __restrict__ klc,
    const float* __restrict__ kldw, float* __restrict__ outp)
{
  int tid=threadIdx.x, lane=tid&63, wv=tid>>6;
  float s0=0,s1=0,s2=0;
  for(int i=tid;i<NSD;i+=256) s0+=ce[i];
  for(int i=tid;i<Hh;i+=256){ s1+=klh[i]; s2+=klc[i]; }
  s0=wave_reduce(s0); s1=wave_reduce(s1); s2=wave_reduce(s2);
  __shared__ float sm[3][4];
  if(lane==0){ sm[0][wv]=s0; sm[1][wv]=s1; sm[2][wv]=s2; }
  __syncthreads();
  if(tid==0){
    float ces=sm[0][0]+sm[0][1]+sm[0][2]+sm[0][3];
    float kh =sm[1][0]+sm[1][1]+sm[1][2]+sm[1][3];
    float kc =sm[2][0]+sm[2][1]+sm[2][2]+sm[2][3];
    float rec=ces/(float)NSD;
    outp[0]=rec+(kh+kc)*kldw[0];
    outp[1]=rec; outp[2]=kh; outp[3]=kc;
  }
}

extern "C" void kernel_launch(void* const* d_in, const int* in_sizes, int n_in,
                              void* d_out, int out_size, void* d_ws, size_t ws_size,
                              hipStream_t stream) {
  const int*   tok   =(const int*)  d_in[0];
  const int*   cond  =(const int*)  d_in[1];
  const float* eps_h =(const float*)d_in[2];
  const float* eps_c =(const float*)d_in[3];
  const float* kldw  =(const float*)d_in[4];
  const float* enc_embed=(const float*)d_in[5];
  const float* enc_cemb =(const float*)d_in[6];
  const float* enc_Wih  =(const float*)d_in[7];
  const float* enc_Whh  =(const float*)d_in[8];
  const float* enc_bih  =(const float*)d_in[9];
  const float* enc_bhh  =(const float*)d_in[10];
  const float* fc_mh_w=(const float*)d_in[11];
  const float* fc_mh_b=(const float*)d_in[12];
  const float* fc_lh_w=(const float*)d_in[13];
  const float* fc_lh_b=(const float*)d_in[14];
  const float* fc_mc_w=(const float*)d_in[15];
  const float* fc_mc_b=(const float*)d_in[16];
  const float* fc_lc_w=(const float*)d_in[17];
  const float* fc_lc_b=(const float*)d_in[18];
  const float* dec_embed=(const float*)d_in[19];
  const float* dec_cemb =(const float*)d_in[20];
  const float* dec_Wih  =(const float*)d_in[21];
  const float* dec_Whh  =(const float*)d_in[22];
  const float* dec_bih  =(const float*)d_in[23];
  const float* dec_bhh  =(const float*)d_in[24];
  const float* fc_h_w=(const float*)d_in[25];
  const float* fc_h_b=(const float*)d_in[26];
  const float* fc_c_w=(const float*)d_in[27];
  const float* fc_c_b=(const float*)d_in[28];
  const float* out_w=(const float*)d_in[29];
  const float* out_b=(const float*)d_in[30];

  float* ws=(float*)d_ws;
  size_t off=0;
  unsigned* estate=(unsigned*)(ws+off); off+=1024;   // 2 x 512 dwords
  unsigned* dstate=(unsigned*)(ws+off); off+=2048;   // 2 x 1024 dwords
  float* cvec=ws+off; off+=G4;
  float* Weff=ws+off; off+=(size_t)G4*HCd;
  float* hT  =ws+off; off+=HCd;
  float* cT  =ws+off; off+=HCd;
  float* zh  =ws+off; off+=HCd;
  float* zc  =ws+off; off+=HCd;
  float* klh =ws+off; off+=Hh;
  float* klc =ws+off; off+=Hh;
  float* Hmat=ws+off; off+=(size_t)NSD*HCd;
  float* ce  =ws+off; off+=2048;
  size_t avail=ws_size/4;
  size_t xa_sz=(size_t)NSE*G4, xb_sz=(size_t)NSD*G4;
  size_t wb_sz=(size_t)VSZ*HCd/2;              // bf16 out_w, in float slots
  float* XA=ws+off;
  bool dual=(off+xa_sz+xb_sz)<=avail;
  float* XB=dual?(XA+xa_sz):XA;
  bool wbok=dual && (off+xa_sz+xb_sz+wb_sz)<=avail;
  unsigned* wB=(unsigned*)(XB+xb_sz);
  size_t region=(avail>off)?(avail-off):0;
  int chunk=256;
  if(!dual){
    if((size_t)chunk*VSZ>region){ chunk=(int)(region/(size_t)VSZ); if(chunk<1)chunk=1; }
  }
  float* lbuf=XA;

  k_init8<<<1,256,0,stream>>>(estate,dstate,enc_cemb,cond);
  k_dconst<<<64,256,0,stream>>>(dec_Whh,fc_h_b,dec_cemb,cond,cvec);
  { dim3 g(G4/GBM, HCd/GBN);
    k_weff<<<g,256,0,stream>>>(dec_Whh,fc_h_w,Weff); }
  { dim3 g((NSE+GBM-1)/GBM, G4/GBN);           // Xenc (fp32)
    k_xgemm<<<g,256,0,stream>>>(enc_embed,enc_Wih,enc_bih,enc_bhh,tok,1,NSE,XA); }
  if(dual){
    dim3 g((NSD+TBM-1)/TBM, G4/TBN);           // Xdec (bf16 MFMA)
    k_xgemm_mfma<<<g,256,0,stream>>>(dec_embed,dec_Wih,dec_bih,dec_bhh,tok,NSD,XB);
  }
  if(wbok) k_cvtB<<<2048,256,0,stream>>>(out_w,wB);
  k_enc8<<<EB,ET,0,stream>>>(XA,enc_Whh,estate,hT,cT);
  k_head<<<Hh,256,0,stream>>>(hT,cT,fc_mh_w,fc_mh_b,fc_lh_w,fc_lh_b,
                              fc_mc_w,fc_mc_b,fc_lc_w,fc_lc_b,
                              eps_h,eps_c,dec_cemb,cond,zh,zc,klh,klc);
  if(!dual){
    dim3 g((NSD+TBM-1)/TBM, G4/TBN);           // Xdec overwrites Xenc (encoder done)
    k_xgemm_mfma<<<g,256,0,stream>>>(dec_embed,dec_Wih,dec_bih,dec_bhh,tok,NSD,XB);
  }
  k_dec0<<<256,256,0,stream>>>(XB,dec_Whh,zh,zc,dstate,Hmat);
  k_dec8<<<EB,ET,0,stream>>>(XB,Weff,cvec,fc_c_w,fc_c_b,dec_cemb,cond,dstate,Hmat);
  for(int base=0;base<NSD;base+=chunk){        // lbuf overlays XA — scans done
    int rows=NSD-base; if(rows>chunk) rows=chunk;
    dim3 g((rows+TBM-1)/TBM, VSZ/TBN);
    if(wbok) k_gemm2<<<g,256,0,stream>>>(Hmat+(size_t)base*HCd,(const ushort*)wB,out_b,lbuf,rows);
    else     k_gemm_mfma<<<g,256,0,stream>>>(Hmat+(size_t)base*HCd,out_w,out_b,lbuf,rows);
    k_ce<<<rows,256,0,stream>>>(lbuf,tok,base,ce);
  }
  k_final<<<1,256,0,stream>>>(ce,klh,klc,kldw,(float*)d_out);
}

// Round 9
// 13526.581 us; speedup vs baseline: 1.0925x; 1.0867x over previous
//
#include <hip/hip_runtime.h>
#include <math.h>

// Problem sizes (fixed)
#define VSZ 32000
#define Hh  768
#define Cc  256
#define HCd 1024
#define G4  4096
#define NSE 2046   // encoder steps
#define NSD 2047   // decoder steps

// Scan: 64 blocks x 512 threads (8 waves) = 512 waves, 2 outputs/wave.
#define EB 64
#define ET 512
// Fused encoder: 64 scan blocks + 192 prologue helper blocks (independent work).
#define FGRID 256

typedef __attribute__((ext_vector_type(4))) unsigned uint4v;
typedef __attribute__((ext_vector_type(2))) unsigned uint2v;
typedef __attribute__((ext_vector_type(8))) short bf16x8;
typedef __attribute__((ext_vector_type(4))) float f32x4;

__device__ __forceinline__ float sigmoidf_(float x){ return 1.0f/(1.0f+expf(-x)); }

__device__ __forceinline__ float wave_reduce(float v){
#pragma unroll
  for(int o=32;o;o>>=1) v += __shfl_xor(v,o,64);
  return v;
}
// Reduce 64 lanes; total valid in lane 0.
__device__ __forceinline__ float redl0(float v){
  int x;
  x=__builtin_amdgcn_update_dpp(0,__float_as_int(v),0xB1,0xf,0xf,true); v+=__int_as_float(x); // ^1
  x=__builtin_amdgcn_update_dpp(0,__float_as_int(v),0x4E,0xf,0xf,true); v+=__int_as_float(x); // ^2
  v+=__int_as_float(__builtin_amdgcn_ds_swizzle(__float_as_int(v),0x101F)); // ^4
  v+=__int_as_float(__builtin_amdgcn_ds_swizzle(__float_as_int(v),0x201F)); // ^8
  v+=__int_as_float(__builtin_amdgcn_ds_swizzle(__float_as_int(v),0x401F)); // ^16
  v+=__int_as_float(__builtin_amdgcn_readlane(__float_as_int(v),32));
  return v;
}

// Device-scope (coherence-point) ops. Per-dword LSB parity self-validates.
__device__ __forceinline__ uint2v ld_uc2(const unsigned* p){
  uint2v r;
  asm volatile("global_load_dwordx2 %0, %1, off sc0 sc1\n\ts_waitcnt vmcnt(0)"
               : "=v"(r) : "v"(p) : "memory");
  return r;
}
__device__ __forceinline__ uint4v ld_uc4(const unsigned* p){
  uint4v r;
  asm volatile("global_load_dwordx4 %0, %1, off sc0 sc1\n\ts_waitcnt vmcnt(0)"
               : "=v"(r) : "v"(p) : "memory");
  return r;
}
__device__ __forceinline__ void st_uc2(unsigned* p, uint2v v){
  asm volatile("global_store_dwordx2 %0, %1, off sc0 sc1" :: "v"(p), "v"(v) : "memory");
}
__device__ __forceinline__ void st_uc4(unsigned* p, uint4v v){
  asm volatile("global_store_dwordx4 %0, %1, off sc0 sc1" :: "v"(p), "v"(v) : "memory");
}

// fp32->bf16 RNE, pack two per dword
__device__ __forceinline__ unsigned pk_bf16(float a, float b){
  unsigned ua=__float_as_uint(a); ua += 0x7fffu + ((ua>>16)&1u);
  unsigned ub=__float_as_uint(b); ub += 0x7fffu + ((ub>>16)&1u);
  return (ua>>16) | (ub & 0xffff0000u);
}

// init (re-runs every replay): enc S0 slot0 parity0, slot1 parity1-stale;
// dec slot0 zeroed (parity0 = invalid for its first poll, which expects 1).
__global__ void k_init9(unsigned* estate, unsigned* dstate,
                        const float* __restrict__ cemb, const int* __restrict__ condp){
  int tid=threadIdx.x;
  int cond=condp[0];
  for(int i=tid;i<HCd;i+=256){
    float v=(i<Hh)?0.f:cemb[cond*Cc+(i-Hh)];
    estate[i]=__float_as_uint(v)&~1u;
    estate[HCd+i]=1u;
  }
  for(int i=tid;i<2*HCd;i+=256) dstate[i]=0u;   // slot0 stale
}

#define GBM 128
#define GBN 128
#define GBK 16
#define TBM 128
#define TBN 128
#define TBK 32

// Shared-memory union for the fused encoder kernel.
struct SmU {
  union {
    float hlds[2][HCd];                                        // scan: 8KB
    struct { float As[GBK][GBM]; float Bs[GBK][GBN]; } wf;     // weff: 16KB
    struct { ushort As[TBM*TBK]; ushort Bs[TBN*TBK]; } xd;     // xdec: 16KB
  } u;
};

// ---- helper units (run inside k_encF on blocks 64..255) ----
// weff tile u in [0,256): Weff[m0+.., n0+..] = dec_W_hh[:, :768] @ fc_h_w
__device__ void weff_unit(int u, const float* __restrict__ A,
    const float* __restrict__ B, float* __restrict__ Cm, SmU& sm, int tid){
  int m0=(u>>3)*GBM, n0=(u&7)*GBN;
  int tm=tid>>4, tn=tid&15;
  float acc[8][8]={};
  for(int k0=0;k0<Hh;k0+=GBK){
    if(tid<256){
#pragma unroll
      for(int uu=0;uu<2;uu++){
        int idx=tid*2+uu;
        int row=idx>>2, q=idx&3;
        float4 v=*(const float4*)(A+(size_t)(m0+row)*HCd + k0+q*4);
        sm.u.wf.As[q*4+0][row]=v.x; sm.u.wf.As[q*4+1][row]=v.y;
        sm.u.wf.As[q*4+2][row]=v.z; sm.u.wf.As[q*4+3][row]=v.w;
        int kk=idx>>5, nc=idx&31;
        float4 w=*(const float4*)(B+(size_t)(k0+kk)*HCd + n0+nc*4);
        *(float4*)&sm.u.wf.Bs[kk][nc*4]=w;
      }
    }
    __syncthreads();
    if(tid<256){
#pragma unroll
      for(int kk=0;kk<GBK;kk++){
        float a[8],b[8];
        *(float4*)&a[0]=*(float4*)&sm.u.wf.As[kk][tm*8]; *(float4*)&a[4]=*(float4*)&sm.u.wf.As[kk][tm*8+4];
        *(float4*)&b[0]=*(float4*)&sm.u.wf.Bs[kk][tn*8]; *(float4*)&b[4]=*(float4*)&sm.u.wf.Bs[kk][tn*8+4];
#pragma unroll
        for(int i=0;i<8;i++)
#pragma unroll
          for(int j=0;j<8;j++) acc[i][j]+=a[i]*b[j];
      }
    }
    __syncthreads();
  }
  if(tid<256){
#pragma unroll
    for(int i=0;i<8;i++)
#pragma unroll
      for(int j=0;j<8;j++)
        Cm[(size_t)(m0+tm*8+i)*HCd + n0+tn*8+j]=acc[i][j];
  }
}

// xdec tile q in [0,512): XB tile via bf16 MFMA
__device__ void xdec_unit(int q, const float* __restrict__ emb,
    const float* __restrict__ Wih, const float* __restrict__ b1,
    const float* __restrict__ b2, const int* __restrict__ tok,
    float* __restrict__ X, SmU& sm, int tid){
  int m0=(q>>5)*TBM, n0=(q&31)*TBN;
  int wid=tid>>6, lane=tid&63;
  int wm=wid>>1, wn=wid&1;
  int r15=lane&15, g=lane>>4;
  f32x4 acc[4][4]={};
  int srow=tid>>1, shalf=tid&1;
  int arow=m0+srow;
  bool act=(tid<256);
  int atok=(act&&arow<NSD)?tok[arow]:0;
  const float* aptr=emb+(size_t)atok*HCd + shalf*16;
  const float* bptr=Wih+(size_t)(n0+srow)*HCd + shalf*16;
  bool aok=act&&(arow<NSD);
  float bj[4];
  if(act){
#pragma unroll
    for(int j=0;j<4;j++){ int n=n0+wn*64+j*16+r15; bj[j]=b1[n]+b2[n]; }
  }
  for(int k0=0;k0<HCd;k0+=TBK){
    if(act){
      float4 va0={0,0,0,0},va1={0,0,0,0},va2={0,0,0,0},va3={0,0,0,0};
      if(aok){
        va0=*(const float4*)(aptr+k0);   va1=*(const float4*)(aptr+k0+4);
        va2=*(const float4*)(aptr+k0+8); va3=*(const float4*)(aptr+k0+12);
      }
      float4 vb0=*(const float4*)(bptr+k0),   vb1=*(const float4*)(bptr+k0+4);
      float4 vb2=*(const float4*)(bptr+k0+8), vb3=*(const float4*)(bptr+k0+12);
      uint4v pa0={pk_bf16(va0.x,va0.y),pk_bf16(va0.z,va0.w),pk_bf16(va1.x,va1.y),pk_bf16(va1.z,va1.w)};
      uint4v pa1={pk_bf16(va2.x,va2.y),pk_bf16(va2.z,va2.w),pk_bf16(va3.x,va3.y),pk_bf16(va3.z,va3.w)};
      uint4v pb0={pk_bf16(vb0.x,vb0.y),pk_bf16(vb0.z,vb0.w),pk_bf16(vb1.x,vb1.y),pk_bf16(vb1.z,vb1.w)};
      uint4v pb1={pk_bf16(vb2.x,vb2.y),pk_bf16(vb2.z,vb2.w),pk_bf16(vb3.x,vb3.y),pk_bf16(vb3.z,vb3.w)};
      int sx=(srow>>1)&3;
      int u0=(shalf*2+0)^sx, u1=(shalf*2+1)^sx;
      *(uint4v*)&sm.u.xd.As[srow*32+u0*8]=pa0; *(uint4v*)&sm.u.xd.As[srow*32+u1*8]=pa1;
      *(uint4v*)&sm.u.xd.Bs[srow*32+u0*8]=pb0; *(uint4v*)&sm.u.xd.Bs[srow*32+u1*8]=pb1;
    }
    __syncthreads();
    if(act){
      bf16x8 af[4], bf[4];
#pragma unroll
      for(int i=0;i<4;i++){
        int ra=wm*64+i*16+r15;
        af[i]=*(const bf16x8*)&sm.u.xd.As[ra*32+((g^((ra>>1)&3))<<3)];
        int rb=wn*64+i*16+r15;
        bf[i]=*(const bf16x8*)&sm.u.xd.Bs[rb*32+((g^((rb>>1)&3))<<3)];
      }
#pragma unroll
      for(int i=0;i<4;i++)
#pragma unroll
        for(int j=0;j<4;j++)
          acc[i][j]=__builtin_amdgcn_mfma_f32_16x16x32_bf16(af[i],bf[j],acc[i][j],0,0,0);
    }
    __syncthreads();
  }
  if(act){
#pragma unroll
    for(int i=0;i<4;i++){
      int grow0=m0+wm*64+i*16+g*4;
#pragma unroll
      for(int j=0;j<4;j++){
        int gcol=n0+wn*64+j*16+r15;
#pragma unroll
        for(int r=0;r<4;r++){
          int grow=grow0+r;
          if(grow<NSD) X[(size_t)grow*G4+gcol]=acc[i][j][r]+bj[j];
        }
      }
    }
  }
}

// cvtB stripe i in [0,64): 128000 float4 units each (total 8,192,000)
__device__ void cvtb_unit(int i, const float* __restrict__ B,
    unsigned* __restrict__ Bb, int tid){
  size_t base=(size_t)i*128000u;
  for(size_t x=base+tid; x<base+128000u; x+=ET){
    float4 v=*(const float4*)(B+x*4);
    Bb[x*2]  =pk_bf16(v.x,v.y);
    Bb[x*2+1]=pk_bf16(v.z,v.w);
  }
}

// dconst chunk i in [0,16): rows [i*256,(i+1)*256)
__device__ void dconst_unit(int i, const float* __restrict__ Whh,
    const float* __restrict__ fhb, const float* __restrict__ cemb,
    int cond, float* __restrict__ cvec, int tid){
  int lane=tid&63, wv=tid>>6;
  for(int r=i*256+wv; r<i*256+256; r+=8){
    const float* row=Whh+(size_t)r*HCd;
    float s=0.f;
    for(int k=lane;k<Hh;k+=64) s+=row[k]*fhb[k];
    for(int k=lane;k<Cc;k+=64) s+=row[Hh+k]*cemb[cond*Cc+k];
    s=wave_reduce(s);
    if(lane==0) cvec[r]=s;
  }
}

// Encoder X (fp32 tile GEMM — kl precision headroom is thin)
__global__ __launch_bounds__(256) void k_xgemm(
    const float* __restrict__ emb, const float* __restrict__ Wih,
    const float* __restrict__ b1, const float* __restrict__ b2,
    const int* __restrict__ tok, int tshift, int M,
    float* __restrict__ X)
{
  __shared__ float As[GBK][GBM];
  __shared__ float Bs[GBK][GBN];
  int tid=threadIdx.x;
  int m0=blockIdx.x*GBM, n0=blockIdx.y*GBN;
  int tm=tid>>4, tn=tid&15;
  int arow=m0+(tid>>1);
  int atok=(arow<M)?tok[arow+tshift]:0;
  const float* abase=emb+(size_t)atok*HCd+(tid&1)*8;
  const float* bbase=Wih+(size_t)(n0+(tid>>1))*HCd+(tid&1)*8;
  int srow=tid>>1;
  float acc[8][8]={};
  for(int k0=0;k0<HCd;k0+=GBK){
#pragma unroll
    for(int u=0;u<2;u++){
      int q=2*(tid&1)+u;
      float4 v={0,0,0,0};
      if(arow<M) v=*(const float4*)(abase+k0+u*4);
      As[q*4+0][srow]=v.x; As[q*4+1][srow]=v.y; As[q*4+2][srow]=v.z; As[q*4+3][srow]=v.w;
      float4 w=*(const float4*)(bbase+k0+u*4);
      Bs[q*4+0][srow]=w.x; Bs[q*4+1][srow]=w.y; Bs[q*4+2][srow]=w.z; Bs[q*4+3][srow]=w.w;
    }
    __syncthreads();
#pragma unroll
    for(int kk=0;kk<GBK;kk++){
      float a[8],b[8];
      *(float4*)&a[0]=*(float4*)&As[kk][tm*8]; *(float4*)&a[4]=*(float4*)&As[kk][tm*8+4];
      *(float4*)&b[0]=*(float4*)&Bs[kk][tn*8]; *(float4*)&b[4]=*(float4*)&Bs[kk][tn*8+4];
#pragma unroll
      for(int i=0;i<8;i++)
#pragma unroll
        for(int j=0;j<8;j++) acc[i][j]+=a[i]*b[j];
    }
    __syncthreads();
  }
#pragma unroll
  for(int i=0;i<8;i++){
    int m=m0+tm*8+i; if(m>=M) continue;
#pragma unroll
    for(int j=0;j<8;j++){
      int n=n0+tn*8+j;
      X[(size_t)m*G4+n]=acc[i][j]+b1[n]+b2[n];
    }
  }
}

// Standalone Xdec (fallback when !dual)
__global__ __launch_bounds__(256) void k_xgemm_mfma(
    const float* __restrict__ emb, const float* __restrict__ Wih,
    const float* __restrict__ b1, const float* __restrict__ b2,
    const int* __restrict__ tok, int M, float* __restrict__ X)
{
  __shared__ ushort As[TBM*TBK];
  __shared__ ushort Bs[TBN*TBK];
  int tid=threadIdx.x;
  int m0=blockIdx.x*TBM, n0=blockIdx.y*TBN;
  int wid=tid>>6, lane=tid&63;
  int wm=wid>>1, wn=wid&1;
  int r15=lane&15, g=lane>>4;
  f32x4 acc[4][4]={};
  int srow=tid>>1, shalf=tid&1;
  int arow=m0+srow;
  int atok=(arow<M)?tok[arow]:0;
  const float* aptr=emb+(size_t)atok*HCd + shalf*16;
  const float* bptr=Wih+(size_t)(n0+srow)*HCd + shalf*16;
  bool aok=arow<M;
  float bj[4];
#pragma unroll
  for(int j=0;j<4;j++){ int n=n0+wn*64+j*16+r15; bj[j]=b1[n]+b2[n]; }
  for(int k0=0;k0<HCd;k0+=TBK){
    float4 va0={0,0,0,0},va1={0,0,0,0},va2={0,0,0,0},va3={0,0,0,0};
    if(aok){
      va0=*(const float4*)(aptr+k0);   va1=*(const float4*)(aptr+k0+4);
      va2=*(const float4*)(aptr+k0+8); va3=*(const float4*)(aptr+k0+12);
    }
    float4 vb0=*(const float4*)(bptr+k0),   vb1=*(const float4*)(bptr+k0+4);
    float4 vb2=*(const float4*)(bptr+k0+8), vb3=*(const float4*)(bptr+k0+12);
    uint4v pa0={pk_bf16(va0.x,va0.y),pk_bf16(va0.z,va0.w),pk_bf16(va1.x,va1.y),pk_bf16(va1.z,va1.w)};
    uint4v pa1={pk_bf16(va2.x,va2.y),pk_bf16(va2.z,va2.w),pk_bf16(va3.x,va3.y),pk_bf16(va3.z,va3.w)};
    uint4v pb0={pk_bf16(vb0.x,vb0.y),pk_bf16(vb0.z,vb0.w),pk_bf16(vb1.x,vb1.y),pk_bf16(vb1.z,vb1.w)};
    uint4v pb1={pk_bf16(vb2.x,vb2.y),pk_bf16(vb2.z,vb2.w),pk_bf16(vb3.x,vb3.y),pk_bf16(vb3.z,vb3.w)};
    int sx=(srow>>1)&3;
    int u0=(shalf*2+0)^sx, u1=(shalf*2+1)^sx;
    *(uint4v*)&As[srow*32+u0*8]=pa0; *(uint4v*)&As[srow*32+u1*8]=pa1;
    *(uint4v*)&Bs[srow*32+u0*8]=pb0; *(uint4v*)&Bs[srow*32+u1*8]=pb1;
    __syncthreads();
    bf16x8 af[4], bf[4];
#pragma unroll
    for(int i=0;i<4;i++){
      int ra=wm*64+i*16+r15;
      af[i]=*(const bf16x8*)&As[ra*32+((g^((ra>>1)&3))<<3)];
      int rb=wn*64+i*16+r15;
      bf[i]=*(const bf16x8*)&Bs[rb*32+((g^((rb>>1)&3))<<3)];
    }
#pragma unroll
    for(int i=0;i<4;i++)
#pragma unroll
      for(int j=0;j<4;j++)
        acc[i][j]=__builtin_amdgcn_mfma_f32_16x16x32_bf16(af[i],bf[j],acc[i][j],0,0,0);
    __syncthreads();
  }
#pragma unroll
  for(int i=0;i<4;i++){
    int grow0=m0+wm*64+i*16+g*4;
#pragma unroll
    for(int j=0;j<4;j++){
      int gcol=n0+wn*64+j*16+r15;
#pragma unroll
      for(int r=0;r<4;r++){
        int grow=grow0+r;
        if(grow<M) X[(size_t)grow*G4+gcol]=acc[i][j][r]+bj[j];
      }
    }
  }
}

// ---------------- Fused: encoder scan (blocks 0..63) + prologue helpers ----------------
__global__ __launch_bounds__(ET,2) void k_encF(
    const float* __restrict__ Xg, const float* __restrict__ Whh,
    unsigned* estate, float* hT, float* cT,
    // helper args:
    const float* __restrict__ dWhh, const float* __restrict__ fhw,
    float* __restrict__ Weff,
    const float* __restrict__ demb, const float* __restrict__ dWih,
    const float* __restrict__ dbih, const float* __restrict__ dbhh,
    const int* __restrict__ tok, float* __restrict__ XB,
    const float* __restrict__ outw, unsigned* __restrict__ wB,
    const float* __restrict__ fhb, const float* __restrict__ dcemb,
    const int* __restrict__ condp, float* __restrict__ cvec,
    int do_xdec, int do_cvtb)
{
  __shared__ SmU sm;
  const int tid=threadIdx.x, lane=tid&63, wv=tid>>6;
  const int bid=blockIdx.x;

  if(bid>=EB){
    // -------- helpers: dconst(16) + weff(256) + xdec(512?) + cvtb(64?) --------
    int cond=condp[0];
    int n_x=do_xdec?512:0, n_c=do_cvtb?64:0;
    int total=16+256+n_x+n_c;
    for(int u=bid-EB; u<total; u+=FGRID-EB){
      if(u<16) dconst_unit(u,dWhh,fhb,dcemb,cond,cvec,tid);
      else if(u<272) weff_unit(u-16,dWhh,fhw,Weff,sm,tid);
      else if(u<272+n_x) xdec_unit(u-272,demb,dWih,dbih,dbhh,tok,XB,sm,tid);
      else cvtb_unit(u-272-n_x,outw,wB,tid);
      __syncthreads();
    }
    return;
  }

  // -------- encoder scan (r6-proven fp32 seqlock) --------
  const int wid=bid*8+wv;
  const int j0=wid*2, j1=j0+1;
  float w[8][16];
#pragma unroll
  for(int q=0;q<4;q++)
#pragma unroll
    for(int jj=0;jj<2;jj++){
      const float* p=Whh+(size_t)(q*HCd+j0+jj)*HCd+lane;
#pragma unroll
      for(int e=0;e<16;e++) w[q*2+jj][e]=p[(size_t)e*64];
    }
  float xg[8];
#pragma unroll
  for(int r=0;r<8;r++) xg[r]=Xg[(r>>1)*HCd+j0+(r&1)];
  float c0=0.f,c1=0.f;
  const int i0=tid*2, i1=i0+1;

  for(int s=1;s<=NSE;s++){
    uint2v v;
    unsigned* src=estate+((s-1)&1)*HCd;
    if(s==1){ v.x=src[i0]; v.y=src[i1]; }
    else{
      const unsigned expp=(unsigned)(((s-1)>>1)&1);
      for(;;){
        v=ld_uc2(src+i0);
        if((((v.x^expp)|(v.y^expp))&1u)==0u) break;
        __builtin_amdgcn_s_sleep(1);
      }
    }
    float* hl=sm.u.hlds[(s-1)&1];
    hl[i0]=__uint_as_float(v.x); hl[i1]=__uint_as_float(v.y);
    __syncthreads();
    if(s==1){ c0=hl[j0]; c1=hl[j1]; }   // h0 == c0
    float hseg[16];
#pragma unroll
    for(int e=0;e<16;e++) hseg[e]=hl[lane+64*e];
    float d[8];
#pragma unroll
    for(int r=0;r<8;r++){ float sacc=0.f;
#pragma unroll
      for(int e=0;e<16;e++) sacc+=w[r][e]*hseg[e];
      d[r]=sacc; }
#pragma unroll
    for(int r=0;r<8;r++) d[r]=redl0(d[r]);
    float gi0=d[0]+xg[0], gi1=d[1]+xg[1];
    float gf0=d[2]+xg[2], gf1=d[3]+xg[3];
    float gg0=d[4]+xg[4], gg1=d[5]+xg[5];
    float go0=d[6]+xg[6], go1=d[7]+xg[7];
    if(s<NSE){
      const float* px=Xg+(size_t)s*G4;
#pragma unroll
      for(int r=0;r<8;r++) xg[r]=px[(r>>1)*HCd+j0+(r&1)];
    }
    c0=sigmoidf_(gf0)*c0+sigmoidf_(gi0)*tanhf(gg0);
    float h0=sigmoidf_(go0)*tanhf(c0);
    c1=sigmoidf_(gf1)*c1+sigmoidf_(gi1)*tanhf(gg1);
    float h1=sigmoidf_(go1)*tanhf(c1);
    unsigned wpar=(unsigned)((s>>1)&1);
    if(lane==0){
      uint2v pk;
      pk.x=(__float_as_uint(h0)&~1u)|wpar;
      pk.y=(__float_as_uint(h1)&~1u)|wpar;
      st_uc2(estate+(s&1)*HCd+j0,pk);
      if(s==NSE){ hT[j0]=h0; hT[j1]=h1; cT[j0]=c0; cT[j1]=c1; }
    }
  }
}

// ---------------- VAE heads (fp32 z vectors) ----------------
__global__ __launch_bounds__(256) void k_head(
    const float* __restrict__ hT, const float* __restrict__ cT,
    const float* __restrict__ mhw, const float* __restrict__ mhb,
    const float* __restrict__ lhw, const float* __restrict__ lhb,
    const float* __restrict__ mcw, const float* __restrict__ mcb,
    const float* __restrict__ lcw, const float* __restrict__ lcb,
    const float* __restrict__ eps_h, const float* __restrict__ eps_c,
    const float* __restrict__ cemb, const int* __restrict__ condp,
    float* zh, float* zc, float* klh, float* klc)
{
  int i=blockIdx.x;
  int tid=threadIdx.x, lane=tid&63, wv=tid>>6;
  __shared__ float sm[4];
  const float* Wm=(wv==0)?mhw:(wv==1)?lhw:(wv==2)?mcw:lcw;
  const float* vec=(wv<2)?hT:cT;
  const float* row=Wm+(size_t)i*HCd;
  float s=0.f;
  for(int k=lane;k<HCd;k+=64) s+=row[k]*vec[k];
  s=wave_reduce(s);
  if(lane==0) sm[wv]=s;
  __syncthreads();
  if(tid==0){
    float mh=sm[0]+mhb[i], lh=sm[1]+lhb[i];
    float mc=sm[2]+mcb[i], lc=sm[3]+lcb[i];
    zh[i]=eps_h[i]*expf(lh*0.5f)+mh;
    zc[i]=eps_c[i]*expf(lc*0.5f)+mc;
    klh[i]=0.5f*(mh*mh+expf(lh)-1.f-lh);
    klc[i]=0.5f*(mc*mc+expf(lc)-1.f-lc);
    if(i<Cc){
      float cd=cemb[condp[0]*Cc+i];
      zh[Hh+i]=cd; zc[Hh+i]=cd;
    }
  }
}

// decoder step 1: writes S1 (fp32, parity 0) into dstate slot1 + Hmat row 0
__global__ __launch_bounds__(256) void k_dec0(
    const float* __restrict__ Xg, const float* __restrict__ WhhO,
    const float* __restrict__ zh, const float* __restrict__ zc,
    unsigned* dstate1, float* Hmat)
{
  int tid=threadIdx.x, lane=tid&63, wv=tid>>6;
  int j=blockIdx.x*4+wv;
  float hseg[16];
#pragma unroll
  for(int e=0;e<16;e++) hseg[e]=zh[lane+64*e];
  float g[4];
#pragma unroll
  for(int q=0;q<4;q++){
    const float* p=WhhO+(size_t)(q*HCd+j)*HCd+lane;
    float s=0.f;
#pragma unroll
    for(int e=0;e<16;e++) s+=p[(size_t)e*64]*hseg[e];
    s=wave_reduce(s);
    g[q]=s+Xg[q*HCd+j];
  }
  float cc=zc[j];
  float cn=sigmoidf_(g[1])*cc+sigmoidf_(g[0])*tanhf(g[2]);
  float hn=sigmoidf_(g[3])*tanhf(cn);
  if(lane==0){
    dstate1[2*j]  =__float_as_uint(hn)&~1u;
    dstate1[2*j+1]=__float_as_uint(cn)&~1u;
    Hmat[j]=hn;
  }
}

// ---------------- Decoder scan (r6-proven fp32 seqlock, 1 ldx4 poll/step) ----------------
__global__ __launch_bounds__(ET,2) void k_dec9(
    const float* __restrict__ Xg, const float* __restrict__ Weff,
    const float* __restrict__ cvec,
    const float* __restrict__ fccw, const float* __restrict__ fccb,
    const float* __restrict__ cemb, const int* __restrict__ condp,
    unsigned* dstate, float* __restrict__ Hmat)
{
  __shared__ float hlds[2][HCd];
  __shared__ float clds[2][HCd];
  const int tid=threadIdx.x, lane=tid&63, wv=tid>>6;
  const int wid=blockIdx.x*8+wv;
  const int j0=wid*2, j1=j0+1;
  float w[8][16];
#pragma unroll
  for(int q=0;q<4;q++)
#pragma unroll
    for(int jj=0;jj<2;jj++){
      const float* p=Weff+(size_t)(q*HCd+j0+jj)*HCd+lane;
#pragma unroll
      for(int e=0;e<16;e++) w[q*2+jj][e]=p[(size_t)e*64];
    }
  const bool hasf=(j0<Hh);
  float fcc0[16], fcc1[16];
  if(hasf){
    const float* p0=fccw+(size_t)j0*HCd+lane;
    const float* p1=fccw+(size_t)j1*HCd+lane;
#pragma unroll
    for(int e=0;e<16;e++){ fcc0[e]=p0[(size_t)e*64]; fcc1[e]=p1[(size_t)e*64]; }
  } else {
#pragma unroll
    for(int e=0;e<16;e++){ fcc0[e]=0.f; fcc1[e]=0.f; }
  }
  float fb0=hasf?fccb[j0]:0.f, fb1=hasf?fccb[j1]:0.f;
  int cond=condp[0];
  float cd0=hasf?0.f:cemb[cond*Cc+(j0-Hh)];
  float cd1=hasf?0.f:cemb[cond*Cc+(j1-Hh)];
  float cv[8];
#pragma unroll
  for(int r=0;r<8;r++) cv[r]=cvec[(r>>1)*HCd+j0+(r&1)];
  float xg[8];
  { const float* px=Xg+(size_t)1*G4;
#pragma unroll
    for(int r=0;r<8;r++) xg[r]=px[(r>>1)*HCd+j0+(r&1)]; }
  const int i0=tid*2, i1=i0+1;

  for(int s=2;s<=NSD;s++){
    uint4v v;
    unsigned* st=dstate+((s-1)&1)*2*HCd;
    if(s==2){ v=*(const uint4v*)(st+4*tid); }   // S_1 from k_dec0
    else{
      const unsigned expp=(unsigned)(((s-1)>>1)&1);
      for(;;){
        v=ld_uc4(st+4*tid);
        if((((v.x^expp)|(v.y^expp)|(v.z^expp)|(v.w^expp))&1u)==0u) break;
        __builtin_amdgcn_s_sleep(1);
      }
    }
    float* hl=hlds[(s-1)&1]; float* cl=clds[(s-1)&1];
    hl[i0]=__uint_as_float(v.x); cl[i0]=__uint_as_float(v.y);
    hl[i1]=__uint_as_float(v.z); cl[i1]=__uint_as_float(v.w);
    __syncthreads();
    float hseg[16], cseg[16];
#pragma unroll
    for(int e=0;e<16;e++){ hseg[e]=hl[lane+64*e]; cseg[e]=cl[lane+64*e]; }
    float d[8]; float s8=0.f, s9=0.f;
#pragma unroll
    for(int r=0;r<8;r++){ float sacc=0.f;
#pragma unroll
      for(int e=0;e<16;e++) sacc+=w[r][e]*hseg[e];
      d[r]=sacc; }
#pragma unroll
    for(int r=0;r<8;r++) d[r]=redl0(d[r]);
    if(hasf){
#pragma unroll
      for(int e=0;e<16;e++){ s8+=fcc0[e]*cseg[e]; s9+=fcc1[e]*cseg[e]; }
      s8=redl0(s8); s9=redl0(s9);
    }
    float gi0=d[0]+xg[0]+cv[0], gi1=d[1]+xg[1]+cv[1];
    float gf0=d[2]+xg[2]+cv[2], gf1=d[3]+xg[3]+cv[3];
    float gg0=d[4]+xg[4]+cv[4], gg1=d[5]+xg[5]+cv[5];
    float go0=d[6]+xg[6]+cv[6], go1=d[7]+xg[7]+cv[7];
    if(s<NSD){
      const float* px=Xg+(size_t)s*G4;
#pragma unroll
      for(int r=0;r<8;r++) xg[r]=px[(r>>1)*HCd+j0+(r&1)];
    }
    float cc0=hasf?(s8+fb0):cd0;
    float cc1=hasf?(s9+fb1):cd1;
    float cn0=sigmoidf_(gf0)*cc0+sigmoidf_(gi0)*tanhf(gg0);
    float hn0=sigmoidf_(go0)*tanhf(cn0);
    float cn1=sigmoidf_(gf1)*cc1+sigmoidf_(gi1)*tanhf(gg1);
    float hn1=sigmoidf_(go1)*tanhf(cn1);
    unsigned wpar=(unsigned)((s>>1)&1);
    if(lane==0){
      uint4v pk;
      pk.x=(__float_as_uint(hn0)&~1u)|wpar;
      pk.y=(__float_as_uint(cn0)&~1u)|wpar;
      pk.z=(__float_as_uint(hn1)&~1u)|wpar;
      pk.w=(__float_as_uint(cn1)&~1u)|wpar;
      st_uc4(dstate+(s&1)*2*HCd+2*j0,pk);
      Hmat[(size_t)(s-1)*HCd+j0]=hn0; Hmat[(size_t)(s-1)*HCd+j1]=hn1;
    }
  }
}

// ---------------- logits GEMM, B pre-converted bf16 ----------------
__global__ __launch_bounds__(256) void k_gemm2(
    const float* __restrict__ A, const ushort* __restrict__ Bb,
    const float* __restrict__ bias, float* __restrict__ Cm, int M)
{
  __shared__ ushort As[TBM*TBK];
  __shared__ ushort Bs[TBN*TBK];
  int tid=threadIdx.x;
  int m0=blockIdx.x*TBM, n0=blockIdx.y*TBN;
  int wid=tid>>6, lane=tid&63;
  int wm=wid>>1, wn=wid&1;
  int r15=lane&15, g=lane>>4;
  f32x4 acc[4][4]={};
  int srow=tid>>1, shalf=tid&1;
  const float*  aptr=A +(size_t)(m0+srow)*HCd + shalf*16;
  const ushort* bptr=Bb+(size_t)(n0+srow)*HCd + shalf*16;
  bool aok=(m0+srow)<M;
  float bj[4];
#pragma unroll
  for(int j=0;j<4;j++) bj[j]=bias[n0+wn*64+j*16+r15];

  for(int k0=0;k0<HCd;k0+=TBK){
    float4 va0={0,0,0,0},va1={0,0,0,0},va2={0,0,0,0},va3={0,0,0,0};
    if(aok){
      va0=*(const float4*)(aptr+k0);   va1=*(const float4*)(aptr+k0+4);
      va2=*(const float4*)(aptr+k0+8); va3=*(const float4*)(aptr+k0+12);
    }
    uint4v qb0=*(const uint4v*)(bptr+k0);
    uint4v qb1=*(const uint4v*)(bptr+k0+8);
    uint4v pa0={pk_bf16(va0.x,va0.y),pk_bf16(va0.z,va0.w),pk_bf16(va1.x,va1.y),pk_bf16(va1.z,va1.w)};
    uint4v pa1={pk_bf16(va2.x,va2.y),pk_bf16(va2.z,va2.w),pk_bf16(va3.x,va3.y),pk_bf16(va3.z,va3.w)};
    int sx=(srow>>1)&3;
    int u0=(shalf*2+0)^sx, u1=(shalf*2+1)^sx;
    *(uint4v*)&As[srow*32+u0*8]=pa0; *(uint4v*)&As[srow*32+u1*8]=pa1;
    *(uint4v*)&Bs[srow*32+u0*8]=qb0; *(uint4v*)&Bs[srow*32+u1*8]=qb1;
    __syncthreads();
    bf16x8 af[4], bf[4];
#pragma unroll
    for(int i=0;i<4;i++){
      int ra=wm*64+i*16+r15;
      af[i]=*(const bf16x8*)&As[ra*32+((g^((ra>>1)&3))<<3)];
      int rb=wn*64+i*16+r15;
      bf[i]=*(const bf16x8*)&Bs[rb*32+((g^((rb>>1)&3))<<3)];
    }
#pragma unroll
    for(int i=0;i<4;i++)
#pragma unroll
      for(int j=0;j<4;j++)
        acc[i][j]=__builtin_amdgcn_mfma_f32_16x16x32_bf16(af[i],bf[j],acc[i][j],0,0,0);
    __syncthreads();
  }
#pragma unroll
  for(int i=0;i<4;i++){
    int grow0=m0+wm*64+i*16+g*4;
#pragma unroll
    for(int j=0;j<4;j++){
      int gcol=n0+wn*64+j*16+r15;
#pragma unroll
      for(int r=0;r<4;r++){
        int grow=grow0+r;
        if(grow<M) Cm[(size_t)grow*VSZ+gcol]=acc[i][j][r]+bj[j];
      }
    }
  }
}

// fallback logits GEMM (in-kernel B conversion)
__global__ __launch_bounds__(256) void k_gemm_mfma(
    const float* __restrict__ A, const float* __restrict__ B,
    const float* __restrict__ bias, float* __restrict__ Cm, int M)
{
  __shared__ ushort As[TBM*TBK];
  __shared__ ushort Bs[TBN*TBK];
  int tid=threadIdx.x;
  int m0=blockIdx.x*TBM, n0=blockIdx.y*TBN;
  int wid=tid>>6, lane=tid&63;
  int wm=wid>>1, wn=wid&1;
  int r15=lane&15, g=lane>>4;
  f32x4 acc[4][4]={};
  int srow=tid>>1, shalf=tid&1;
  const float* aptr=A+(size_t)(m0+srow)*HCd + shalf*16;
  const float* bptr=B+(size_t)(n0+srow)*HCd + shalf*16;
  bool aok=(m0+srow)<M;
  float bj[4];
#pragma unroll
  for(int j=0;j<4;j++) bj[j]=bias[n0+wn*64+j*16+r15];
  for(int k0=0;k0<HCd;k0+=TBK){
    float4 va0={0,0,0,0},va1={0,0,0,0},va2={0,0,0,0},va3={0,0,0,0};
    if(aok){
      va0=*(const float4*)(aptr+k0);   va1=*(const float4*)(aptr+k0+4);
      va2=*(const float4*)(aptr+k0+8); va3=*(const float4*)(aptr+k0+12);
    }
    float4 vb0=*(const float4*)(bptr+k0),   vb1=*(const float4*)(bptr+k0+4);
    float4 vb2=*(const float4*)(bptr+k0+8), vb3=*(const float4*)(bptr+k0+12);
    uint4v pa0={pk_bf16(va0.x,va0.y),pk_bf16(va0.z,va0.w),pk_bf16(va1.x,va1.y),pk_bf16(va1.z,va1.w)};
    uint4v pa1={pk_bf16(va2.x,va2.y),pk_bf16(va2.z,va2.w),pk_bf16(va3.x,va3.y),pk_bf16(va3.z,va3.w)};
    uint4v pb0={pk_bf16(vb0.x,vb0.y),pk_bf16(vb0.z,vb0.w),pk_bf16(vb1.x,vb1.y),pk_bf16(vb1.z,vb1.w)};
    uint4v pb1={pk_bf16(vb2.x,vb2.y),pk_bf16(vb2.z,vb2.w),pk_bf16(vb3.x,vb3.y),pk_bf16(vb3.z,vb3.w)};
    int sx=(srow>>1)&3;
    int u0=(shalf*2+0)^sx, u1=(shalf*2+1)^sx;
    *(uint4v*)&As[srow*32+u0*8]=pa0; *(uint4v*)&As[srow*32+u1*8]=pa1;
    *(uint4v*)&Bs[srow*32+u0*8]=pb0; *(uint4v*)&Bs[srow*32+u1*8]=pb1;
    __syncthreads();
    bf16x8 af[4], bf[4];
#pragma unroll
    for(int i=0;i<4;i++){
      int ra=wm*64+i*16+r15;
      af[i]=*(const bf16x8*)&As[ra*32+((g^((ra>>1)&3))<<3)];
      int rb=wn*64+i*16+r15;
      bf[i]=*(const bf16x8*)&Bs[rb*32+((g^((rb>>1)&3))<<3)];
    }
#pragma unroll
    for(int i=0;i<4;i++)
#pragma unroll
      for(int j=0;j<4;j++)
        acc[i][j]=__builtin_amdgcn_mfma_f32_16x16x32_bf16(af[i],bf[j],acc[i][j],0,0,0);
    __syncthreads();
  }
#pragma unroll
  for(int i=0;i<4;i++){
    int grow0=m0+wm*64+i*16+g*4;
#pragma unroll
    for(int j=0;j<4;j++){
      int gcol=n0+wn*64+j*16+r15;
#pragma unroll
      for(int r=0;r<4;r++){
        int grow=grow0+r;
        if(grow<M) Cm[(size_t)grow*VSZ+gcol]=acc[i][j][r]+bj[j];
      }
    }
  }
}

// per-row cross-entropy, single-pass online softmax
__global__ __launch_bounds__(256) void k_ce(const float* __restrict__ logits,
    const int* __restrict__ tok, int base, float* __restrict__ ce)
{
  int r=blockIdx.x;
  const float* row=logits+(size_t)r*VSZ;
  int tid=threadIdx.x, lane=tid&63, wv=tid>>6;
  float m=-1e30f, s=0.f;
  for(int i=tid;i<VSZ;i+=256){
    float v=row[i];
    if(v>m){ s=s*__expf(m-v)+1.f; m=v; }
    else s+=__expf(v-m);
  }
#pragma unroll
  for(int o=32;o;o>>=1){
    float mo=__shfl_xor(m,o,64), so=__shfl_xor(s,o,64);
    float mn=fmaxf(m,mo);
    s=s*__expf(m-mn)+so*__expf(mo-mn);
    m=mn;
  }
  __shared__ float smm[4], sms[4];
  if(lane==0){ smm[wv]=m; sms[wv]=s; }
  __syncthreads();
  if(tid==0){
    float M2=fmaxf(fmaxf(smm[0],smm[1]),fmaxf(smm[2],smm[3]));
    float S2=sms[0]*__expf(smm[0]-M2)+sms[1]*__expf(smm[1]-M2)
            +sms[2]*__expf(smm[2]-M2)+sms[3]*__expf(smm[3]-M2);
    int tgt=tok[base+r+1];
    ce[base+r]=M2+logf(S2)-row[tgt];
  }
}

__global__ __launch_bounds__(256) void k_final(const float* __restrict__ ce,
    const float* __restrict__ klh, const float* __restrict__ klc,
    const float* __restrict__ kldw, float* __restrict__ outp)
{
  int tid=threadIdx.x, lane=tid&63, wv=tid>>6;
  float s0=0,s1=0,s2=0;
  for(int i=tid;i<NSD;i+=256) s0+=ce[i];
  for(int i=tid;i<Hh;i+=256){ s1+=klh[i]; s2+=klc[i]; }
  s0=wave_reduce(s0); s1=wave_reduce(s1); s2=wave_reduce(s2);
  __shared__ float sm[3][4];
  if(lane==0){ sm[0][wv]=s0; sm[1][wv]=s1; sm[2][wv]=s2; }
  __syncthreads();
  if(tid==0){
    float ces=sm[0][0]+sm[0][1]+sm[0][2]+sm[0][3];
    float kh =sm[1][0]+sm[1][1]+sm[1][2]+sm[1][3];
    float kc =sm[2][0]+sm[2][1]+sm[2][2]+sm[2][3];
    float rec=ces/(float)NSD;
    outp[0]=rec+(kh+kc)*kldw[0];
    outp[1]=rec; outp[2]=kh; outp[3]=kc;
  }
}

extern "C" void kernel_launch(void* const* d_in, const int* in_sizes, int n_in,
                              void* d_out, int out_size, void* d_ws, size_t ws_size,
                              hipStream_t stream) {
  const int*   tok   =(const int*)  d_in[0];
  const int*   cond  =(const int*)  d_in[1];
  const float* eps_h =(const float*)d_in[2];
  const float* eps_c =(const float*)d_in[3];
  const float* kldw  =(const float*)d_in[4];
  const float* enc_embed=(const float*)d_in[5];
  const float* enc_cemb =(const float*)d_in[6];
  const float* enc_Wih  =(const float*)d_in[7];
  const float* enc_Whh  =(const float*)d_in[8];
  const float* enc_bih  =(const float*)d_in[9];
  const float* enc_bhh  =(const float*)d_in[10];
  const float* fc_mh_w=(const float*)d_in[11];
  const float* fc_mh_b=(const float*)d_in[12];
  const float* fc_lh_w=(const float*)d_in[13];
  const float* fc_lh_b=(const float*)d_in[14];
  const float* fc_mc_w=(const float*)d_in[15];
  const float* fc_mc_b=(const float*)d_in[16];
  const float* fc_lc_w=(const float*)d_in[17];
  const float* fc_lc_b=(const float*)d_in[18];
  const float* dec_embed=(const float*)d_in[19];
  const float* dec_cemb =(const float*)d_in[20];
  const float* dec_Wih  =(const float*)d_in[21];
  const float* dec_Whh  =(const float*)d_in[22];
  const float* dec_bih  =(const float*)d_in[23];
  const float* dec_bhh  =(const float*)d_in[24];
  const float* fc_h_w=(const float*)d_in[25];
  const float* fc_h_b=(const float*)d_in[26];
  const float* fc_c_w=(const float*)d_in[27];
  const float* fc_c_b=(const float*)d_in[28];
  const float* out_w=(const float*)d_in[29];
  const float* out_b=(const float*)d_in[30];

  float* ws=(float*)d_ws;
  size_t off=0;
  unsigned* estate=(unsigned*)(ws+off); off+=2*HCd;   // fp32 h, 2 slots
  unsigned* dstate=(unsigned*)(ws+off); off+=4*HCd;   // fp32 (h,c) pairs, 2 slots
  float* cvec=ws+off; off+=G4;
  float* Weff=ws+off; off+=(size_t)G4*HCd;
  float* hT  =ws+off; off+=HCd;
  float* cT  =ws+off; off+=HCd;
  float* zh  =ws+off; off+=HCd;
  float* zc  =ws+off; off+=HCd;
  float* klh =ws+off; off+=Hh;
  float* klc =ws+off; off+=Hh;
  float* Hmat=ws+off; off+=(size_t)NSD*HCd;
  float* ce  =ws+off; off+=2048;
  size_t avail=ws_size/4;
  size_t xa_sz=(size_t)NSE*G4, xb_sz=(size_t)NSD*G4;
  size_t wb_sz=(size_t)VSZ*HCd/2;              // bf16 out_w, in float slots
  float* XA=ws+off;
  bool dual=(off+xa_sz+xb_sz)<=avail;
  float* XB=dual?(XA+xa_sz):XA;
  bool wbok=dual && (off+xa_sz+xb_sz+wb_sz)<=avail;
  unsigned* wB=(unsigned*)(XB+xb_sz);
  size_t region=(avail>off)?(avail-off):0;
  int chunk;
  if(dual){
    chunk=(int)((xa_sz+xb_sz)/(size_t)VSZ); if(chunk>512)chunk=512;  // lbuf spans XA+XB
  } else {
    chunk=256;
    if((size_t)chunk*VSZ>region){ chunk=(int)(region/(size_t)VSZ); if(chunk<1)chunk=1; }
  }
  float* lbuf=XA;

  k_init9<<<1,256,0,stream>>>(estate,dstate,enc_cemb,cond);
  { dim3 g((NSE+GBM-1)/GBM, G4/GBN);           // Xenc (fp32) — scan dependency
    k_xgemm<<<g,256,0,stream>>>(enc_embed,enc_Wih,enc_bih,enc_bhh,tok,1,NSE,XA); }
  // fused: encoder scan + {dconst, weff, Xdec, cvtB} helpers
  k_encF<<<FGRID,ET,0,stream>>>(XA,enc_Whh,estate,hT,cT,
                                dec_Whh,fc_h_w,Weff,
                                dec_embed,dec_Wih,dec_bih,dec_bhh,tok,XB,
                                out_w,wB,fc_h_b,dec_cemb,cond,cvec,
                                dual?1:0, wbok?1:0);
  k_head<<<Hh,256,0,stream>>>(hT,cT,fc_mh_w,fc_mh_b,fc_lh_w,fc_lh_b,
                              fc_mc_w,fc_mc_b,fc_lc_w,fc_lc_b,
                              eps_h,eps_c,dec_cemb,cond,zh,zc,klh,klc);
  if(!dual){
    dim3 g((NSD+TBM-1)/TBM, G4/TBN);           // Xdec overwrites XA (encoder done)
    k_xgemm_mfma<<<g,256,0,stream>>>(dec_embed,dec_Wih,dec_bih,dec_bhh,tok,NSD,XB);
  }
  k_dec0<<<256,256,0,stream>>>(XB,dec_Whh,zh,zc,dstate+2*HCd,Hmat);
  k_dec9<<<EB,ET,0,stream>>>(XB,Weff,cvec,fc_c_w,fc_c_b,dec_cemb,cond,dstate,Hmat);
  for(int base=0;base<NSD;base+=chunk){        // lbuf overlays XA(+XB) — scans done
    int rows=NSD-base; if(rows>chunk) rows=chunk;
    dim3 g((rows+TBM-1)/TBM, VSZ/TBN);
    if(wbok) k_gemm2<<<g,256,0,stream>>>(Hmat+(size_t)base*HCd,(const ushort*)wB,out_b,lbuf,rows);
    else     k_gemm_mfma<<<g,256,0,stream>>>(Hmat+(size_t)base*HCd,out_w,out_b,lbuf,rows);
    k_ce<<<rows,256,0,stream>>>(lbuf,tok,base,ce);
  }
  k_final<<<1,256,0,stream>>>(ce,klh,klc,kldw,(float*)d_out);
}

// Round 11
// 13422.299 us; speedup vs baseline: 1.1009x; 1.0078x over previous
//
#include <hip/hip_runtime.h>
#include <math.h>

// Problem sizes (fixed)
#define VSZ 32000
#define Hh  768
#define Cc  256
#define HCd 1024
#define G4  4096
#define NSE 2046   // encoder steps
#define NSD 2047   // decoder steps

// Scan: 64 blocks x 512 threads (8 waves) = 512 waves, 2 outputs/wave.
#define EB 64
#define ET 512
// Fused encoder: 64 scan blocks + 192 prologue helper blocks (independent work).
#define FGRID 256

typedef __attribute__((ext_vector_type(4))) unsigned uint4v;
typedef __attribute__((ext_vector_type(2))) unsigned uint2v;
typedef __attribute__((ext_vector_type(8))) short bf16x8;
typedef __attribute__((ext_vector_type(4))) float f32x4;

__device__ __forceinline__ float sigmoidf_(float x){ return 1.0f/(1.0f+expf(-x)); }

__device__ __forceinline__ float wave_reduce(float v){
#pragma unroll
  for(int o=32;o;o>>=1) v += __shfl_xor(v,o,64);
  return v;
}
// Reduce 64 lanes; total valid in lane 0.
__device__ __forceinline__ float redl0(float v){
  int x;
  x=__builtin_amdgcn_update_dpp(0,__float_as_int(v),0xB1,0xf,0xf,true); v+=__int_as_float(x); // ^1
  x=__builtin_amdgcn_update_dpp(0,__float_as_int(v),0x4E,0xf,0xf,true); v+=__int_as_float(x); // ^2
  v+=__int_as_float(__builtin_amdgcn_ds_swizzle(__float_as_int(v),0x101F)); // ^4
  v+=__int_as_float(__builtin_amdgcn_ds_swizzle(__float_as_int(v),0x201F)); // ^8
  v+=__int_as_float(__builtin_amdgcn_ds_swizzle(__float_as_int(v),0x401F)); // ^16
  v+=__int_as_float(__builtin_amdgcn_readlane(__float_as_int(v),32));
  return v;
}

// Device-scope (coherence-point) ops. Per-dword LSB parity self-validates.
__device__ __forceinline__ uint2v ld_uc2(const unsigned* p){
  uint2v r;
  asm volatile("global_load_dwordx2 %0, %1, off sc0 sc1\n\ts_waitcnt vmcnt(0)"
               : "=v"(r) : "v"(p) : "memory");
  return r;
}
__device__ __forceinline__ uint4v ld_uc4(const unsigned* p){
  uint4v r;
  asm volatile("global_load_dwordx4 %0, %1, off sc0 sc1\n\ts_waitcnt vmcnt(0)"
               : "=v"(r) : "v"(p) : "memory");
  return r;
}
__device__ __forceinline__ void st_uc2(unsigned* p, uint2v v){
  asm volatile("global_store_dwordx2 %0, %1, off sc0 sc1" :: "v"(p), "v"(v) : "memory");
}
__device__ __forceinline__ void st_uc4(unsigned* p, uint4v v){
  asm volatile("global_store_dwordx4 %0, %1, off sc0 sc1" :: "v"(p), "v"(v) : "memory");
}

// fp32->bf16 RNE, pack two per dword; unpack halves
__device__ __forceinline__ unsigned pk_bf16(float a, float b){
  unsigned ua=__float_as_uint(a); ua += 0x7fffu + ((ua>>16)&1u);
  unsigned ub=__float_as_uint(b); ub += 0x7fffu + ((ub>>16)&1u);
  return (ua>>16) | (ub & 0xffff0000u);
}
__device__ __forceinline__ float bf_lo(unsigned u){ return __uint_as_float(u<<16); }
__device__ __forceinline__ float bf_hi(unsigned u){ return __uint_as_float(u&0xffff0000u); }

// init (re-runs every replay): enc S0 slot0 parity0, slot1 parity1-stale;
// dec slot0 zeroed (parity0 = invalid for its first poll, which expects 1).
__global__ void k_init9(unsigned* estate, unsigned* dstate,
                        const float* __restrict__ cemb, const int* __restrict__ condp){
  int tid=threadIdx.x;
  int cond=condp[0];
  for(int i=tid;i<HCd;i+=256){
    float v=(i<Hh)?0.f:cemb[cond*Cc+(i-Hh)];
    estate[i]=__float_as_uint(v)&~1u;
    estate[HCd+i]=1u;
  }
  for(int i=tid;i<2*HCd;i+=256) dstate[i]=0u;   // slot0 stale
}

#define GBM 128
#define GBN 128
#define GBK 16
#define TBM 128
#define TBN 128
#define TBK 32

// Shared-memory union for the fused encoder kernel.
struct SmU {
  union {
    float hlds[2][HCd];                                        // scan: 8KB
    struct { float As[GBK][GBM]; float Bs[GBK][GBN]; } wf;     // weff: 16KB
    struct { ushort As[TBM*TBK]; ushort Bs[TBN*TBK]; } xd;     // xdec: 16KB
  } u;
};

// ---- helper units (run inside k_encF on blocks 64..255) ----
__device__ void weff_unit(int u, const float* __restrict__ A,
    const float* __restrict__ B, float* __restrict__ Cm, SmU& sm, int tid){
  int m0=(u>>3)*GBM, n0=(u&7)*GBN;
  int tm=tid>>4, tn=tid&15;
  float acc[8][8]={};
  for(int k0=0;k0<Hh;k0+=GBK){
    if(tid<256){
#pragma unroll
      for(int uu=0;uu<2;uu++){
        int idx=tid*2+uu;
        int row=idx>>2, q=idx&3;
        float4 v=*(const float4*)(A+(size_t)(m0+row)*HCd + k0+q*4);
        sm.u.wf.As[q*4+0][row]=v.x; sm.u.wf.As[q*4+1][row]=v.y;
        sm.u.wf.As[q*4+2][row]=v.z; sm.u.wf.As[q*4+3][row]=v.w;
        int kk=idx>>5, nc=idx&31;
        float4 w=*(const float4*)(B+(size_t)(k0+kk)*HCd + n0+nc*4);
        *(float4*)&sm.u.wf.Bs[kk][nc*4]=w;
      }
    }
    __syncthreads();
    if(tid<256){
#pragma unroll
      for(int kk=0;kk<GBK;kk++){
        float a[8],b[8];
        *(float4*)&a[0]=*(float4*)&sm.u.wf.As[kk][tm*8]; *(float4*)&a[4]=*(float4*)&sm.u.wf.As[kk][tm*8+4];
        *(float4*)&b[0]=*(float4*)&sm.u.wf.Bs[kk][tn*8]; *(float4*)&b[4]=*(float4*)&sm.u.wf.Bs[kk][tn*8+4];
#pragma unroll
        for(int i=0;i<8;i++)
#pragma unroll
          for(int j=0;j<8;j++) acc[i][j]+=a[i]*b[j];
      }
    }
    __syncthreads();
  }
  if(tid<256){
#pragma unroll
    for(int i=0;i<8;i++)
#pragma unroll
      for(int j=0;j<8;j++)
        Cm[(size_t)(m0+tm*8+i)*HCd + n0+tn*8+j]=acc[i][j];
  }
}

__device__ void xdec_unit(int q, const float* __restrict__ emb,
    const float* __restrict__ Wih, const float* __restrict__ b1,
    const float* __restrict__ b2, const int* __restrict__ tok,
    float* __restrict__ X, SmU& sm, int tid){
  int m0=(q>>5)*TBM, n0=(q&31)*TBN;
  int wid=tid>>6, lane=tid&63;
  int wm=wid>>1, wn=wid&1;
  int r15=lane&15, g=lane>>4;
  f32x4 acc[4][4]={};
  int srow=tid>>1, shalf=tid&1;
  int arow=m0+srow;
  bool act=(tid<256);
  int atok=(act&&arow<NSD)?tok[arow]:0;
  const float* aptr=emb+(size_t)atok*HCd + shalf*16;
  const float* bptr=Wih+(size_t)(n0+srow)*HCd + shalf*16;
  bool aok=act&&(arow<NSD);
  float bj[4];
  if(act){
#pragma unroll
    for(int j=0;j<4;j++){ int n=n0+wn*64+j*16+r15; bj[j]=b1[n]+b2[n]; }
  }
  for(int k0=0;k0<HCd;k0+=TBK){
    if(act){
      float4 va0={0,0,0,0},va1={0,0,0,0},va2={0,0,0,0},va3={0,0,0,0};
      if(aok){
        va0=*(const float4*)(aptr+k0);   va1=*(const float4*)(aptr+k0+4);
        va2=*(const float4*)(aptr+k0+8); va3=*(const float4*)(aptr+k0+12);
      }
      float4 vb0=*(const float4*)(bptr+k0),   vb1=*(const float4*)(bptr+k0+4);
      float4 vb2=*(const float4*)(bptr+k0+8), vb3=*(const float4*)(bptr+k0+12);
      uint4v pa0={pk_bf16(va0.x,va0.y),pk_bf16(va0.z,va0.w),pk_bf16(va1.x,va1.y),pk_bf16(va1.z,va1.w)};
      uint4v pa1={pk_bf16(va2.x,va2.y),pk_bf16(va2.z,va2.w),pk_bf16(va3.x,va3.y),pk_bf16(va3.z,va3.w)};
      uint4v pb0={pk_bf16(vb0.x,vb0.y),pk_bf16(vb0.z,vb0.w),pk_bf16(vb1.x,vb1.y),pk_bf16(vb1.z,vb1.w)};
      uint4v pb1={pk_bf16(vb2.x,vb2.y),pk_bf16(vb2.z,vb2.w),pk_bf16(vb3.x,vb3.y),pk_bf16(vb3.z,vb3.w)};
      int sx=(srow>>1)&3;
      int u0=(shalf*2+0)^sx, u1=(shalf*2+1)^sx;
      *(uint4v*)&sm.u.xd.As[srow*32+u0*8]=pa0; *(uint4v*)&sm.u.xd.As[srow*32+u1*8]=pa1;
      *(uint4v*)&sm.u.xd.Bs[srow*32+u0*8]=pb0; *(uint4v*)&sm.u.xd.Bs[srow*32+u1*8]=pb1;
    }
    __syncthreads();
    if(act){
      bf16x8 af[4], bf[4];
#pragma unroll
      for(int i=0;i<4;i++){
        int ra=wm*64+i*16+r15;
        af[i]=*(const bf16x8*)&sm.u.xd.As[ra*32+((g^((ra>>1)&3))<<3)];
        int rb=wn*64+i*16+r15;
        bf[i]=*(const bf16x8*)&sm.u.xd.Bs[rb*32+((g^((rb>>1)&3))<<3)];
      }
#pragma unroll
      for(int i=0;i<4;i++)
#pragma unroll
        for(int j=0;j<4;j++)
          acc[i][j]=__builtin_amdgcn_mfma_f32_16x16x32_bf16(af[i],bf[j],acc[i][j],0,0,0);
    }
    __syncthreads();
  }
  if(act){
#pragma unroll
    for(int i=0;i<4;i++){
      int grow0=m0+wm*64+i*16+g*4;
#pragma unroll
      for(int j=0;j<4;j++){
        int gcol=n0+wn*64+j*16+r15;
#pragma unroll
        for(int r=0;r<4;r++){
          int grow=grow0+r;
          if(grow<NSD) X[(size_t)grow*G4+gcol]=acc[i][j][r]+bj[j];
        }
      }
    }
  }
}

__device__ void cvtb_unit(int i, const float* __restrict__ B,
    unsigned* __restrict__ Bb, int tid){
  size_t base=(size_t)i*128000u;
  for(size_t x=base+tid; x<base+128000u; x+=ET){
    float4 v=*(const float4*)(B+x*4);
    Bb[x*2]  =pk_bf16(v.x,v.y);
    Bb[x*2+1]=pk_bf16(v.z,v.w);
  }
}

__device__ void dconst_unit(int i, const float* __restrict__ Whh,
    const float* __restrict__ fhb, const float* __restrict__ cemb,
    int cond, float* __restrict__ cvec, int tid){
  int lane=tid&63, wv=tid>>6;
  for(int r=i*256+wv; r<i*256+256; r+=8){
    const float* row=Whh+(size_t)r*HCd;
    float s=0.f;
    for(int k=lane;k<Hh;k+=64) s+=row[k]*fhb[k];
    for(int k=lane;k<Cc;k+=64) s+=row[Hh+k]*cemb[cond*Cc+k];
    s=wave_reduce(s);
    if(lane==0) cvec[r]=s;
  }
}

// Encoder X (fp32 tile GEMM — kl precision headroom is thin)
__global__ __launch_bounds__(256) void k_xgemm(
    const float* __restrict__ emb, const float* __restrict__ Wih,
    const float* __restrict__ b1, const float* __restrict__ b2,
    const int* __restrict__ tok, int tshift, int M,
    float* __restrict__ X)
{
  __shared__ float As[GBK][GBM];
  __shared__ float Bs[GBK][GBN];
  int tid=threadIdx.x;
  int m0=blockIdx.x*GBM, n0=blockIdx.y*GBN;
  int tm=tid>>4, tn=tid&15;
  int arow=m0+(tid>>1);
  int atok=(arow<M)?tok[arow+tshift]:0;
  const float* abase=emb+(size_t)atok*HCd+(tid&1)*8;
  const float* bbase=Wih+(size_t)(n0+(tid>>1))*HCd+(tid&1)*8;
  int srow=tid>>1;
  float acc[8][8]={};
  for(int k0=0;k0<HCd;k0+=GBK){
#pragma unroll
    for(int u=0;u<2;u++){
      int q=2*(tid&1)+u;
      float4 v={0,0,0,0};
      if(arow<M) v=*(const float4*)(abase+k0+u*4);
      As[q*4+0][srow]=v.x; As[q*4+1][srow]=v.y; As[q*4+2][srow]=v.z; As[q*4+3][srow]=v.w;
      float4 w=*(const float4*)(bbase+k0+u*4);
      Bs[q*4+0][srow]=w.x; Bs[q*4+1][srow]=w.y; Bs[q*4+2][srow]=w.z; Bs[q*4+3][srow]=w.w;
    }
    __syncthreads();
#pragma unroll
    for(int kk=0;kk<GBK;kk++){
      float a[8],b[8];
      *(float4*)&a[0]=*(float4*)&As[kk][tm*8]; *(float4*)&a[4]=*(float4*)&As[kk][tm*8+4];
      *(float4*)&b[0]=*(float4*)&Bs[kk][tn*8]; *(float4*)&b[4]=*(float4*)&Bs[kk][tn*8+4];
#pragma unroll
      for(int i=0;i<8;i++)
#pragma unroll
        for(int j=0;j<8;j++) acc[i][j]+=a[i]*b[j];
    }
    __syncthreads();
  }
#pragma unroll
  for(int i=0;i<8;i++){
    int m=m0+tm*8+i; if(m>=M) continue;
#pragma unroll
    for(int j=0;j<8;j++){
      int n=n0+tn*8+j;
      X[(size_t)m*G4+n]=acc[i][j]+b1[n]+b2[n];
    }
  }
}

// Standalone Xdec (fallback when !dual)
__global__ __launch_bounds__(256) void k_xgemm_mfma(
    const float* __restrict__ emb, const float* __restrict__ Wih,
    const float* __restrict__ b1, const float* __restrict__ b2,
    const int* __restrict__ tok, int M, float* __restrict__ X)
{
  __shared__ ushort As[TBM*TBK];
  __shared__ ushort Bs[TBN*TBK];
  int tid=threadIdx.x;
  int m0=blockIdx.x*TBM, n0=blockIdx.y*TBN;
  int wid=tid>>6, lane=tid&63;
  int wm=wid>>1, wn=wid&1;
  int r15=lane&15, g=lane>>4;
  f32x4 acc[4][4]={};
  int srow=tid>>1, shalf=tid&1;
  int arow=m0+srow;
  int atok=(arow<M)?tok[arow]:0;
  const float* aptr=emb+(size_t)atok*HCd + shalf*16;
  const float* bptr=Wih+(size_t)(n0+srow)*HCd + shalf*16;
  bool aok=arow<M;
  float bj[4];
#pragma unroll
  for(int j=0;j<4;j++){ int n=n0+wn*64+j*16+r15; bj[j]=b1[n]+b2[n]; }
  for(int k0=0;k0<HCd;k0+=TBK){
    float4 va0={0,0,0,0},va1={0,0,0,0},va2={0,0,0,0},va3={0,0,0,0};
    if(aok){
      va0=*(const float4*)(aptr+k0);   va1=*(const float4*)(aptr+k0+4);
      va2=*(const float4*)(aptr+k0+8); va3=*(const float4*)(aptr+k0+12);
    }
    float4 vb0=*(const float4*)(bptr+k0),   vb1=*(const float4*)(bptr+k0+4);
    float4 vb2=*(const float4*)(bptr+k0+8), vb3=*(const float4*)(bptr+k0+12);
    uint4v pa0={pk_bf16(va0.x,va0.y),pk_bf16(va0.z,va0.w),pk_bf16(va1.x,va1.y),pk_bf16(va1.z,va1.w)};
    uint4v pa1={pk_bf16(va2.x,va2.y),pk_bf16(va2.z,va2.w),pk_bf16(va3.x,va3.y),pk_bf16(va3.z,va3.w)};
    uint4v pb0={pk_bf16(vb0.x,vb0.y),pk_bf16(vb0.z,vb0.w),pk_bf16(vb1.x,vb1.y),pk_bf16(vb1.z,vb1.w)};
    uint4v pb1={pk_bf16(vb2.x,vb2.y),pk_bf16(vb2.z,vb2.w),pk_bf16(vb3.x,vb3.y),pk_bf16(vb3.z,vb3.w)};
    int sx=(srow>>1)&3;
    int u0=(shalf*2+0)^sx, u1=(shalf*2+1)^sx;
    *(uint4v*)&As[srow*32+u0*8]=pa0; *(uint4v*)&As[srow*32+u1*8]=pa1;
    *(uint4v*)&Bs[srow*32+u0*8]=pb0; *(uint4v*)&Bs[srow*32+u1*8]=pb1;
    __syncthreads();
    bf16x8 af[4], bf[4];
#pragma unroll
    for(int i=0;i<4;i++){
      int ra=wm*64+i*16+r15;
      af[i]=*(const bf16x8*)&As[ra*32+((g^((ra>>1)&3))<<3)];
      int rb=wn*64+i*16+r15;
      bf[i]=*(const bf16x8*)&Bs[rb*32+((g^((rb>>1)&3))<<3)];
    }
#pragma unroll
    for(int i=0;i<4;i++)
#pragma unroll
      for(int j=0;j<4;j++)
        acc[i][j]=__builtin_amdgcn_mfma_f32_16x16x32_bf16(af[i],bf[j],acc[i][j],0,0,0);
    __syncthreads();
  }
#pragma unroll
  for(int i=0;i<4;i++){
    int grow0=m0+wm*64+i*16+g*4;
#pragma unroll
    for(int j=0;j<4;j++){
      int gcol=n0+wn*64+j*16+r15;
#pragma unroll
      for(int r=0;r<4;r++){
        int grow=grow0+r;
        if(grow<M) X[(size_t)grow*G4+gcol]=acc[i][j][r]+bj[j];
      }
    }
  }
}

// ---------------- Fused: encoder scan (blocks 0..63, REGISTER-RESIDENT bf16 weights)
//                  + prologue helpers (blocks 64..255) ----------------
__global__ __launch_bounds__(ET,2) void k_encF(
    const float* __restrict__ Xg, const float* __restrict__ Whh,
    unsigned* estate, float* hT, float* cT,
    const float* __restrict__ dWhh, const float* __restrict__ fhw,
    float* __restrict__ Weff,
    const float* __restrict__ demb, const float* __restrict__ dWih,
    const float* __restrict__ dbih, const float* __restrict__ dbhh,
    const int* __restrict__ tok, float* __restrict__ XB,
    const float* __restrict__ outw, unsigned* __restrict__ wB,
    const float* __restrict__ fhb, const float* __restrict__ dcemb,
    const int* __restrict__ condp, float* __restrict__ cvec,
    int do_xdec, int do_cvtb)
{
  __shared__ SmU sm;
  const int tid=threadIdx.x, lane=tid&63, wv=tid>>6;
  const int bid=blockIdx.x;

  if(bid>=EB){
    int cond=condp[0];
    int n_x=do_xdec?512:0, n_c=do_cvtb?64:0;
    int total=16+256+n_x+n_c;
    for(int u=bid-EB; u<total; u+=FGRID-EB){
      if(u<16) dconst_unit(u,dWhh,fhb,dcemb,cond,cvec,tid);
      else if(u<272) weff_unit(u-16,dWhh,fhw,Weff,sm,tid);
      else if(u<272+n_x) xdec_unit(u-272,demb,dWih,dbih,dbhh,tok,XB,sm,tid);
      else cvtb_unit(u-272-n_x,outw,wB,tid);
      __syncthreads();
    }
    return;
  }

  // -------- encoder scan --------
  const int wid=bid*8+wv;
  const int j0=wid*2, j1=j0+1;
  // Load recurrent weights once, pack bf16 2/dword, pin in VGPRs via asm.
  uint4v wp[8][2];
#pragma unroll
  for(int q=0;q<4;q++)
#pragma unroll
    for(int jj=0;jj<2;jj++){
      const float* p=Whh+(size_t)(q*HCd+j0+jj)*HCd+lane;
      float t[16];
#pragma unroll
      for(int e=0;e<16;e++) t[e]=p[(size_t)e*64];
      int r=q*2+jj;
      wp[r][0]=(uint4v){pk_bf16(t[0],t[1]),pk_bf16(t[2],t[3]),pk_bf16(t[4],t[5]),pk_bf16(t[6],t[7])};
      wp[r][1]=(uint4v){pk_bf16(t[8],t[9]),pk_bf16(t[10],t[11]),pk_bf16(t[12],t[13]),pk_bf16(t[14],t[15])};
    }
#pragma unroll
  for(int r=0;r<8;r++) asm volatile("" : "+v"(wp[r][0]), "+v"(wp[r][1]));

  float xg[8];
#pragma unroll
  for(int r=0;r<8;r++) xg[r]=Xg[(r>>1)*HCd+j0+(r&1)];
  float c0=0.f,c1=0.f;
  const int i0=tid*2, i1=i0+1;

  for(int s=1;s<=NSE;s++){
    uint2v v;
    unsigned* src=estate+((s-1)&1)*HCd;
    if(s==1){ v.x=src[i0]; v.y=src[i1]; }
    else{
      const unsigned expp=(unsigned)(((s-1)>>1)&1);
      for(;;){
        v=ld_uc2(src+i0);
        if((((v.x^expp)|(v.y^expp))&1u)==0u) break;
        __builtin_amdgcn_s_sleep(1);
      }
    }
    float* hl=sm.u.hlds[(s-1)&1];
    hl[i0]=__uint_as_float(v.x); hl[i1]=__uint_as_float(v.y);
    __syncthreads();
    if(s==1){ c0=hl[j0]; c1=hl[j1]; }   // h0 == c0
    float hseg[16];
#pragma unroll
    for(int e=0;e<16;e++) hseg[e]=hl[lane+64*e];
    float d[8];
#pragma unroll
    for(int r=0;r<8;r++){ float sacc=0.f;
#pragma unroll
      for(int d0=0;d0<8;d0++){
        unsigned u=wp[r][d0>>2][d0&3];
        sacc += bf_lo(u)*hseg[2*d0] + bf_hi(u)*hseg[2*d0+1];
      }
      d[r]=sacc; }
#pragma unroll
    for(int r=0;r<8;r++) d[r]=redl0(d[r]);
    float gi0=d[0]+xg[0], gi1=d[1]+xg[1];
    float gf0=d[2]+xg[2], gf1=d[3]+xg[3];
    float gg0=d[4]+xg[4], gg1=d[5]+xg[5];
    float go0=d[6]+xg[6], go1=d[7]+xg[7];
    if(s<NSE){
      const float* px=Xg+(size_t)s*G4;
#pragma unroll
      for(int r=0;r<8;r++) xg[r]=px[(r>>1)*HCd+j0+(r&1)];
    }
    c0=sigmoidf_(gf0)*c0+sigmoidf_(gi0)*tanhf(gg0);
    float h0=sigmoidf_(go0)*tanhf(c0);
    c1=sigmoidf_(gf1)*c1+sigmoidf_(gi1)*tanhf(gg1);
    float h1=sigmoidf_(go1)*tanhf(c1);
    unsigned wpar=(unsigned)((s>>1)&1);
    if(lane==0){
      uint2v pk;
      pk.x=(__float_as_uint(h0)&~1u)|wpar;
      pk.y=(__float_as_uint(h1)&~1u)|wpar;
      st_uc2(estate+(s&1)*HCd+j0,pk);
      if(s==NSE){ hT[j0]=h0; hT[j1]=h1; cT[j0]=c0; cT[j1]=c1; }
    }
  }
}

// ---------------- VAE heads (fp32 z vectors) ----------------
__global__ __launch_bounds__(256) void k_head(
    const float* __restrict__ hT, const float* __restrict__ cT,
    const float* __restrict__ mhw, const float* __restrict__ mhb,
    const float* __restrict__ lhw, const float* __restrict__ lhb,
    const float* __restrict__ mcw, const float* __restrict__ mcb,
    const float* __restrict__ lcw, const float* __restrict__ lcb,
    const float* __restrict__ eps_h, const float* __restrict__ eps_c,
    const float* __restrict__ cemb, const int* __restrict__ condp,
    float* zh, float* zc, float* klh, float* klc)
{
  int i=blockIdx.x;
  int tid=threadIdx.x, lane=tid&63, wv=tid>>6;
  __shared__ float sm[4];
  const float* Wm=(wv==0)?mhw:(wv==1)?lhw:(wv==2)?mcw:lcw;
  const float* vec=(wv<2)?hT:cT;
  const float* row=Wm+(size_t)i*HCd;
  float s=0.f;
  for(int k=lane;k<HCd;k+=64) s+=row[k]*vec[k];
  s=wave_reduce(s);
  if(lane==0) sm[wv]=s;
  __syncthreads();
  if(tid==0){
    float mh=sm[0]+mhb[i], lh=sm[1]+lhb[i];
    float mc=sm[2]+mcb[i], lc=sm[3]+lcb[i];
    zh[i]=eps_h[i]*expf(lh*0.5f)+mh;
    zc[i]=eps_c[i]*expf(lc*0.5f)+mc;
    klh[i]=0.5f*(mh*mh+expf(lh)-1.f-lh);
    klc[i]=0.5f*(mc*mc+expf(lc)-1.f-lc);
    if(i<Cc){
      float cd=cemb[condp[0]*Cc+i];
      zh[Hh+i]=cd; zc[Hh+i]=cd;
    }
  }
}

// decoder step 1: writes S1 (fp32, parity 0) into dstate slot1 + Hmat row 0
__global__ __launch_bounds__(256) void k_dec0(
    const float* __restrict__ Xg, const float* __restrict__ WhhO,
    const float* __restrict__ zh, const float* __restrict__ zc,
    unsigned* dstate1, float* Hmat)
{
  int tid=threadIdx.x, lane=tid&63, wv=tid>>6;
  int j=blockIdx.x*4+wv;
  float hseg[16];
#pragma unroll
  for(int e=0;e<16;e++) hseg[e]=zh[lane+64*e];
  float g[4];
#pragma unroll
  for(int q=0;q<4;q++){
    const float* p=WhhO+(size_t)(q*HCd+j)*HCd+lane;
    float s=0.f;
#pragma unroll
    for(int e=0;e<16;e++) s+=p[(size_t)e*64]*hseg[e];
    s=wave_reduce(s);
    g[q]=s+Xg[q*HCd+j];
  }
  float cc=zc[j];
  float cn=sigmoidf_(g[1])*cc+sigmoidf_(g[0])*tanhf(g[2]);
  float hn=sigmoidf_(g[3])*tanhf(cn);
  if(lane==0){
    dstate1[2*j]  =__float_as_uint(hn)&~1u;
    dstate1[2*j+1]=__float_as_uint(cn)&~1u;
    Hmat[j]=hn;
  }
}

// ---------------- Decoder scan (fp32 seqlock; REGISTER-RESIDENT bf16 weights) ----------------
__global__ __launch_bounds__(ET,2) void k_dec9(
    const float* __restrict__ Xg, const float* __restrict__ Weff,
    const float* __restrict__ cvec,
    const float* __restrict__ fccw, const float* __restrict__ fccb,
    const float* __restrict__ cemb, const int* __restrict__ condp,
    unsigned* dstate, float* __restrict__ Hmat)
{
  __shared__ float hlds[2][HCd];
  __shared__ float clds[2][HCd];
  const int tid=threadIdx.x, lane=tid&63, wv=tid>>6;
  const int wid=blockIdx.x*8+wv;
  const int j0=wid*2, j1=j0+1;
  uint4v wp[8][2];
#pragma unroll
  for(int q=0;q<4;q++)
#pragma unroll
    for(int jj=0;jj<2;jj++){
      const float* p=Weff+(size_t)(q*HCd+j0+jj)*HCd+lane;
      float t[16];
#pragma unroll
      for(int e=0;e<16;e++) t[e]=p[(size_t)e*64];
      int r=q*2+jj;
      wp[r][0]=(uint4v){pk_bf16(t[0],t[1]),pk_bf16(t[2],t[3]),pk_bf16(t[4],t[5]),pk_bf16(t[6],t[7])};
      wp[r][1]=(uint4v){pk_bf16(t[8],t[9]),pk_bf16(t[10],t[11]),pk_bf16(t[12],t[13]),pk_bf16(t[14],t[15])};
    }
  const bool hasf=(j0<Hh);
  uint4v fp0[2], fp1[2];
  {
    float t0[16], t1[16];
#pragma unroll
    for(int e=0;e<16;e++){ t0[e]=0.f; t1[e]=0.f; }
    if(hasf){
      const float* p0=fccw+(size_t)j0*HCd+lane;
      const float* p1=fccw+(size_t)j1*HCd+lane;
#pragma unroll
      for(int e=0;e<16;e++){ t0[e]=p0[(size_t)e*64]; t1[e]=p1[(size_t)e*64]; }
    }
    fp0[0]=(uint4v){pk_bf16(t0[0],t0[1]),pk_bf16(t0[2],t0[3]),pk_bf16(t0[4],t0[5]),pk_bf16(t0[6],t0[7])};
    fp0[1]=(uint4v){pk_bf16(t0[8],t0[9]),pk_bf16(t0[10],t0[11]),pk_bf16(t0[12],t0[13]),pk_bf16(t0[14],t0[15])};
    fp1[0]=(uint4v){pk_bf16(t1[0],t1[1]),pk_bf16(t1[2],t1[3]),pk_bf16(t1[4],t1[5]),pk_bf16(t1[6],t1[7])};
    fp1[1]=(uint4v){pk_bf16(t1[8],t1[9]),pk_bf16(t1[10],t1[11]),pk_bf16(t1[12],t1[13]),pk_bf16(t1[14],t1[15])};
  }
#pragma unroll
  for(int r=0;r<8;r++) asm volatile("" : "+v"(wp[r][0]), "+v"(wp[r][1]));
  asm volatile("" : "+v"(fp0[0]), "+v"(fp0[1]), "+v"(fp1[0]), "+v"(fp1[1]));

  float fb0=hasf?fccb[j0]:0.f, fb1=hasf?fccb[j1]:0.f;
  int cond=condp[0];
  float cd0=hasf?0.f:cemb[cond*Cc+(j0-Hh)];
  float cd1=hasf?0.f:cemb[cond*Cc+(j1-Hh)];
  float cv[8];
#pragma unroll
  for(int r=0;r<8;r++) cv[r]=cvec[(r>>1)*HCd+j0+(r&1)];
  float xg[8];
  { const float* px=Xg+(size_t)1*G4;
#pragma unroll
    for(int r=0;r<8;r++) xg[r]=px[(r>>1)*HCd+j0+(r&1)]; }
  const int i0=tid*2, i1=i0+1;

  for(int s=2;s<=NSD;s++){
    uint4v v;
    unsigned* st=dstate+((s-1)&1)*2*HCd;
    if(s==2){ v=*(const uint4v*)(st+4*tid); }   // S_1 from k_dec0
    else{
      const unsigned expp=(unsigned)(((s-1)>>1)&1);
      for(;;){
        v=ld_uc4(st+4*tid);
        if((((v.x^expp)|(v.y^expp)|(v.z^expp)|(v.w^expp))&1u)==0u) break;
        __builtin_amdgcn_s_sleep(1);
      }
    }
    float* hl=hlds[(s-1)&1]; float* cl=clds[(s-1)&1];
    hl[i0]=__uint_as_float(v.x); cl[i0]=__uint_as_float(v.y);
    hl[i1]=__uint_as_float(v.z); cl[i1]=__uint_as_float(v.w);
    __syncthreads();
    float hseg[16], cseg[16];
#pragma unroll
    for(int e=0;e<16;e++){ hseg[e]=hl[lane+64*e]; cseg[e]=cl[lane+64*e]; }
    float d[8]; float s8=0.f, s9=0.f;
#pragma unroll
    for(int r=0;r<8;r++){ float sacc=0.f;
#pragma unroll
      for(int d0=0;d0<8;d0++){
        unsigned u=wp[r][d0>>2][d0&3];
        sacc += bf_lo(u)*hseg[2*d0] + bf_hi(u)*hseg[2*d0+1];
      }
      d[r]=sacc; }
#pragma unroll
    for(int r=0;r<8;r++) d[r]=redl0(d[r]);
    if(hasf){
#pragma unroll
      for(int d0=0;d0<8;d0++){
        unsigned u0=fp0[d0>>2][d0&3], u1=fp1[d0>>2][d0&3];
        s8 += bf_lo(u0)*cseg[2*d0] + bf_hi(u0)*cseg[2*d0+1];
        s9 += bf_lo(u1)*cseg[2*d0] + bf_hi(u1)*cseg[2*d0+1];
      }
      s8=redl0(s8); s9=redl0(s9);
    }
    float gi0=d[0]+xg[0]+cv[0], gi1=d[1]+xg[1]+cv[1];
    float gf0=d[2]+xg[2]+cv[2], gf1=d[3]+xg[3]+cv[3];
    float gg0=d[4]+xg[4]+cv[4], gg1=d[5]+xg[5]+cv[5];
    float go0=d[6]+xg[6]+cv[6], go1=d[7]+xg[7]+cv[7];
    if(s<NSD){
      const float* px=Xg+(size_t)s*G4;
#pragma unroll
      for(int r=0;r<8;r++) xg[r]=px[(r>>1)*HCd+j0+(r&1)];
    }
    float cc0=hasf?(s8+fb0):cd0;
    float cc1=hasf?(s9+fb1):cd1;
    float cn0=sigmoidf_(gf0)*cc0+sigmoidf_(gi0)*tanhf(gg0);
    float hn0=sigmoidf_(go0)*tanhf(cn0);
    float cn1=sigmoidf_(gf1)*cc1+sigmoidf_(gi1)*tanhf(gg1);
    float hn1=sigmoidf_(go1)*tanhf(cn1);
    unsigned wpar=(unsigned)((s>>1)&1);
    if(lane==0){
      uint4v pk;
      pk.x=(__float_as_uint(hn0)&~1u)|wpar;
      pk.y=(__float_as_uint(cn0)&~1u)|wpar;
      pk.z=(__float_as_uint(hn1)&~1u)|wpar;
      pk.w=(__float_as_uint(cn1)&~1u)|wpar;
      st_uc4(dstate+(s&1)*2*HCd+2*j0,pk);
      Hmat[(size_t)(s-1)*HCd+j0]=hn0; Hmat[(size_t)(s-1)*HCd+j1]=hn1;
    }
  }
}

// ---------------- logits GEMM, B pre-converted bf16 ----------------
__global__ __launch_bounds__(256) void k_gemm2(
    const float* __restrict__ A, const ushort* __restrict__ Bb,
    const float* __restrict__ bias, float* __restrict__ Cm, int M)
{
  __shared__ ushort As[TBM*TBK];
  __shared__ ushort Bs[TBN*TBK];
  int tid=threadIdx.x;
  int m0=blockIdx.x*TBM, n0=blockIdx.y*TBN;
  int wid=tid>>6, lane=tid&63;
  int wm=wid>>1, wn=wid&1;
  int r15=lane&15, g=lane>>4;
  f32x4 acc[4][4]={};
  int srow=tid>>1, shalf=tid&1;
  const float*  aptr=A +(size_t)(m0+srow)*HCd + shalf*16;
  const ushort* bptr=Bb+(size_t)(n0+srow)*HCd + shalf*16;
  bool aok=(m0+srow)<M;
  float bj[4];
#pragma unroll
  for(int j=0;j<4;j++) bj[j]=bias[n0+wn*64+j*16+r15];

  for(int k0=0;k0<HCd;k0+=TBK){
    float4 va0={0,0,0,0},va1={0,0,0,0},va2={0,0,0,0},va3={0,0,0,0};
    if(aok){
      va0=*(const float4*)(aptr+k0);   va1=*(const float4*)(aptr+k0+4);
      va2=*(const float4*)(aptr+k0+8); va3=*(const float4*)(aptr+k0+12);
    }
    uint4v qb0=*(const uint4v*)(bptr+k0);
    uint4v qb1=*(const uint4v*)(bptr+k0+8);
    uint4v pa0={pk_bf16(va0.x,va0.y),pk_bf16(va0.z,va0.w),pk_bf16(va1.x,va1.y),pk_bf16(va1.z,va1.w)};
    uint4v pa1={pk_bf16(va2.x,va2.y),pk_bf16(va2.z,va2.w),pk_bf16(va3.x,va3.y),pk_bf16(va3.z,va3.w)};
    int sx=(srow>>1)&3;
    int u0=(shalf*2+0)^sx, u1=(shalf*2+1)^sx;
    *(uint4v*)&As[srow*32+u0*8]=pa0; *(uint4v*)&As[srow*32+u1*8]=pa1;
    *(uint4v*)&Bs[srow*32+u0*8]=qb0; *(uint4v*)&Bs[srow*32+u1*8]=qb1;
    __syncthreads();
    bf16x8 af[4], bf[4];
#pragma unroll
    for(int i=0;i<4;i++){
      int ra=wm*64+i*16+r15;
      af[i]=*(const bf16x8*)&As[ra*32+((g^((ra>>1)&3))<<3)];
      int rb=wn*64+i*16+r15;
      bf[i]=*(const bf16x8*)&Bs[rb*32+((g^((rb>>1)&3))<<3)];
    }
#pragma unroll
    for(int i=0;i<4;i++)
#pragma unroll
      for(int j=0;j<4;j++)
        acc[i][j]=__builtin_amdgcn_mfma_f32_16x16x32_bf16(af[i],bf[j],acc[i][j],0,0,0);
    __syncthreads();
  }
#pragma unroll
  for(int i=0;i<4;i++){
    int grow0=m0+wm*64+i*16+g*4;
#pragma unroll
    for(int j=0;j<4;j++){
      int gcol=n0+wn*64+j*16+r15;
#pragma unroll
      for(int r=0;r<4;r++){
        int grow=grow0+r;
        if(grow<M) Cm[(size_t)grow*VSZ+gcol]=acc[i][j][r]+bj[j];
      }
    }
  }
}

// fallback logits GEMM (in-kernel B conversion)
__global__ __launch_bounds__(256) void k_gemm_mfma(
    const float* __restrict__ A, const float* __restrict__ B,
    const float* __restrict__ bias, float* __restrict__ Cm, int M)
{
  __shared__ ushort As[TBM*TBK];
  __shared__ ushort Bs[TBN*TBK];
  int tid=threadIdx.x;
  int m0=blockIdx.x*TBM, n0=blockIdx.y*TBN;
  int wid=tid>>6, lane=tid&63;
  int wm=wid>>1, wn=wid&1;
  int r15=lane&15, g=lane>>4;
  f32x4 acc[4][4]={};
  int srow=tid>>1, shalf=tid&1;
  const float* aptr=A+(size_t)(m0+srow)*HCd + shalf*16;
  const float* bptr=B+(size_t)(n0+srow)*HCd + shalf*16;
  bool aok=(m0+srow)<M;
  float bj[4];
#pragma unroll
  for(int j=0;j<4;j++) bj[j]=bias[n0+wn*64+j*16+r15];
  for(int k0=0;k0<HCd;k0+=TBK){
    float4 va0={0,0,0,0},va1={0,0,0,0},va2={0,0,0,0},va3={0,0,0,0};
    if(aok){
      va0=*(const float4*)(aptr+k0);   va1=*(const float4*)(aptr+k0+4);
      va2=*(const float4*)(aptr+k0+8); va3=*(const float4*)(aptr+k0+12);
    }
    float4 vb0=*(const float4*)(bptr+k0),   vb1=*(const float4*)(bptr+k0+4);
    float4 vb2=*(const float4*)(bptr+k0+8), vb3=*(const float4*)(bptr+k0+12);
    uint4v pa0={pk_bf16(va0.x,va0.y),pk_bf16(va0.z,va0.w),pk_bf16(va1.x,va1.y),pk_bf16(va1.z,va1.w)};
    uint4v pa1={pk_bf16(va2.x,va2.y),pk_bf16(va2.z,va2.w),pk_bf16(va3.x,va3.y),pk_bf16(va3.z,va3.w)};
    uint4v pb0={pk_bf16(vb0.x,vb0.y),pk_bf16(vb0.z,vb0.w),pk_bf16(vb1.x,vb1.y),pk_bf16(vb1.z,vb1.w)};
    uint4v pb1={pk_bf16(vb2.x,vb2.y),pk_bf16(vb2.z,vb2.w),pk_bf16(vb3.x,vb3.y),pk_bf16(vb3.z,vb3.w)};
    int sx=(srow>>1)&3;
    int u0=(shalf*2+0)^sx, u1=(shalf*2+1)^sx;
    *(uint4v*)&As[srow*32+u0*8]=pa0; *(uint4v*)&As[srow*32+u1*8]=pa1;
    *(uint4v*)&Bs[srow*32+u0*8]=pb0; *(uint4v*)&Bs[srow*32+u1*8]=pb1;
    __syncthreads();
    bf16x8 af[4], bf[4];
#pragma unroll
    for(int i=0;i<4;i++){
      int ra=wm*64+i*16+r15;
      af[i]=*(const bf16x8*)&As[ra*32+((g^((ra>>1)&3))<<3)];
      int rb=wn*64+i*16+r15;
      bf[i]=*(const bf16x8*)&Bs[rb*32+((g^((rb>>1)&3))<<3)];
    }
#pragma unroll
    for(int i=0;i<4;i++)
#pragma unroll
      for(int j=0;j<4;j++)
        acc[i][j]=__builtin_amdgcn_mfma_f32_16x16x32_bf16(af[i],bf[j],acc[i][j],0,0,0);
    __syncthreads();
  }
#pragma unroll
  for(int i=0;i<4;i++){
    int grow0=m0+wm*64+i*16+g*4;
#pragma unroll
    for(int j=0;j<4;j++){
      int gcol=n0+wn*64+j*16+r15;
#pragma unroll
      for(int r=0;r<4;r++){
        int grow=grow0+r;
        if(grow<M) Cm[(size_t)grow*VSZ+gcol]=acc[i][j][r]+bj[j];
      }
    }
  }
}

// per-row cross-entropy, single-pass online softmax
__global__ __launch_bounds__(256) void k_ce(const float* __restrict__ logits,
    const int* __restrict__ tok, int base, float* __restrict__ ce)
{
  int r=blockIdx.x;
  const float* row=logits+(size_t)r*VSZ;
  int tid=threadIdx.x, lane=tid&63, wv=tid>>6;
  float m=-1e30f, s=0.f;
  for(int i=tid;i<VSZ;i+=256){
    float v=row[i];
    if(v>m){ s=s*__expf(m-v)+1.f; m=v; }
    else s+=__expf(v-m);
  }
#pragma unroll
  for(int o=32;o;o>>=1){
    float mo=__shfl_xor(m,o,64), so=__shfl_xor(s,o,64);
    float mn=fmaxf(m,mo);
    s=s*__expf(m-mn)+so*__expf(mo-mn);
    m=mn;
  }
  __shared__ float smm[4], sms[4];
  if(lane==0){ smm[wv]=m; sms[wv]=s; }
  __syncthreads();
  if(tid==0){
    float M2=fmaxf(fmaxf(smm[0],smm[1]),fmaxf(smm[2],smm[3]));
    float S2=sms[0]*__expf(smm[0]-M2)+sms[1]*__expf(smm[1]-M2)
            +sms[2]*__expf(smm[2]-M2)+sms[3]*__expf(smm[3]-M2);
    int tgt=tok[base+r+1];
    ce[base+r]=M2+logf(S2)-row[tgt];
  }
}

__global__ __launch_bounds__(256) void k_final(const float* __restrict__ ce,
    const float* __restrict__ klh, const float* __restrict__ klc,
    const float* __restrict__ kldw, float* __restrict__ outp)
{
  int tid=threadIdx.x, lane=tid&63, wv=tid>>6;
  float s0=0,s1=0,s2=0;
  for(int i=tid;i<NSD;i+=256) s0+=ce[i];
  for(int i=tid;i<Hh;i+=256){ s1+=klh[i]; s2+=klc[i]; }
  s0=wave_reduce(s0); s1=wave_reduce(s1); s2=wave_reduce(s2);
  __shared__ float sm[3][4];
  if(lane==0){ sm[0][wv]=s0; sm[1][wv]=s1; sm[2][wv]=s2; }
  __syncthreads();
  if(tid==0){
    float ces=sm[0][0]+sm[0][1]+sm[0][2]+sm[0][3];
    float kh =sm[1][0]+sm[1][1]+sm[1][2]+sm[1][3];
    float kc =sm[2][0]+sm[2][1]+sm[2][2]+sm[2][3];
    float rec=ces/(float)NSD;
    outp[0]=rec+(kh+kc)*kldw[0];
    outp[1]=rec; outp[2]=kh; outp[3]=kc;
  }
}

extern "C" void kernel_launch(void* const* d_in, const int* in_sizes, int n_in,
                              void* d_out, int out_size, void* d_ws, size_t ws_size,
                              hipStream_t stream) {
  const int*   tok   =(const int*)  d_in[0];
  const int*   cond  =(const int*)  d_in[1];
  const float* eps_h =(const float*)d_in[2];
  const float* eps_c =(const float*)d_in[3];
  const float* kldw  =(const float*)d_in[4];
  const float* enc_embed=(const float*)d_in[5];
  const float* enc_cemb =(const float*)d_in[6];
  const float* enc_Wih  =(const float*)d_in[7];
  const float* enc_Whh  =(const float*)d_in[8];
  const float* enc_bih  =(const float*)d_in[9];
  const float* enc_bhh  =(const float*)d_in[10];
  const float* fc_mh_w=(const float*)d_in[11];
  const float* fc_mh_b=(const float*)d_in[12];
  const float* fc_lh_w=(const float*)d_in[13];
  const float* fc_lh_b=(const float*)d_in[14];
  const float* fc_mc_w=(const float*)d_in[15];
  const float* fc_mc_b=(const float*)d_in[16];
  const float* fc_lc_w=(const float*)d_in[17];
  const float* fc_lc_b=(const float*)d_in[18];
  const float* dec_embed=(const float*)d_in[19];
  const float* dec_cemb =(const float*)d_in[20];
  const float* dec_Wih  =(const float*)d_in[21];
  const float* dec_Whh  =(const float*)d_in[22];
  const float* dec_bih  =(const float*)d_in[23];
  const float* dec_bhh  =(const float*)d_in[24];
  const float* fc_h_w=(const float*)d_in[25];
  const float* fc_h_b=(const float*)d_in[26];
  const float* fc_c_w=(const float*)d_in[27];
  const float* fc_c_b=(const float*)d_in[28];
  const float* out_w=(const float*)d_in[29];
  const float* out_b=(const float*)d_in[30];

  float* ws=(float*)d_ws;
  size_t off=0;
  unsigned* estate=(unsigned*)(ws+off); off+=2*HCd;   // fp32 h, 2 slots
  unsigned* dstate=(unsigned*)(ws+off); off+=4*HCd;   // fp32 (h,c) pairs, 2 slots
  float* cvec=ws+off; off+=G4;
  float* Weff=ws+off; off+=(size_t)G4*HCd;
  float* hT  =ws+off; off+=HCd;
  float* cT  =ws+off; off+=HCd;
  float* zh  =ws+off; off+=HCd;
  float* zc  =ws+off; off+=HCd;
  float* klh =ws+off; off+=Hh;
  float* klc =ws+off; off+=Hh;
  float* Hmat=ws+off; off+=(size_t)NSD*HCd;
  float* ce  =ws+off; off+=2048;
  size_t avail=ws_size/4;
  size_t xa_sz=(size_t)NSE*G4, xb_sz=(size_t)NSD*G4;
  size_t wb_sz=(size_t)VSZ*HCd/2;              // bf16 out_w, in float slots
  float* XA=ws+off;
  bool dual=(off+xa_sz+xb_sz)<=avail;
  float* XB=dual?(XA+xa_sz):XA;
  bool wbok=dual && (off+xa_sz+xb_sz+wb_sz)<=avail;
  unsigned* wB=(unsigned*)(XB+xb_sz);
  size_t region=(avail>off)?(avail-off):0;
  int chunk;
  if(dual){
    chunk=(int)((xa_sz+xb_sz)/(size_t)VSZ); if(chunk>512)chunk=512;  // lbuf spans XA+XB
  } else {
    chunk=256;
    if((size_t)chunk*VSZ>region){ chunk=(int)(region/(size_t)VSZ); if(chunk<1)chunk=1; }
  }
  float* lbuf=XA;

  k_init9<<<1,256,0,stream>>>(estate,dstate,enc_cemb,cond);
  { dim3 g((NSE+GBM-1)/GBM, G4/GBN);           // Xenc (fp32) — scan dependency
    k_xgemm<<<g,256,0,stream>>>(enc_embed,enc_Wih,enc_bih,enc_bhh,tok,1,NSE,XA); }
  // fused: encoder scan + {dconst, weff, Xdec, cvtB} helpers
  k_encF<<<FGRID,ET,0,stream>>>(XA,enc_Whh,estate,hT,cT,
                                dec_Whh,fc_h_w,Weff,
                                dec_embed,dec_Wih,dec_bih,dec_bhh,tok,XB,
                                out_w,wB,fc_h_b,dec_cemb,cond,cvec,
                                dual?1:0, wbok?1:0);
  k_head<<<Hh,256,0,stream>>>(hT,cT,fc_mh_w,fc_mh_b,fc_lh_w,fc_lh_b,
                              fc_mc_w,fc_mc_b,fc_lc_w,fc_lc_b,
                              eps_h,eps_c,dec_cemb,cond,zh,zc,klh,klc);
  if(!dual){
    dim3 g((NSD+TBM-1)/TBM, G4/TBN);           // Xdec overwrites XA (encoder done)
    k_xgemm_mfma<<<g,256,0,stream>>>(dec_embed,dec_Wih,dec_bih,dec_bhh,tok,NSD,XB);
  }
  k_dec0<<<256,256,0,stream>>>(XB,dec_Whh,zh,zc,dstate+2*HCd,Hmat);
  k_dec9<<<EB,ET,0,stream>>>(XB,Weff,cvec,fc_c_w,fc_c_b,dec_cemb,cond,dstate,Hmat);
  for(int base=0;base<NSD;base+=chunk){        // lbuf overlays XA(+XB) — scans done
    int rows=NSD-base; if(rows>chunk) rows=chunk;
    dim3 g((rows+TBM-1)/TBM, VSZ/TBN);
    if(wbok) k_gemm2<<<g,256,0,stream>>>(Hmat+(size_t)base*HCd,(const ushort*)wB,out_b,lbuf,rows);
    else     k_gemm_mfma<<<g,256,0,stream>>>(Hmat+(size_t)base*HCd,out_w,out_b,lbuf,rows);
    k_ce<<<rows,256,0,stream>>>(lbuf,tok,base,ce);
  }
  k_final<<<1,256,0,stream>>>(ce,klh,klc,kldw,(float*)d_out);
}

// Round 12
// 12987.018 us; speedup vs baseline: 1.1378x; 1.0335x over previous
//
#include <hip/hip_runtime.h>
#include <math.h>

// Problem sizes (fixed)
#define VSZ 32000
#define Hh  768
#define Cc  256
#define HCd 1024
#define G4  4096
#define NSE 2046   // encoder steps
#define NSD 2047   // decoder steps

#define EB 64
#define ET 512
#define FGRID 256
#define NCT 125      // 256-wide col tiles over 32000

typedef __attribute__((ext_vector_type(4))) unsigned uint4v;
typedef __attribute__((ext_vector_type(2))) unsigned uint2v;
typedef __attribute__((ext_vector_type(8))) short bf16x8;
typedef __attribute__((ext_vector_type(4))) float f32x4;

__device__ __forceinline__ float sigmoidf_(float x){ return 1.0f/(1.0f+expf(-x)); }

__device__ __forceinline__ float wave_reduce(float v){
#pragma unroll
  for(int o=32;o;o>>=1) v += __shfl_xor(v,o,64);
  return v;
}
__device__ __forceinline__ unsigned wave_min_u(unsigned v){
#pragma unroll
  for(int o=32;o;o>>=1){ unsigned x=__shfl_xor(v,o,64); v=(x<v)?x:v; }
  return v;
}
// Reduce 64 lanes; total valid in lane 0.
__device__ __forceinline__ float redl0(float v){
  int x;
  x=__builtin_amdgcn_update_dpp(0,__float_as_int(v),0xB1,0xf,0xf,true); v+=__int_as_float(x); // ^1
  x=__builtin_amdgcn_update_dpp(0,__float_as_int(v),0x4E,0xf,0xf,true); v+=__int_as_float(x); // ^2
  v+=__int_as_float(__builtin_amdgcn_ds_swizzle(__float_as_int(v),0x101F)); // ^4
  v+=__int_as_float(__builtin_amdgcn_ds_swizzle(__float_as_int(v),0x201F)); // ^8
  v+=__int_as_float(__builtin_amdgcn_ds_swizzle(__float_as_int(v),0x401F)); // ^16
  v+=__int_as_float(__builtin_amdgcn_readlane(__float_as_int(v),32));
  return v;
}

// Device-scope (coherence-point) ops. Per-dword LSB parity self-validates.
__device__ __forceinline__ unsigned ld_uc1(const unsigned* p){
  unsigned r;
  asm volatile("global_load_dword %0, %1, off sc0 sc1\n\ts_waitcnt vmcnt(0)"
               : "=v"(r) : "v"(p) : "memory");
  return r;
}
__device__ __forceinline__ uint2v ld_uc2(const unsigned* p){
  uint2v r;
  asm volatile("global_load_dwordx2 %0, %1, off sc0 sc1\n\ts_waitcnt vmcnt(0)"
               : "=v"(r) : "v"(p) : "memory");
  return r;
}
__device__ __forceinline__ uint4v ld_uc4(const unsigned* p){
  uint4v r;
  asm volatile("global_load_dwordx4 %0, %1, off sc0 sc1\n\ts_waitcnt vmcnt(0)"
               : "=v"(r) : "v"(p) : "memory");
  return r;
}
__device__ __forceinline__ void st_uc1(unsigned* p, unsigned v){
  asm volatile("global_store_dword %0, %1, off sc0 sc1" :: "v"(p), "v"(v) : "memory");
}
__device__ __forceinline__ void st_uc2(unsigned* p, uint2v v){
  asm volatile("global_store_dwordx2 %0, %1, off sc0 sc1" :: "v"(p), "v"(v) : "memory");
}
__device__ __forceinline__ void st_uc4(unsigned* p, uint4v v){
  asm volatile("global_store_dwordx4 %0, %1, off sc0 sc1" :: "v"(p), "v"(v) : "memory");
}

// fp32->bf16 RNE, pack two per dword
__device__ __forceinline__ unsigned pk_bf16(float a, float b){
  unsigned ua=__float_as_uint(a); ua += 0x7fffu + ((ua>>16)&1u);
  unsigned ub=__float_as_uint(b); ub += 0x7fffu + ((ub>>16)&1u);
  return (ua>>16) | (ub & 0xffff0000u);
}

// init (re-runs every replay): prog zero; enc S0 slot0 parity0, slot1 stale;
// dec slot0 zeroed (stale for its first poll, which expects parity 1).
__global__ void k_init12(unsigned* prog, unsigned* estate, unsigned* dstate,
                         const float* __restrict__ cemb, const int* __restrict__ condp){
  int tid=threadIdx.x;
  int cond=condp[0];
  for(int i=tid;i<4096;i+=256) prog[i]=0u;
  for(int i=tid;i<HCd;i+=256){
    float v=(i<Hh)?0.f:cemb[cond*Cc+(i-Hh)];
    estate[i]=__float_as_uint(v)&~1u;
    estate[HCd+i]=1u;
  }
  for(int i=tid;i<2*HCd;i+=256) dstate[i]=0u;
}

#define GBM 128
#define GBN 128
#define GBK 16
#define TBM 128
#define TBN 128
#define TBK 32

// Shared-memory union for the fused encoder kernel.
struct SmU {
  union {
    float hlds[2][HCd];
    struct { float As[GBK][GBM]; float Bs[GBK][GBN]; } wf;
    struct { ushort As[TBM*TBK]; ushort Bs[TBN*TBK]; } xd;
  } u;
};

// ---- helper units (encoder-phase prologue) ----
__device__ void weff_unit(int u, const float* __restrict__ A,
    const float* __restrict__ B, float* __restrict__ Cm, SmU& sm, int tid){
  int m0=(u>>3)*GBM, n0=(u&7)*GBN;
  int tm=tid>>4, tn=tid&15;
  float acc[8][8]={};
  for(int k0=0;k0<Hh;k0+=GBK){
    if(tid<256){
#pragma unroll
      for(int uu=0;uu<2;uu++){
        int idx=tid*2+uu;
        int row=idx>>2, q=idx&3;
        float4 v=*(const float4*)(A+(size_t)(m0+row)*HCd + k0+q*4);
        sm.u.wf.As[q*4+0][row]=v.x; sm.u.wf.As[q*4+1][row]=v.y;
        sm.u.wf.As[q*4+2][row]=v.z; sm.u.wf.As[q*4+3][row]=v.w;
        int kk=idx>>5, nc=idx&31;
        float4 w=*(const float4*)(B+(size_t)(k0+kk)*HCd + n0+nc*4);
        *(float4*)&sm.u.wf.Bs[kk][nc*4]=w;
      }
    }
    __syncthreads();
    if(tid<256){
#pragma unroll
      for(int kk=0;kk<GBK;kk++){
        float a[8],b[8];
        *(float4*)&a[0]=*(float4*)&sm.u.wf.As[kk][tm*8]; *(float4*)&a[4]=*(float4*)&sm.u.wf.As[kk][tm*8+4];
        *(float4*)&b[0]=*(float4*)&sm.u.wf.Bs[kk][tn*8]; *(float4*)&b[4]=*(float4*)&sm.u.wf.Bs[kk][tn*8+4];
#pragma unroll
        for(int i=0;i<8;i++)
#pragma unroll
          for(int j=0;j<8;j++) acc[i][j]+=a[i]*b[j];
      }
    }
    __syncthreads();
  }
  if(tid<256){
#pragma unroll
    for(int i=0;i<8;i++)
#pragma unroll
      for(int j=0;j<8;j++)
        Cm[(size_t)(m0+tm*8+i)*HCd + n0+tn*8+j]=acc[i][j];
  }
}

__device__ void xdec_unit(int q, const float* __restrict__ emb,
    const float* __restrict__ Wih, const float* __restrict__ b1,
    const float* __restrict__ b2, const int* __restrict__ tok,
    float* __restrict__ X, SmU& sm, int tid){
  int m0=(q>>5)*TBM, n0=(q&31)*TBN;
  int wid=tid>>6, lane=tid&63;
  int wm=wid>>1, wn=wid&1;
  int r15=lane&15, g=lane>>4;
  f32x4 acc[4][4]={};
  int srow=tid>>1, shalf=tid&1;
  int arow=m0+srow;
  bool act=(tid<256);
  int atok=(act&&arow<NSD)?tok[arow]:0;
  const float* aptr=emb+(size_t)atok*HCd + shalf*16;
  const float* bptr=Wih+(size_t)(n0+srow)*HCd + shalf*16;
  bool aok=act&&(arow<NSD);
  float bj[4];
  if(act){
#pragma unroll
    for(int j=0;j<4;j++){ int n=n0+wn*64+j*16+r15; bj[j]=b1[n]+b2[n]; }
  }
  for(int k0=0;k0<HCd;k0+=TBK){
    if(act){
      float4 va0={0,0,0,0},va1={0,0,0,0},va2={0,0,0,0},va3={0,0,0,0};
      if(aok){
        va0=*(const float4*)(aptr+k0);   va1=*(const float4*)(aptr+k0+4);
        va2=*(const float4*)(aptr+k0+8); va3=*(const float4*)(aptr+k0+12);
      }
      float4 vb0=*(const float4*)(bptr+k0),   vb1=*(const float4*)(bptr+k0+4);
      float4 vb2=*(const float4*)(bptr+k0+8), vb3=*(const float4*)(bptr+k0+12);
      uint4v pa0={pk_bf16(va0.x,va0.y),pk_bf16(va0.z,va0.w),pk_bf16(va1.x,va1.y),pk_bf16(va1.z,va1.w)};
      uint4v pa1={pk_bf16(va2.x,va2.y),pk_bf16(va2.z,va2.w),pk_bf16(va3.x,va3.y),pk_bf16(va3.z,va3.w)};
      uint4v pb0={pk_bf16(vb0.x,vb0.y),pk_bf16(vb0.z,vb0.w),pk_bf16(vb1.x,vb1.y),pk_bf16(vb1.z,vb1.w)};
      uint4v pb1={pk_bf16(vb2.x,vb2.y),pk_bf16(vb2.z,vb2.w),pk_bf16(vb3.x,vb3.y),pk_bf16(vb3.z,vb3.w)};
      int sx=(srow>>1)&3;
      int u0=(shalf*2+0)^sx, u1=(shalf*2+1)^sx;
      *(uint4v*)&sm.u.xd.As[srow*32+u0*8]=pa0; *(uint4v*)&sm.u.xd.As[srow*32+u1*8]=pa1;
      *(uint4v*)&sm.u.xd.Bs[srow*32+u0*8]=pb0; *(uint4v*)&sm.u.xd.Bs[srow*32+u1*8]=pb1;
    }
    __syncthreads();
    if(act){
      bf16x8 af[4], bf[4];
#pragma unroll
      for(int i=0;i<4;i++){
        int ra=wm*64+i*16+r15;
        af[i]=*(const bf16x8*)&sm.u.xd.As[ra*32+((g^((ra>>1)&3))<<3)];
        int rb=wn*64+i*16+r15;
        bf[i]=*(const bf16x8*)&sm.u.xd.Bs[rb*32+((g^((rb>>1)&3))<<3)];
      }
#pragma unroll
      for(int i=0;i<4;i++)
#pragma unroll
        for(int j=0;j<4;j++)
          acc[i][j]=__builtin_amdgcn_mfma_f32_16x16x32_bf16(af[i],bf[j],acc[i][j],0,0,0);
    }
    __syncthreads();
  }
  if(act){
#pragma unroll
    for(int i=0;i<4;i++){
      int grow0=m0+wm*64+i*16+g*4;
#pragma unroll
      for(int j=0;j<4;j++){
        int gcol=n0+wn*64+j*16+r15;
#pragma unroll
        for(int r=0;r<4;r++){
          int grow=grow0+r;
          if(grow<NSD) X[(size_t)grow*G4+gcol]=acc[i][j][r]+bj[j];
        }
      }
    }
  }
}

__device__ void cvtb_unit(int i, const float* __restrict__ B,
    unsigned* __restrict__ Bb, int tid){
  size_t base=(size_t)i*128000u;
  for(size_t x=base+tid; x<base+128000u; x+=ET){
    float4 v=*(const float4*)(B+x*4);
    Bb[x*2]  =pk_bf16(v.x,v.y);
    Bb[x*2+1]=pk_bf16(v.z,v.w);
  }
}

__device__ void dconst_unit(int i, const float* __restrict__ Whh,
    const float* __restrict__ fhb, const float* __restrict__ cemb,
    int cond, float* __restrict__ cvec, int tid){
  int lane=tid&63, wv=tid>>6;
  for(int r=i*256+wv; r<i*256+256; r+=8){
    const float* row=Whh+(size_t)r*HCd;
    float s=0.f;
    for(int k=lane;k<Hh;k+=64) s+=row[k]*fhb[k];
    for(int k=lane;k<Cc;k+=64) s+=row[Hh+k]*cemb[cond*Cc+k];
    s=wave_reduce(s);
    if(lane==0) cvec[r]=s;
  }
}

// Encoder X (fp32 tile GEMM — kl precision headroom is thin)
__global__ __launch_bounds__(256) void k_xgemm(
    const float* __restrict__ emb, const float* __restrict__ Wih,
    const float* __restrict__ b1, const float* __restrict__ b2,
    const int* __restrict__ tok, int tshift, int M,
    float* __restrict__ X)
{
  __shared__ float As[GBK][GBM];
  __shared__ float Bs[GBK][GBN];
  int tid=threadIdx.x;
  int m0=blockIdx.x*GBM, n0=blockIdx.y*GBN;
  int tm=tid>>4, tn=tid&15;
  int arow=m0+(tid>>1);
  int atok=(arow<M)?tok[arow+tshift]:0;
  const float* abase=emb+(size_t)atok*HCd+(tid&1)*8;
  const float* bbase=Wih+(size_t)(n0+(tid>>1))*HCd+(tid&1)*8;
  int srow=tid>>1;
  float acc[8][8]={};
  for(int k0=0;k0<HCd;k0+=GBK){
#pragma unroll
    for(int u=0;u<2;u++){
      int q=2*(tid&1)+u;
      float4 v={0,0,0,0};
      if(arow<M) v=*(const float4*)(abase+k0+u*4);
      As[q*4+0][srow]=v.x; As[q*4+1][srow]=v.y; As[q*4+2][srow]=v.z; As[q*4+3][srow]=v.w;
      float4 w=*(const float4*)(bbase+k0+u*4);
      Bs[q*4+0][srow]=w.x; Bs[q*4+1][srow]=w.y; Bs[q*4+2][srow]=w.z; Bs[q*4+3][srow]=w.w;
    }
    __syncthreads();
#pragma unroll
    for(int kk=0;kk<GBK;kk++){
      float a[8],b[8];
      *(float4*)&a[0]=*(float4*)&As[kk][tm*8]; *(float4*)&a[4]=*(float4*)&As[kk][tm*8+4];
      *(float4*)&b[0]=*(float4*)&Bs[kk][tn*8]; *(float4*)&b[4]=*(float4*)&Bs[kk][tn*8+4];
#pragma unroll
      for(int i=0;i<8;i++)
#pragma unroll
        for(int j=0;j<8;j++) acc[i][j]+=a[i]*b[j];
    }
    __syncthreads();
  }
#pragma unroll
  for(int i=0;i<8;i++){
    int m=m0+tm*8+i; if(m>=M) continue;
#pragma unroll
    for(int j=0;j<8;j++){
      int n=n0+tn*8+j;
      X[(size_t)m*G4+n]=acc[i][j]+b1[n]+b2[n];
    }
  }
}

// Standalone Xdec (fallback when !dual)
__global__ __launch_bounds__(256) void k_xgemm_mfma(
    const float* __restrict__ emb, const float* __restrict__ Wih,
    const float* __restrict__ b1, const float* __restrict__ b2,
    const int* __restrict__ tok, int M, float* __restrict__ X)
{
  __shared__ ushort As[TBM*TBK];
  __shared__ ushort Bs[TBN*TBK];
  int tid=threadIdx.x;
  int m0=blockIdx.x*TBM, n0=blockIdx.y*TBN;
  int wid=tid>>6, lane=tid&63;
  int wm=wid>>1, wn=wid&1;
  int r15=lane&15, g=lane>>4;
  f32x4 acc[4][4]={};
  int srow=tid>>1, shalf=tid&1;
  int arow=m0+srow;
  int atok=(arow<M)?tok[arow]:0;
  const float* aptr=emb+(size_t)atok*HCd + shalf*16;
  const float* bptr=Wih+(size_t)(n0+srow)*HCd + shalf*16;
  bool aok=arow<M;
  float bj[4];
#pragma unroll
  for(int j=0;j<4;j++){ int n=n0+wn*64+j*16+r15; bj[j]=b1[n]+b2[n]; }
  for(int k0=0;k0<HCd;k0+=TBK){
    float4 va0={0,0,0,0},va1={0,0,0,0},va2={0,0,0,0},va3={0,0,0,0};
    if(aok){
      va0=*(const float4*)(aptr+k0);   va1=*(const float4*)(aptr+k0+4);
      va2=*(const float4*)(aptr+k0+8); va3=*(const float4*)(aptr+k0+12);
    }
    float4 vb0=*(const float4*)(bptr+k0),   vb1=*(const float4*)(bptr+k0+4);
    float4 vb2=*(const float4*)(bptr+k0+8), vb3=*(const float4*)(bptr+k0+12);
    uint4v pa0={pk_bf16(va0.x,va0.y),pk_bf16(va0.z,va0.w),pk_bf16(va1.x,va1.y),pk_bf16(va1.z,va1.w)};
    uint4v pa1={pk_bf16(va2.x,va2.y),pk_bf16(va2.z,va2.w),pk_bf16(va3.x,va3.y),pk_bf16(va3.z,va3.w)};
    uint4v pb0={pk_bf16(vb0.x,vb0.y),pk_bf16(vb0.z,vb0.w),pk_bf16(vb1.x,vb1.y),pk_bf16(vb1.z,vb1.w)};
    uint4v pb1={pk_bf16(vb2.x,vb2.y),pk_bf16(vb2.z,vb2.w),pk_bf16(vb3.x,vb3.y),pk_bf16(vb3.z,vb3.w)};
    int sx=(srow>>1)&3;
    int u0=(shalf*2+0)^sx, u1=(shalf*2+1)^sx;
    *(uint4v*)&As[srow*32+u0*8]=pa0; *(uint4v*)&As[srow*32+u1*8]=pa1;
    *(uint4v*)&Bs[srow*32+u0*8]=pb0; *(uint4v*)&Bs[srow*32+u1*8]=pb1;
    __syncthreads();
    bf16x8 af[4], bf[4];
#pragma unroll
    for(int i=0;i<4;i++){
      int ra=wm*64+i*16+r15;
      af[i]=*(const bf16x8*)&As[ra*32+((g^((ra>>1)&3))<<3)];
      int rb=wn*64+i*16+r15;
      bf[i]=*(const bf16x8*)&Bs[rb*32+((g^((rb>>1)&3))<<3)];
    }
#pragma unroll
    for(int i=0;i<4;i++)
#pragma unroll
      for(int j=0;j<4;j++)
        acc[i][j]=__builtin_amdgcn_mfma_f32_16x16x32_bf16(af[i],bf[j],acc[i][j],0,0,0);
    __syncthreads();
  }
#pragma unroll
  for(int i=0;i<4;i++){
    int grow0=m0+wm*64+i*16+g*4;
#pragma unroll
    for(int j=0;j<4;j++){
      int gcol=n0+wn*64+j*16+r15;
#pragma unroll
      for(int r=0;r<4;r++){
        int grow=grow0+r;
        if(grow<M) X[(size_t)grow*G4+gcol]=acc[i][j][r]+bj[j];
      }
    }
  }
}

// ---------------- Fused encoder: scan blocks 0..63 + prologue helpers ----------------
__global__ __launch_bounds__(ET,2) void k_encF(
    const float* __restrict__ Xg, const float* __restrict__ Whh,
    unsigned* estate, float* hT, float* cT,
    const float* __restrict__ dWhh, const float* __restrict__ fhw,
    float* __restrict__ Weff,
    const float* __restrict__ demb, const float* __restrict__ dWih,
    const float* __restrict__ dbih, const float* __restrict__ dbhh,
    const int* __restrict__ tok, float* __restrict__ XB,
    const float* __restrict__ outw, unsigned* __restrict__ wB,
    const float* __restrict__ fhb, const float* __restrict__ dcemb,
    const int* __restrict__ condp, float* __restrict__ cvec,
    int do_xdec, int do_cvtb)
{
  __shared__ SmU sm;
  const int tid=threadIdx.x, lane=tid&63, wv=tid>>6;
  const int bid=blockIdx.x;

  if(bid>=EB){
    int cond=condp[0];
    int n_x=do_xdec?512:0, n_c=do_cvtb?64:0;
    int total=16+256+n_x+n_c;
    for(int u=bid-EB; u<total; u+=FGRID-EB){
      if(u<16) dconst_unit(u,dWhh,fhb,dcemb,cond,cvec,tid);
      else if(u<272) weff_unit(u-16,dWhh,fhw,Weff,sm,tid);
      else if(u<272+n_x) xdec_unit(u-272,demb,dWih,dbih,dbhh,tok,XB,sm,tid);
      else cvtb_unit(u-272-n_x,outw,wB,tid);
      __syncthreads();
    }
    return;
  }

  // -------- encoder scan (r9 fp32 body) --------
  const int wid=bid*8+wv;
  const int j0=wid*2, j1=j0+1;
  float w[8][16];
#pragma unroll
  for(int q=0;q<4;q++)
#pragma unroll
    for(int jj=0;jj<2;jj++){
      const float* p=Whh+(size_t)(q*HCd+j0+jj)*HCd+lane;
#pragma unroll
      for(int e=0;e<16;e++) w[q*2+jj][e]=p[(size_t)e*64];
    }
  float xg[8];
#pragma unroll
  for(int r=0;r<8;r++) xg[r]=Xg[(r>>1)*HCd+j0+(r&1)];
  float c0=0.f,c1=0.f;
  const int i0=tid*2, i1=i0+1;

  for(int s=1;s<=NSE;s++){
    uint2v v;
    unsigned* src=estate+((s-1)&1)*HCd;
    if(s==1){ v.x=src[i0]; v.y=src[i1]; }
    else{
      const unsigned expp=(unsigned)(((s-1)>>1)&1);
      for(;;){
        v=ld_uc2(src+i0);
        if((((v.x^expp)|(v.y^expp))&1u)==0u) break;
        __builtin_amdgcn_s_sleep(1);
      }
    }
    float* hl=sm.u.hlds[(s-1)&1];
    hl[i0]=__uint_as_float(v.x); hl[i1]=__uint_as_float(v.y);
    __syncthreads();
    if(s==1){ c0=hl[j0]; c1=hl[j1]; }   // h0 == c0
    float hseg[16];
#pragma unroll
    for(int e=0;e<16;e++) hseg[e]=hl[lane+64*e];
    float d[8];
#pragma unroll
    for(int r=0;r<8;r++){ float sacc=0.f;
#pragma unroll
      for(int e=0;e<16;e++) sacc+=w[r][e]*hseg[e];
      d[r]=sacc; }
#pragma unroll
    for(int r=0;r<8;r++) d[r]=redl0(d[r]);
    float gi0=d[0]+xg[0], gi1=d[1]+xg[1];
    float gf0=d[2]+xg[2], gf1=d[3]+xg[3];
    float gg0=d[4]+xg[4], gg1=d[5]+xg[5];
    float go0=d[6]+xg[6], go1=d[7]+xg[7];
    if(s<NSE){
      const float* px=Xg+(size_t)s*G4;
#pragma unroll
      for(int r=0;r<8;r++) xg[r]=px[(r>>1)*HCd+j0+(r&1)];
    }
    c0=sigmoidf_(gf0)*c0+sigmoidf_(gi0)*tanhf(gg0);
    float h0=sigmoidf_(go0)*tanhf(c0);
    c1=sigmoidf_(gf1)*c1+sigmoidf_(gi1)*tanhf(gg1);
    float h1=sigmoidf_(go1)*tanhf(c1);
    unsigned wpar=(unsigned)((s>>1)&1);
    if(lane==0){
      uint2v pk;
      pk.x=(__float_as_uint(h0)&~1u)|wpar;
      pk.y=(__float_as_uint(h1)&~1u)|wpar;
      st_uc2(estate+(s&1)*HCd+j0,pk);
      if(s==NSE){ hT[j0]=h0; hT[j1]=h1; cT[j0]=c0; cT[j1]=c1; }
    }
  }
}

// ---------------- VAE heads ----------------
__global__ __launch_bounds__(256) void k_head(
    const float* __restrict__ hT, const float* __restrict__ cT,
    const float* __restrict__ mhw, const float* __restrict__ mhb,
    const float* __restrict__ lhw, const float* __restrict__ lhb,
    const float* __restrict__ mcw, const float* __restrict__ mcb,
    const float* __restrict__ lcw, const float* __restrict__ lcb,
    const float* __restrict__ eps_h, const float* __restrict__ eps_c,
    const float* __restrict__ cemb, const int* __restrict__ condp,
    float* zh, float* zc, float* klh, float* klc)
{
  int i=blockIdx.x;
  int tid=threadIdx.x, lane=tid&63, wv=tid>>6;
  __shared__ float sm[4];
  const float* Wm=(wv==0)?mhw:(wv==1)?lhw:(wv==2)?mcw:lcw;
  const float* vec=(wv<2)?hT:cT;
  const float* row=Wm+(size_t)i*HCd;
  float s=0.f;
  for(int k=lane;k<HCd;k+=64) s+=row[k]*vec[k];
  s=wave_reduce(s);
  if(lane==0) sm[wv]=s;
  __syncthreads();
  if(tid==0){
    float mh=sm[0]+mhb[i], lh=sm[1]+lhb[i];
    float mc=sm[2]+mcb[i], lc=sm[3]+lcb[i];
    zh[i]=eps_h[i]*expf(lh*0.5f)+mh;
    zc[i]=eps_c[i]*expf(lc*0.5f)+mc;
    klh[i]=0.5f*(mh*mh+expf(lh)-1.f-lh);
    klc[i]=0.5f*(mc*mc+expf(lc)-1.f-lc);
    if(i<Cc){
      float cd=cemb[condp[0]*Cc+i];
      zh[Hh+i]=cd; zc[Hh+i]=cd;
    }
  }
}

// decoder step 1: writes S1 (fp32, parity 0) into dstate slot1 + Hmat row 0
__global__ __launch_bounds__(256) void k_dec0(
    const float* __restrict__ Xg, const float* __restrict__ WhhO,
    const float* __restrict__ zh, const float* __restrict__ zc,
    unsigned* dstate1, float* Hmat)
{
  int tid=threadIdx.x, lane=tid&63, wv=tid>>6;
  int j=blockIdx.x*4+wv;
  float hseg[16];
#pragma unroll
  for(int e=0;e<16;e++) hseg[e]=zh[lane+64*e];
  float g[4];
#pragma unroll
  for(int q=0;q<4;q++){
    const float* p=WhhO+(size_t)(q*HCd+j)*HCd+lane;
    float s=0.f;
#pragma unroll
    for(int e=0;e<16;e++) s+=p[(size_t)e*64]*hseg[e];
    s=wave_reduce(s);
    g[q]=s+Xg[q*HCd+j];
  }
  float cc=zc[j];
  float cn=sigmoidf_(g[1])*cc+sigmoidf_(g[0])*tanhf(g[2]);
  float hn=sigmoidf_(g[3])*tanhf(cn);
  if(lane==0){
    dstate1[2*j]  =__float_as_uint(hn)&~1u;
    dstate1[2*j+1]=__float_as_uint(cn)&~1u;
    Hmat[j]=hn;
  }
}

// LDS union for fused decoder: scan vs helper
struct SmD {
  union {
    struct { float hl[2][HCd]; float cl[2][HCd]; } scan;              // 16KB
    struct { ushort As[128*32]; ushort Bs[256*32];                    // 24KB
             float smM[128][4]; float smL[128][4]; int tgt[128]; } h; // +4.5KB
  } u;
};

// ---------------- Fused decoder: scan (0..63) + streaming logits helpers ----------------
__global__ __launch_bounds__(ET) void k_decF(
    const float* __restrict__ Xg, const float* __restrict__ Weff,
    const float* __restrict__ cvec,
    const float* __restrict__ fccw, const float* __restrict__ fccb,
    const float* __restrict__ cemb, const int* __restrict__ condp,
    unsigned* dstate, float* __restrict__ Hmat, unsigned* prog,
    const ushort* __restrict__ wB, const float* __restrict__ outb,
    const int* __restrict__ tok,
    float* __restrict__ pm, float* __restrict__ pl, float* __restrict__ tgtlog)
{
  __shared__ SmD smem;
  const int tid=threadIdx.x, lane=tid&63, wv=tid>>6;
  const int bid=blockIdx.x;

  if(bid<EB){
    // ================= scan (r9 body + prog + uncached Hmat) =================
    const int wid=bid*8+wv;
    const int j0=wid*2, j1=j0+1;
    float w[8][16];
#pragma unroll
    for(int q=0;q<4;q++)
#pragma unroll
      for(int jj=0;jj<2;jj++){
        const float* p=Weff+(size_t)(q*HCd+j0+jj)*HCd+lane;
#pragma unroll
        for(int e=0;e<16;e++) w[q*2+jj][e]=p[(size_t)e*64];
      }
    const bool hasf=(j0<Hh);
    float fcc0[16], fcc1[16];
    if(hasf){
      const float* p0=fccw+(size_t)j0*HCd+lane;
      const float* p1=fccw+(size_t)j1*HCd+lane;
#pragma unroll
      for(int e=0;e<16;e++){ fcc0[e]=p0[(size_t)e*64]; fcc1[e]=p1[(size_t)e*64]; }
    } else {
#pragma unroll
      for(int e=0;e<16;e++){ fcc0[e]=0.f; fcc1[e]=0.f; }
    }
    float fb0=hasf?fccb[j0]:0.f, fb1=hasf?fccb[j1]:0.f;
    int cond=condp[0];
    float cd0=hasf?0.f:cemb[cond*Cc+(j0-Hh)];
    float cd1=hasf?0.f:cemb[cond*Cc+(j1-Hh)];
    float cv[8];
#pragma unroll
    for(int r=0;r<8;r++) cv[r]=cvec[(r>>1)*HCd+j0+(r&1)];
    float xg[8];
    { const float* px=Xg+(size_t)1*G4;
#pragma unroll
      for(int r=0;r<8;r++) xg[r]=px[(r>>1)*HCd+j0+(r&1)]; }
    const int i0=tid*2, i1=i0+1;

    for(int s=2;s<=NSD;s++){
      uint4v v;
      unsigned* st=dstate+((s-1)&1)*2*HCd;
      if(s==2){ v=*(const uint4v*)(st+4*tid); }
      else{
        const unsigned expp=(unsigned)(((s-1)>>1)&1);
        for(;;){
          v=ld_uc4(st+4*tid);
          if((((v.x^expp)|(v.y^expp)|(v.z^expp)|(v.w^expp))&1u)==0u) break;
          __builtin_amdgcn_s_sleep(1);
        }
      }
      float* hl=smem.u.scan.hl[(s-1)&1]; float* cl=smem.u.scan.cl[(s-1)&1];
      hl[i0]=__uint_as_float(v.x); cl[i0]=__uint_as_float(v.y);
      hl[i1]=__uint_as_float(v.z); cl[i1]=__uint_as_float(v.w);
      __syncthreads();
      // rows <= s-2 globally visible (each wave's step-(s-1) uncached stores
      // drained by its poll's vmcnt(0))
      if(tid==0) st_uc1(prog+bid*64,(unsigned)(s-2));
      float hseg[16], cseg[16];
#pragma unroll
      for(int e=0;e<16;e++){ hseg[e]=hl[lane+64*e]; cseg[e]=cl[lane+64*e]; }
      float d[8]; float s8=0.f, s9=0.f;
#pragma unroll
      for(int r=0;r<8;r++){ float sacc=0.f;
#pragma unroll
        for(int e=0;e<16;e++) sacc+=w[r][e]*hseg[e];
        d[r]=sacc; }
#pragma unroll
      for(int r=0;r<8;r++) d[r]=redl0(d[r]);
      if(hasf){
#pragma unroll
        for(int e=0;e<16;e++){ s8+=fcc0[e]*cseg[e]; s9+=fcc1[e]*cseg[e]; }
        s8=redl0(s8); s9=redl0(s9);
      }
      float gi0=d[0]+xg[0]+cv[0], gi1=d[1]+xg[1]+cv[1];
      float gf0=d[2]+xg[2]+cv[2], gf1=d[3]+xg[3]+cv[3];
      float gg0=d[4]+xg[4]+cv[4], gg1=d[5]+xg[5]+cv[5];
      float go0=d[6]+xg[6]+cv[6], go1=d[7]+xg[7]+cv[7];
      if(s<NSD){
        const float* px=Xg+(size_t)s*G4;
#pragma unroll
        for(int r=0;r<8;r++) xg[r]=px[(r>>1)*HCd+j0+(r&1)];
      }
      float cc0=hasf?(s8+fb0):cd0;
      float cc1=hasf?(s9+fb1):cd1;
      float cn0=sigmoidf_(gf0)*cc0+sigmoidf_(gi0)*tanhf(gg0);
      float hn0=sigmoidf_(go0)*tanhf(cn0);
      float cn1=sigmoidf_(gf1)*cc1+sigmoidf_(gi1)*tanhf(gg1);
      float hn1=sigmoidf_(go1)*tanhf(cn1);
      unsigned wpar=(unsigned)((s>>1)&1);
      if(lane==0){
        uint4v pk;
        pk.x=(__float_as_uint(hn0)&~1u)|wpar;
        pk.y=(__float_as_uint(cn0)&~1u)|wpar;
        pk.z=(__float_as_uint(hn1)&~1u)|wpar;
        pk.w=(__float_as_uint(cn1)&~1u)|wpar;
        st_uc4(dstate+(s&1)*2*HCd+2*j0,pk);
        uint2v hm; hm.x=__float_as_uint(hn0); hm.y=__float_as_uint(hn1);
        st_uc2((unsigned*)(Hmat+(size_t)(s-1)*HCd+j0),hm);
      }
    }
    asm volatile("s_waitcnt vmcnt(0)");
    __syncthreads();
    if(tid==0) st_uc1(prog+bid*64,(unsigned)(NSD-1));
    return;
  }

  // ================= helper: 128x256 logits tiles + per-tile softmax partials =================
  const int hb=bid-EB;
  const int wid=tid>>6;
  const int r15=lane&15, g=lane>>4;
  const int wm=wid>>2, wn=wid&3;
  const int srA=tid>>2, shA=tid&3;     // A: 128 rows x 4 chunks of 8 floats
  const int srB=tid>>1, shB=tid&1;     // B: 256 cols x 2 chunks of 16 bf16

  for(int u=hb; u<8*2*NCT; u+=FGRID-EB){
    int chunk=u/(2*NCT), t=u%(2*NCT);
    int rt=t/NCT, ct=t%NCT;
    int m0=chunk*256+rt*128, n0=ct*256;
    unsigned need=(unsigned)((m0+127<NSD)?(m0+127):(NSD-1));
    if(wv==0){
      for(;;){
        unsigned pv=ld_uc1(prog+lane*64);
        if(wave_min_u(pv)>=need) break;
        __builtin_amdgcn_s_sleep(32);
      }
    }
    if(tid<128){
      int grow=m0+tid;
      smem.u.h.tgt[tid]=(grow<NSD)?tok[grow+1]:-1;
    }
    __syncthreads();

    f32x4 acc[4][4]={};
    const float*  aptr=Hmat+(size_t)(m0+srA)*HCd + shA*8;
    const ushort* bptr=wB  +(size_t)(n0+srB)*HCd + shB*16;
    bool aok=(m0+srA)<NSD;
    for(int k0=0;k0<HCd;k0+=32){
      float4 va0={0,0,0,0}, va1={0,0,0,0};
      if(aok){ va0=*(const float4*)(aptr+k0); va1=*(const float4*)(aptr+k0+4); }
      uint4v pa={pk_bf16(va0.x,va0.y),pk_bf16(va0.z,va0.w),pk_bf16(va1.x,va1.y),pk_bf16(va1.z,va1.w)};
      int sxA=(srA>>1)&3;
      *(uint4v*)&smem.u.h.As[srA*32+(shA^sxA)*8]=pa;
      uint4v qb0=*(const uint4v*)(bptr+k0);
      uint4v qb1=*(const uint4v*)(bptr+k0+8);
      int sxB=(srB>>1)&3;
      int u0=(shB*2+0)^sxB, u1=(shB*2+1)^sxB;
      *(uint4v*)&smem.u.h.Bs[srB*32+u0*8]=qb0;
      *(uint4v*)&smem.u.h.Bs[srB*32+u1*8]=qb1;
      __syncthreads();
      bf16x8 af[4], bf[4];
#pragma unroll
      for(int i=0;i<4;i++){
        int ra=wm*64+i*16+r15;
        af[i]=*(const bf16x8*)&smem.u.h.As[ra*32+((g^((ra>>1)&3))<<3)];
        int rb=wn*64+i*16+r15;
        bf[i]=*(const bf16x8*)&smem.u.h.Bs[rb*32+((g^((rb>>1)&3))<<3)];
      }
#pragma unroll
      for(int i=0;i<4;i++)
#pragma unroll
        for(int j=0;j<4;j++)
          acc[i][j]=__builtin_amdgcn_mfma_f32_16x16x32_bf16(af[i],bf[j],acc[i][j],0,0,0);
      __syncthreads();
    }
    float bj[4];
#pragma unroll
    for(int j=0;j<4;j++) bj[j]=outb[n0+wn*64+j*16+r15];
#pragma unroll
    for(int i=0;i<4;i++)
#pragma unroll
    for(int r=0;r<4;r++){
      int rloc=wm*64+i*16+g*4+r;
      int tg=smem.u.h.tgt[rloc];
      float vv[4];
#pragma unroll
      for(int j=0;j<4;j++){
        vv[j]=acc[i][j][r]+bj[j];
        if(n0+wn*64+j*16+r15==tg) tgtlog[m0+rloc]=vv[j];
      }
      float mloc=fmaxf(fmaxf(vv[0],vv[1]),fmaxf(vv[2],vv[3]));
      float lloc=__expf(vv[0]-mloc)+__expf(vv[1]-mloc)+__expf(vv[2]-mloc)+__expf(vv[3]-mloc);
#pragma unroll
      for(int o=1;o<16;o<<=1){
        float mo=__shfl_xor(mloc,o,64), lo=__shfl_xor(lloc,o,64);
        float mn=fmaxf(mloc,mo);
        lloc=lloc*__expf(mloc-mn)+lo*__expf(mo-mn);
        mloc=mn;
      }
      if(r15==0){ smem.u.h.smM[rloc][wn]=mloc; smem.u.h.smL[rloc][wn]=lloc; }
    }
    __syncthreads();
    if(tid<128){
      int grow=m0+tid;
      if(grow<NSD){
        float M=-3e38f;
#pragma unroll
        for(int q2=0;q2<4;q2++) M=fmaxf(M,smem.u.h.smM[tid][q2]);
        float L=0.f;
#pragma unroll
        for(int q2=0;q2<4;q2++) L+=smem.u.h.smL[tid][q2]*__expf(smem.u.h.smM[tid][q2]-M);
        pm[(size_t)grow*NCT+ct]=M;
        pl[(size_t)grow*NCT+ct]=L;
      }
    }
    __syncthreads();
  }
}

// merge col-tile partials -> ce[row]
__global__ __launch_bounds__(256) void k_cemerge(const float* __restrict__ pm,
    const float* __restrict__ pl, const float* __restrict__ tgtlog,
    float* __restrict__ ce)
{
  int grow=blockIdx.x*256+threadIdx.x;
  if(grow>=NSD) return;
  float M=-3e38f;
  for(int c=0;c<NCT;c++) M=fmaxf(M,pm[(size_t)grow*NCT+c]);
  float L=0.f;
  for(int c=0;c<NCT;c++) L+=pl[(size_t)grow*NCT+c]*__expf(pm[(size_t)grow*NCT+c]-M);
  ce[grow]=M+logf(L)-tgtlog[grow];
}

// ---------------- fallback decoder scan (r9, standalone) ----------------
__global__ __launch_bounds__(ET,2) void k_dec9(
    const float* __restrict__ Xg, const float* __restrict__ Weff,
    const float* __restrict__ cvec,
    const float* __restrict__ fccw, const float* __restrict__ fccb,
    const float* __restrict__ cemb, const int* __restrict__ condp,
    unsigned* dstate, float* __restrict__ Hmat)
{
  __shared__ float hlds[2][HCd];
  __shared__ float clds[2][HCd];
  const int tid=threadIdx.x, lane=tid&63, wv=tid>>6;
  const int wid=blockIdx.x*8+wv;
  const int j0=wid*2, j1=j0+1;
  float w[8][16];
#pragma unroll
  for(int q=0;q<4;q++)
#pragma unroll
    for(int jj=0;jj<2;jj++){
      const float* p=Weff+(size_t)(q*HCd+j0+jj)*HCd+lane;
#pragma unroll
      for(int e=0;e<16;e++) w[q*2+jj][e]=p[(size_t)e*64];
    }
  const bool hasf=(j0<Hh);
  float fcc0[16], fcc1[16];
  if(hasf){
    const float* p0=fccw+(size_t)j0*HCd+lane;
    const float* p1=fccw+(size_t)j1*HCd+lane;
#pragma unroll
    for(int e=0;e<16;e++){ fcc0[e]=p0[(size_t)e*64]; fcc1[e]=p1[(size_t)e*64]; }
  } else {
#pragma unroll
    for(int e=0;e<16;e++){ fcc0[e]=0.f; fcc1[e]=0.f; }
  }
  float fb0=hasf?fccb[j0]:0.f, fb1=hasf?fccb[j1]:0.f;
  int cond=condp[0];
  float cd0=hasf?0.f:cemb[cond*Cc+(j0-Hh)];
  float cd1=hasf?0.f:cemb[cond*Cc+(j1-Hh)];
  float cv[8];
#pragma unroll
  for(int r=0;r<8;r++) cv[r]=cvec[(r>>1)*HCd+j0+(r&1)];
  float xg[8];
  { const float* px=Xg+(size_t)1*G4;
#pragma unroll
    for(int r=0;r<8;r++) xg[r]=px[(r>>1)*HCd+j0+(r&1)]; }
  const int i0=tid*2, i1=i0+1;

  for(int s=2;s<=NSD;s++){
    uint4v v;
    unsigned* st=dstate+((s-1)&1)*2*HCd;
    if(s==2){ v=*(const uint4v*)(st+4*tid); }
    else{
      const unsigned expp=(unsigned)(((s-1)>>1)&1);
      for(;;){
        v=ld_uc4(st+4*tid);
        if((((v.x^expp)|(v.y^expp)|(v.z^expp)|(v.w^expp))&1u)==0u) break;
        __builtin_amdgcn_s_sleep(1);
      }
    }
    float* hl=hlds[(s-1)&1]; float* cl=clds[(s-1)&1];
    hl[i0]=__uint_as_float(v.x); cl[i0]=__uint_as_float(v.y);
    hl[i1]=__uint_as_float(v.z); cl[i1]=__uint_as_float(v.w);
    __syncthreads();
    float hseg[16], cseg[16];
#pragma unroll
    for(int e=0;e<16;e++){ hseg[e]=hl[lane+64*e]; cseg[e]=cl[lane+64*e]; }
    float d[8]; float s8=0.f, s9=0.f;
#pragma unroll
    for(int r=0;r<8;r++){ float sacc=0.f;
#pragma unroll
      for(int e=0;e<16;e++) sacc+=w[r][e]*hseg[e];
      d[r]=sacc; }
#pragma unroll
    for(int r=0;r<8;r++) d[r]=redl0(d[r]);
    if(hasf){
#pragma unroll
      for(int e=0;e<16;e++){ s8+=fcc0[e]*cseg[e]; s9+=fcc1[e]*cseg[e]; }
      s8=redl0(s8); s9=redl0(s9);
    }
    float gi0=d[0]+xg[0]+cv[0], gi1=d[1]+xg[1]+cv[1];
    float gf0=d[2]+xg[2]+cv[2], gf1=d[3]+xg[3]+cv[3];
    float gg0=d[4]+xg[4]+cv[4], gg1=d[5]+xg[5]+cv[5];
    float go0=d[6]+xg[6]+cv[6], go1=d[7]+xg[7]+cv[7];
    if(s<NSD){
      const float* px=Xg+(size_t)s*G4;
#pragma unroll
      for(int r=0;r<8;r++) xg[r]=px[(r>>1)*HCd+j0+(r&1)];
    }
    float cc0=hasf?(s8+fb0):cd0;
    float cc1=hasf?(s9+fb1):cd1;
    float cn0=sigmoidf_(gf0)*cc0+sigmoidf_(gi0)*tanhf(gg0);
    float hn0=sigmoidf_(go0)*tanhf(cn0);
    float cn1=sigmoidf_(gf1)*cc1+sigmoidf_(gi1)*tanhf(gg1);
    float hn1=sigmoidf_(go1)*tanhf(cn1);
    unsigned wpar=(unsigned)((s>>1)&1);
    if(lane==0){
      uint4v pk;
      pk.x=(__float_as_uint(hn0)&~1u)|wpar;
      pk.y=(__float_as_uint(cn0)&~1u)|wpar;
      pk.z=(__float_as_uint(hn1)&~1u)|wpar;
      pk.w=(__float_as_uint(cn1)&~1u)|wpar;
      st_uc4(dstate+(s&1)*2*HCd+2*j0,pk);
      Hmat[(size_t)(s-1)*HCd+j0]=hn0; Hmat[(size_t)(s-1)*HCd+j1]=hn1;
    }
  }
}

// fallback logits GEMM (in-kernel B conversion)
__global__ __launch_bounds__(256) void k_gemm_mfma(
    const float* __restrict__ A, const float* __restrict__ B,
    const float* __restrict__ bias, float* __restrict__ Cm, int M)
{
  __shared__ ushort As[TBM*TBK];
  __shared__ ushort Bs[TBN*TBK];
  int tid=threadIdx.x;
  int m0=blockIdx.x*TBM, n0=blockIdx.y*TBN;
  int wid=tid>>6, lane=tid&63;
  int wm=wid>>1, wn=wid&1;
  int r15=lane&15, g=lane>>4;
  f32x4 acc[4][4]={};
  int srow=tid>>1, shalf=tid&1;
  const float* aptr=A+(size_t)(m0+srow)*HCd + shalf*16;
  const float* bptr=B+(size_t)(n0+srow)*HCd + shalf*16;
  bool aok=(m0+srow)<M;
  float bj[4];
#pragma unroll
  for(int j=0;j<4;j++) bj[j]=bias[n0+wn*64+j*16+r15];
  for(int k0=0;k0<HCd;k0+=TBK){
    float4 va0={0,0,0,0},va1={0,0,0,0},va2={0,0,0,0},va3={0,0,0,0};
    if(aok){
      va0=*(const float4*)(aptr+k0);   va1=*(const float4*)(aptr+k0+4);
      va2=*(const float4*)(aptr+k0+8); va3=*(const float4*)(aptr+k0+12);
    }
    float4 vb0=*(const float4*)(bptr+k0),   vb1=*(const float4*)(bptr+k0+4);
    float4 vb2=*(const float4*)(bptr+k0+8), vb3=*(const float4*)(bptr+k0+12);
    uint4v pa0={pk_bf16(va0.x,va0.y),pk_bf16(va0.z,va0.w),pk_bf16(va1.x,va1.y),pk_bf16(va1.z,va1.w)};
    uint4v pa1={pk_bf16(va2.x,va2.y),pk_bf16(va2.z,va2.w),pk_bf16(va3.x,va3.y),pk_bf16(va3.z,va3.w)};
    uint4v pb0={pk_bf16(vb0.x,vb0.y),pk_bf16(vb0.z,vb0.w),pk_bf16(vb1.x,vb1.y),pk_bf16(vb1.z,vb1.w)};
    uint4v pb1={pk_bf16(vb2.x,vb2.y),pk_bf16(vb2.z,vb2.w),pk_bf16(vb3.x,vb3.y),pk_bf16(vb3.z,vb3.w)};
    int sx=(srow>>1)&3;
    int u0=(shalf*2+0)^sx, u1=(shalf*2+1)^sx;
    *(uint4v*)&As[srow*32+u0*8]=pa0; *(uint4v*)&As[srow*32+u1*8]=pa1;
    *(uint4v*)&Bs[srow*32+u0*8]=pb0; *(uint4v*)&Bs[srow*32+u1*8]=pb1;
    __syncthreads();
    bf16x8 af[4], bf[4];
#pragma unroll
    for(int i=0;i<4;i++){
      int ra=wm*64+i*16+r15;
      af[i]=*(const bf16x8*)&As[ra*32+((g^((ra>>1)&3))<<3)];
      int rb=wn*64+i*16+r15;
      bf[i]=*(const bf16x8*)&Bs[rb*32+((g^((rb>>1)&3))<<3)];
    }
#pragma unroll
    for(int i=0;i<4;i++)
#pragma unroll
      for(int j=0;j<4;j++)
        acc[i][j]=__builtin_amdgcn_mfma_f32_16x16x32_bf16(af[i],bf[j],acc[i][j],0,0,0);
    __syncthreads();
  }
#pragma unroll
  for(int i=0;i<4;i++){
    int grow0=m0+wm*64+i*16+g*4;
#pragma unroll
    for(int j=0;j<4;j++){
      int gcol=n0+wn*64+j*16+r15;
#pragma unroll
      for(int r=0;r<4;r++){
        int grow=grow0+r;
        if(grow<M) Cm[(size_t)grow*VSZ+gcol]=acc[i][j][r]+bj[j];
      }
    }
  }
}

// per-row cross-entropy (fallback tail)
__global__ __launch_bounds__(256) void k_ce(const float* __restrict__ logits,
    const int* __restrict__ tok, int base, float* __restrict__ ce)
{
  int r=blockIdx.x;
  const float* row=logits+(size_t)r*VSZ;
  int tid=threadIdx.x, lane=tid&63, wv=tid>>6;
  float m=-1e30f, s=0.f;
  for(int i=tid;i<VSZ;i+=256){
    float v=row[i];
    if(v>m){ s=s*__expf(m-v)+1.f; m=v; }
    else s+=__expf(v-m);
  }
#pragma unroll
  for(int o=32;o;o>>=1){
    float mo=__shfl_xor(m,o,64), so=__shfl_xor(s,o,64);
    float mn=fmaxf(m,mo);
    s=s*__expf(m-mn)+so*__expf(mo-mn);
    m=mn;
  }
  __shared__ float smm[4], sms[4];
  if(lane==0){ smm[wv]=m; sms[wv]=s; }
  __syncthreads();
  if(tid==0){
    float M2=fmaxf(fmaxf(smm[0],smm[1]),fmaxf(smm[2],smm[3]));
    float S2=sms[0]*__expf(smm[0]-M2)+sms[1]*__expf(smm[1]-M2)
            +sms[2]*__expf(smm[2]-M2)+sms[3]*__expf(smm[3]-M2);
    int tgt=tok[base+r+1];
    ce[base+r]=M2+logf(S2)-row[tgt];
  }
}

__global__ __launch_bounds__(256) void k_final(const float* __restrict__ ce,
    const float* __restrict__ klh, const float* __restrict__ klc,
    const float* __restrict__ kldw, float* __restrict__ outp)
{
  int tid=threadIdx.x, lane=tid&63, wv=tid>>6;
  float s0=0,s1=0,s2=0;
  for(int i=tid;i<NSD;i+=256) s0+=ce[i];
  for(int i=tid;i<Hh;i+=256){ s1+=klh[i]; s2+=klc[i]; }
  s0=wave_reduce(s0); s1=wave_reduce(s1); s2=wave_reduce(s2);
  __shared__ float sm[3][4];
  if(lane==0){ sm[0][wv]=s0; sm[1][wv]=s1; sm[2][wv]=s2; }
  __syncthreads();
  if(tid==0){
    float ces=sm[0][0]+sm[0][1]+sm[0][2]+sm[0][3];
    float kh =sm[1][0]+sm[1][1]+sm[1][2]+sm[1][3];
    float kc =sm[2][0]+sm[2][1]+sm[2][2]+sm[2][3];
    float rec=ces/(float)NSD;
    outp[0]=rec+(kh+kc)*kldw[0];
    outp[1]=rec; outp[2]=kh; outp[3]=kc;
  }
}

extern "C" void kernel_launch(void* const* d_in, const int* in_sizes, int n_in,
                              void* d_out, int out_size, void* d_ws, size_t ws_size,
                              hipStream_t stream) {
  const int*   tok   =(const int*)  d_in[0];
  const int*   cond  =(const int*)  d_in[1];
  const float* eps_h =(const float*)d_in[2];
  const float* eps_c =(const float*)d_in[3];
  const float* kldw  =(const float*)d_in[4];
  const float* enc_embed=(const float*)d_in[5];
  const float* enc_cemb =(const float*)d_in[6];
  const float* enc_Wih  =(const float*)d_in[7];
  const float* enc_Whh  =(const float*)d_in[8];
  const float* enc_bih  =(const float*)d_in[9];
  const float* enc_bhh  =(const float*)d_in[10];
  const float* fc_mh_w=(const float*)d_in[11];
  const float* fc_mh_b=(const float*)d_in[12];
  const float* fc_lh_w=(const float*)d_in[13];
  const float* fc_lh_b=(const float*)d_in[14];
  const float* fc_mc_w=(const float*)d_in[15];
  const float* fc_mc_b=(const float*)d_in[16];
  const float* fc_lc_w=(const float*)d_in[17];
  const float* fc_lc_b=(const float*)d_in[18];
  const float* dec_embed=(const float*)d_in[19];
  const float* dec_cemb =(const float*)d_in[20];
  const float* dec_Wih  =(const float*)d_in[21];
  const float* dec_Whh  =(const float*)d_in[22];
  const float* dec_bih  =(const float*)d_in[23];
  const float* dec_bhh  =(const float*)d_in[24];
  const float* fc_h_w=(const float*)d_in[25];
  const float* fc_h_b=(const float*)d_in[26];
  const float* fc_c_w=(const float*)d_in[27];
  const float* fc_c_b=(const float*)d_in[28];
  const float* out_w=(const float*)d_in[29];
  const float* out_b=(const float*)d_in[30];

  float* ws=(float*)d_ws;
  size_t off=0;
  unsigned* prog  =(unsigned*)(ws+off); off+=4096;    // 64 words, 256B apart
  unsigned* estate=(unsigned*)(ws+off); off+=2*HCd;
  unsigned* dstate=(unsigned*)(ws+off); off+=4*HCd;
  float* cvec=ws+off; off+=G4;
  float* Weff=ws+off; off+=(size_t)G4*HCd;
  float* hT  =ws+off; off+=HCd;
  float* cT  =ws+off; off+=HCd;
  float* zh  =ws+off; off+=HCd;
  float* zc  =ws+off; off+=HCd;
  float* klh =ws+off; off+=Hh;
  float* klc =ws+off; off+=Hh;
  float* Hmat=ws+off; off+=(size_t)NSD*HCd;
  float* ce  =ws+off; off+=2048;
  float* pm  =ws+off; off+=(size_t)2048*NCT;
  float* pl  =ws+off; off+=(size_t)2048*NCT;
  float* tgtlog=ws+off; off+=2048;
  size_t avail=ws_size/4;
  size_t xa_sz=(size_t)NSE*G4, xb_sz=(size_t)NSD*G4;
  size_t wb_sz=(size_t)VSZ*HCd/2;
  float* XA=ws+off;
  bool dual=(off+xa_sz+xb_sz)<=avail;
  float* XB=dual?(XA+xa_sz):XA;
  bool wbok=dual && (off+xa_sz+xb_sz+wb_sz)<=avail;
  unsigned* wB=(unsigned*)(XB+xb_sz);
  size_t region=(avail>off)?(avail-off):0;
  int chunk=256;
  if(!dual){
    if((size_t)chunk*VSZ>region){ chunk=(int)(region/(size_t)VSZ); if(chunk<1)chunk=1; }
  }
  float* lbuf=XA;

  k_init12<<<1,256,0,stream>>>(prog,estate,dstate,enc_cemb,cond);
  { dim3 g((NSE+GBM-1)/GBM, G4/GBN);
    k_xgemm<<<g,256,0,stream>>>(enc_embed,enc_Wih,enc_bih,enc_bhh,tok,1,NSE,XA); }
  k_encF<<<FGRID,ET,0,stream>>>(XA,enc_Whh,estate,hT,cT,
                                dec_Whh,fc_h_w,Weff,
                                dec_embed,dec_Wih,dec_bih,dec_bhh,tok,XB,
                                out_w,wB,fc_h_b,dec_cemb,cond,cvec,
                                dual?1:0, wbok?1:0);
  k_head<<<Hh,256,0,stream>>>(hT,cT,fc_mh_w,fc_mh_b,fc_lh_w,fc_lh_b,
                              fc_mc_w,fc_mc_b,fc_lc_w,fc_lc_b,
                              eps_h,eps_c,dec_cemb,cond,zh,zc,klh,klc);
  if(!dual){
    dim3 g((NSD+TBM-1)/TBM, G4/TBN);
    k_xgemm_mfma<<<g,256,0,stream>>>(dec_embed,dec_Wih,dec_bih,dec_bhh,tok,NSD,XB);
  }
  k_dec0<<<256,256,0,stream>>>(XB,dec_Whh,zh,zc,dstate+2*HCd,Hmat);
  if(dual&&wbok){
    // fused decoder scan + streaming logits/softmax helpers
    k_decF<<<FGRID,ET,0,stream>>>(XB,Weff,cvec,fc_c_w,fc_c_b,dec_cemb,cond,
                                  dstate,Hmat,prog,(const ushort*)wB,out_b,tok,
                                  pm,pl,tgtlog);
    k_cemerge<<<(NSD+255)/256,256,0,stream>>>(pm,pl,tgtlog,ce);
  } else {
    k_dec9<<<EB,ET,0,stream>>>(XB,Weff,cvec,fc_c_w,fc_c_b,dec_cemb,cond,dstate,Hmat);
    for(int base=0;base<NSD;base+=chunk){
      int rows=NSD-base; if(rows>chunk) rows=chunk;
      dim3 g((rows+TBM-1)/TBM, VSZ/TBN);
      k_gemm_mfma<<<g,256,0,stream>>>(Hmat+(size_t)base*HCd,out_w,out_b,lbuf,rows);
      k_ce<<<rows,256,0,stream>>>(lbuf,tok,base,ce);
    }
  }
  k_final<<<1,256,0,stream>>>(ce,klh,klc,kldw,(float*)d_out);
}

// Round 13
// 12849.100 us; speedup vs baseline: 1.1501x; 1.0107x over previous
//
#include <hip/hip_runtime.h>
#include <math.h>

// Problem sizes (fixed)
#define VSZ 32000
#define Hh  768
#define Cc  256
#define HCd 1024
#define G4  4096
#define NSE 2046   // encoder steps
#define NSD 2047   // decoder steps

#define EB 64
#define ET 512
#define FGRID 256
#define NCT 125      // 256-wide col tiles over 32000

// Seqlock state layout: 512 slices per slot, one 256B cacheline per slice
// (channel-spread). enc slice = 2 dwords used; dec slice = 4 dwords used.
#define SS 64                 // dwords between slices (256B)
#define SLOT (512*SS)         // dwords per slot (128KB)

typedef __attribute__((ext_vector_type(4))) unsigned uint4v;
typedef __attribute__((ext_vector_type(2))) unsigned uint2v;
typedef __attribute__((ext_vector_type(8))) short bf16x8;
typedef __attribute__((ext_vector_type(4))) float f32x4;

__device__ __forceinline__ float sigmoidf_(float x){ return 1.0f/(1.0f+expf(-x)); }

__device__ __forceinline__ float wave_reduce(float v){
#pragma unroll
  for(int o=32;o;o>>=1) v += __shfl_xor(v,o,64);
  return v;
}
__device__ __forceinline__ unsigned wave_min_u(unsigned v){
#pragma unroll
  for(int o=32;o;o>>=1){ unsigned x=__shfl_xor(v,o,64); v=(x<v)?x:v; }
  return v;
}
// Reduce 64 lanes; total valid in lane 0.
__device__ __forceinline__ float redl0(float v){
  int x;
  x=__builtin_amdgcn_update_dpp(0,__float_as_int(v),0xB1,0xf,0xf,true); v+=__int_as_float(x); // ^1
  x=__builtin_amdgcn_update_dpp(0,__float_as_int(v),0x4E,0xf,0xf,true); v+=__int_as_float(x); // ^2
  v+=__int_as_float(__builtin_amdgcn_ds_swizzle(__float_as_int(v),0x101F)); // ^4
  v+=__int_as_float(__builtin_amdgcn_ds_swizzle(__float_as_int(v),0x201F)); // ^8
  v+=__int_as_float(__builtin_amdgcn_ds_swizzle(__float_as_int(v),0x401F)); // ^16
  v+=__int_as_float(__builtin_amdgcn_readlane(__float_as_int(v),32));
  return v;
}

// Device-scope (coherence-point) ops. Per-dword LSB parity self-validates.
__device__ __forceinline__ unsigned ld_uc1(const unsigned* p){
  unsigned r;
  asm volatile("global_load_dword %0, %1, off sc0 sc1\n\ts_waitcnt vmcnt(0)"
               : "=v"(r) : "v"(p) : "memory");
  return r;
}
__device__ __forceinline__ uint2v ld_uc2(const unsigned* p){
  uint2v r;
  asm volatile("global_load_dwordx2 %0, %1, off sc0 sc1\n\ts_waitcnt vmcnt(0)"
               : "=v"(r) : "v"(p) : "memory");
  return r;
}
__device__ __forceinline__ uint4v ld_uc4(const unsigned* p){
  uint4v r;
  asm volatile("global_load_dwordx4 %0, %1, off sc0 sc1\n\ts_waitcnt vmcnt(0)"
               : "=v"(r) : "v"(p) : "memory");
  return r;
}
__device__ __forceinline__ void st_uc1(unsigned* p, unsigned v){
  asm volatile("global_store_dword %0, %1, off sc0 sc1" :: "v"(p), "v"(v) : "memory");
}
__device__ __forceinline__ void st_uc2(unsigned* p, uint2v v){
  asm volatile("global_store_dwordx2 %0, %1, off sc0 sc1" :: "v"(p), "v"(v) : "memory");
}
__device__ __forceinline__ void st_uc4(unsigned* p, uint4v v){
  asm volatile("global_store_dwordx4 %0, %1, off sc0 sc1" :: "v"(p), "v"(v) : "memory");
}

// fp32->bf16 RNE, pack two per dword
__device__ __forceinline__ unsigned pk_bf16(float a, float b){
  unsigned ua=__float_as_uint(a); ua += 0x7fffu + ((ua>>16)&1u);
  unsigned ub=__float_as_uint(b); ub += 0x7fffu + ((ub>>16)&1u);
  return (ua>>16) | (ub & 0xffff0000u);
}

// init (re-runs every replay): prog zero; enc S0 slot0 parity0, slot1 stale;
// dec both slots zeroed (stale: first poll expects parity 1).
__global__ void k_init13(unsigned* prog, unsigned* estate, unsigned* dstate,
                         const float* __restrict__ cemb, const int* __restrict__ condp){
  int tid=threadIdx.x;
  int cond=condp[0];
  for(int i=tid;i<4096;i+=256) prog[i]=0u;
  for(int i=tid;i<512;i+=256){
    int j0=2*i, j1=2*i+1;
    float h0=(j0<Hh)?0.f:cemb[cond*Cc+(j0-Hh)];
    float h1=(j1<Hh)?0.f:cemb[cond*Cc+(j1-Hh)];
    estate[i*SS]  =__float_as_uint(h0)&~1u;
    estate[i*SS+1]=__float_as_uint(h1)&~1u;
    estate[SLOT+i*SS]  =1u;
    estate[SLOT+i*SS+1]=1u;
    dstate[i*SS]=0u; dstate[i*SS+1]=0u; dstate[i*SS+2]=0u; dstate[i*SS+3]=0u;
    dstate[SLOT+i*SS]=0u; dstate[SLOT+i*SS+1]=0u;
    dstate[SLOT+i*SS+2]=0u; dstate[SLOT+i*SS+3]=0u;
  }
}

#define GBM 128
#define GBN 128
#define GBK 16
#define TBM 128
#define TBN 128
#define TBK 32

// Shared-memory union for the fused encoder kernel.
struct SmU {
  union {
    float hlds[2][HCd];
    struct { float As[GBK][GBM]; float Bs[GBK][GBN]; } wf;
    struct { ushort As[TBM*TBK]; ushort Bs[TBN*TBK]; } xd;
  } u;
};

// ---- helper units (encoder-phase prologue) ----
__device__ void weff_unit(int u, const float* __restrict__ A,
    const float* __restrict__ B, float* __restrict__ Cm, SmU& sm, int tid){
  int m0=(u>>3)*GBM, n0=(u&7)*GBN;
  int tm=tid>>4, tn=tid&15;
  float acc[8][8]={};
  for(int k0=0;k0<Hh;k0+=GBK){
    if(tid<256){
#pragma unroll
      for(int uu=0;uu<2;uu++){
        int idx=tid*2+uu;
        int row=idx>>2, q=idx&3;
        float4 v=*(const float4*)(A+(size_t)(m0+row)*HCd + k0+q*4);
        sm.u.wf.As[q*4+0][row]=v.x; sm.u.wf.As[q*4+1][row]=v.y;
        sm.u.wf.As[q*4+2][row]=v.z; sm.u.wf.As[q*4+3][row]=v.w;
        int kk=idx>>5, nc=idx&31;
        float4 w=*(const float4*)(B+(size_t)(k0+kk)*HCd + n0+nc*4);
        *(float4*)&sm.u.wf.Bs[kk][nc*4]=w;
      }
    }
    __syncthreads();
    if(tid<256){
#pragma unroll
      for(int kk=0;kk<GBK;kk++){
        float a[8],b[8];
        *(float4*)&a[0]=*(float4*)&sm.u.wf.As[kk][tm*8]; *(float4*)&a[4]=*(float4*)&sm.u.wf.As[kk][tm*8+4];
        *(float4*)&b[0]=*(float4*)&sm.u.wf.Bs[kk][tn*8]; *(float4*)&b[4]=*(float4*)&sm.u.wf.Bs[kk][tn*8+4];
#pragma unroll
        for(int i=0;i<8;i++)
#pragma unroll
          for(int j=0;j<8;j++) acc[i][j]+=a[i]*b[j];
      }
    }
    __syncthreads();
  }
  if(tid<256){
#pragma unroll
    for(int i=0;i<8;i++)
#pragma unroll
      for(int j=0;j<8;j++)
        Cm[(size_t)(m0+tm*8+i)*HCd + n0+tn*8+j]=acc[i][j];
  }
}

__device__ void xdec_unit(int q, const float* __restrict__ emb,
    const float* __restrict__ Wih, const float* __restrict__ b1,
    const float* __restrict__ b2, const int* __restrict__ tok,
    float* __restrict__ X, SmU& sm, int tid){
  int m0=(q>>5)*TBM, n0=(q&31)*TBN;
  int wid=tid>>6, lane=tid&63;
  int wm=wid>>1, wn=wid&1;
  int r15=lane&15, g=lane>>4;
  f32x4 acc[4][4]={};
  int srow=tid>>1, shalf=tid&1;
  int arow=m0+srow;
  bool act=(tid<256);
  int atok=(act&&arow<NSD)?tok[arow]:0;
  const float* aptr=emb+(size_t)atok*HCd + shalf*16;
  const float* bptr=Wih+(size_t)(n0+srow)*HCd + shalf*16;
  bool aok=act&&(arow<NSD);
  float bj[4];
  if(act){
#pragma unroll
    for(int j=0;j<4;j++){ int n=n0+wn*64+j*16+r15; bj[j]=b1[n]+b2[n]; }
  }
  for(int k0=0;k0<HCd;k0+=TBK){
    if(act){
      float4 va0={0,0,0,0},va1={0,0,0,0},va2={0,0,0,0},va3={0,0,0,0};
      if(aok){
        va0=*(const float4*)(aptr+k0);   va1=*(const float4*)(aptr+k0+4);
        va2=*(const float4*)(aptr+k0+8); va3=*(const float4*)(aptr+k0+12);
      }
      float4 vb0=*(const float4*)(bptr+k0),   vb1=*(const float4*)(bptr+k0+4);
      float4 vb2=*(const float4*)(bptr+k0+8), vb3=*(const float4*)(bptr+k0+12);
      uint4v pa0={pk_bf16(va0.x,va0.y),pk_bf16(va0.z,va0.w),pk_bf16(va1.x,va1.y),pk_bf16(va1.z,va1.w)};
      uint4v pa1={pk_bf16(va2.x,va2.y),pk_bf16(va2.z,va2.w),pk_bf16(va3.x,va3.y),pk_bf16(va3.z,va3.w)};
      uint4v pb0={pk_bf16(vb0.x,vb0.y),pk_bf16(vb0.z,vb0.w),pk_bf16(vb1.x,vb1.y),pk_bf16(vb1.z,vb1.w)};
      uint4v pb1={pk_bf16(vb2.x,vb2.y),pk_bf16(vb2.z,vb2.w),pk_bf16(vb3.x,vb3.y),pk_bf16(vb3.z,vb3.w)};
      int sx=(srow>>1)&3;
      int u0=(shalf*2+0)^sx, u1=(shalf*2+1)^sx;
      *(uint4v*)&sm.u.xd.As[srow*32+u0*8]=pa0; *(uint4v*)&sm.u.xd.As[srow*32+u1*8]=pa1;
      *(uint4v*)&sm.u.xd.Bs[srow*32+u0*8]=pb0; *(uint4v*)&sm.u.xd.Bs[srow*32+u1*8]=pb1;
    }
    __syncthreads();
    if(act){
      bf16x8 af[4], bf[4];
#pragma unroll
      for(int i=0;i<4;i++){
        int ra=wm*64+i*16+r15;
        af[i]=*(const bf16x8*)&sm.u.xd.As[ra*32+((g^((ra>>1)&3))<<3)];
        int rb=wn*64+i*16+r15;
        bf[i]=*(const bf16x8*)&sm.u.xd.Bs[rb*32+((g^((rb>>1)&3))<<3)];
      }
#pragma unroll
      for(int i=0;i<4;i++)
#pragma unroll
        for(int j=0;j<4;j++)
          acc[i][j]=__builtin_amdgcn_mfma_f32_16x16x32_bf16(af[i],bf[j],acc[i][j],0,0,0);
    }
    __syncthreads();
  }
  if(act){
#pragma unroll
    for(int i=0;i<4;i++){
      int grow0=m0+wm*64+i*16+g*4;
#pragma unroll
      for(int j=0;j<4;j++){
        int gcol=n0+wn*64+j*16+r15;
#pragma unroll
        for(int r=0;r<4;r++){
          int grow=grow0+r;
          if(grow<NSD) X[(size_t)grow*G4+gcol]=acc[i][j][r]+bj[j];
        }
      }
    }
  }
}

__device__ void cvtb_unit(int i, const float* __restrict__ B,
    unsigned* __restrict__ Bb, int tid){
  size_t base=(size_t)i*128000u;
  for(size_t x=base+tid; x<base+128000u; x+=ET){
    float4 v=*(const float4*)(B+x*4);
    Bb[x*2]  =pk_bf16(v.x,v.y);
    Bb[x*2+1]=pk_bf16(v.z,v.w);
  }
}

__device__ void dconst_unit(int i, const float* __restrict__ Whh,
    const float* __restrict__ fhb, const float* __restrict__ cemb,
    int cond, float* __restrict__ cvec, int tid){
  int lane=tid&63, wv=tid>>6;
  for(int r=i*256+wv; r<i*256+256; r+=8){
    const float* row=Whh+(size_t)r*HCd;
    float s=0.f;
    for(int k=lane;k<Hh;k+=64) s+=row[k]*fhb[k];
    for(int k=lane;k<Cc;k+=64) s+=row[Hh+k]*cemb[cond*Cc+k];
    s=wave_reduce(s);
    if(lane==0) cvec[r]=s;
  }
}

// Encoder X (fp32 tile GEMM — kl precision headroom is thin)
__global__ __launch_bounds__(256) void k_xgemm(
    const float* __restrict__ emb, const float* __restrict__ Wih,
    const float* __restrict__ b1, const float* __restrict__ b2,
    const int* __restrict__ tok, int tshift, int M,
    float* __restrict__ X)
{
  __shared__ float As[GBK][GBM];
  __shared__ float Bs[GBK][GBN];
  int tid=threadIdx.x;
  int m0=blockIdx.x*GBM, n0=blockIdx.y*GBN;
  int tm=tid>>4, tn=tid&15;
  int arow=m0+(tid>>1);
  int atok=(arow<M)?tok[arow+tshift]:0;
  const float* abase=emb+(size_t)atok*HCd+(tid&1)*8;
  const float* bbase=Wih+(size_t)(n0+(tid>>1))*HCd+(tid&1)*8;
  int srow=tid>>1;
  float acc[8][8]={};
  for(int k0=0;k0<HCd;k0+=GBK){
#pragma unroll
    for(int u=0;u<2;u++){
      int q=2*(tid&1)+u;
      float4 v={0,0,0,0};
      if(arow<M) v=*(const float4*)(abase+k0+u*4);
      As[q*4+0][srow]=v.x; As[q*4+1][srow]=v.y; As[q*4+2][srow]=v.z; As[q*4+3][srow]=v.w;
      float4 w=*(const float4*)(bbase+k0+u*4);
      Bs[q*4+0][srow]=w.x; Bs[q*4+1][srow]=w.y; Bs[q*4+2][srow]=w.z; Bs[q*4+3][srow]=w.w;
    }
    __syncthreads();
#pragma unroll
    for(int kk=0;kk<GBK;kk++){
      float a[8],b[8];
      *(float4*)&a[0]=*(float4*)&As[kk][tm*8]; *(float4*)&a[4]=*(float4*)&As[kk][tm*8+4];
      *(float4*)&b[0]=*(float4*)&Bs[kk][tn*8]; *(float4*)&b[4]=*(float4*)&Bs[kk][tn*8+4];
#pragma unroll
      for(int i=0;i<8;i++)
#pragma unroll
        for(int j=0;j<8;j++) acc[i][j]+=a[i]*b[j];
    }
    __syncthreads();
  }
#pragma unroll
  for(int i=0;i<8;i++){
    int m=m0+tm*8+i; if(m>=M) continue;
#pragma unroll
    for(int j=0;j<8;j++){
      int n=n0+tn*8+j;
      X[(size_t)m*G4+n]=acc[i][j]+b1[n]+b2[n];
    }
  }
}

// Standalone Xdec (fallback when !dual)
__global__ __launch_bounds__(256) void k_xgemm_mfma(
    const float* __restrict__ emb, const float* __restrict__ Wih,
    const float* __restrict__ b1, const float* __restrict__ b2,
    const int* __restrict__ tok, int M, float* __restrict__ X)
{
  __shared__ ushort As[TBM*TBK];
  __shared__ ushort Bs[TBN*TBK];
  int tid=threadIdx.x;
  int m0=blockIdx.x*TBM, n0=blockIdx.y*TBN;
  int wid=tid>>6, lane=tid&63;
  int wm=wid>>1, wn=wid&1;
  int r15=lane&15, g=lane>>4;
  f32x4 acc[4][4]={};
  int srow=tid>>1, shalf=tid&1;
  int arow=m0+srow;
  int atok=(arow<M)?tok[arow]:0;
  const float* aptr=emb+(size_t)atok*HCd + shalf*16;
  const float* bptr=Wih+(size_t)(n0+srow)*HCd + shalf*16;
  bool aok=arow<M;
  float bj[4];
#pragma unroll
  for(int j=0;j<4;j++){ int n=n0+wn*64+j*16+r15; bj[j]=b1[n]+b2[n]; }
  for(int k0=0;k0<HCd;k0+=TBK){
    float4 va0={0,0,0,0},va1={0,0,0,0},va2={0,0,0,0},va3={0,0,0,0};
    if(aok){
      va0=*(const float4*)(aptr+k0);   va1=*(const float4*)(aptr+k0+4);
      va2=*(const float4*)(aptr+k0+8); va3=*(const float4*)(aptr+k0+12);
    }
    float4 vb0=*(const float4*)(bptr+k0),   vb1=*(const float4*)(bptr+k0+4);
    float4 vb2=*(const float4*)(bptr+k0+8), vb3=*(const float4*)(bptr+k0+12);
    uint4v pa0={pk_bf16(va0.x,va0.y),pk_bf16(va0.z,va0.w),pk_bf16(va1.x,va1.y),pk_bf16(va1.z,va1.w)};
    uint4v pa1={pk_bf16(va2.x,va2.y),pk_bf16(va2.z,va2.w),pk_bf16(va3.x,va3.y),pk_bf16(va3.z,va3.w)};
    uint4v pb0={pk_bf16(vb0.x,vb0.y),pk_bf16(vb0.z,vb0.w),pk_bf16(vb1.x,vb1.y),pk_bf16(vb1.z,vb1.w)};
    uint4v pb1={pk_bf16(vb2.x,vb2.y),pk_bf16(vb2.z,vb2.w),pk_bf16(vb3.x,vb3.y),pk_bf16(vb3.z,vb3.w)};
    int sx=(srow>>1)&3;
    int u0=(shalf*2+0)^sx, u1=(shalf*2+1)^sx;
    *(uint4v*)&As[srow*32+u0*8]=pa0; *(uint4v*)&As[srow*32+u1*8]=pa1;
    *(uint4v*)&Bs[srow*32+u0*8]=pb0; *(uint4v*)&Bs[srow*32+u1*8]=pb1;
    __syncthreads();
    bf16x8 af[4], bf[4];
#pragma unroll
    for(int i=0;i<4;i++){
      int ra=wm*64+i*16+r15;
      af[i]=*(const bf16x8*)&As[ra*32+((g^((ra>>1)&3))<<3)];
      int rb=wn*64+i*16+r15;
      bf[i]=*(const bf16x8*)&Bs[rb*32+((g^((rb>>1)&3))<<3)];
    }
#pragma unroll
    for(int i=0;i<4;i++)
#pragma unroll
      for(int j=0;j<4;j++)
        acc[i][j]=__builtin_amdgcn_mfma_f32_16x16x32_bf16(af[i],bf[j],acc[i][j],0,0,0);
    __syncthreads();
  }
#pragma unroll
  for(int i=0;i<4;i++){
    int grow0=m0+wm*64+i*16+g*4;
#pragma unroll
    for(int j=0;j<4;j++){
      int gcol=n0+wn*64+j*16+r15;
#pragma unroll
      for(int r=0;r<4;r++){
        int grow=grow0+r;
        if(grow<M) X[(size_t)grow*G4+gcol]=acc[i][j][r]+bj[j];
      }
    }
  }
}

// ---------------- Fused encoder: scan blocks 0..63 + prologue helpers ----------------
__global__ __launch_bounds__(ET,2) void k_encF(
    const float* __restrict__ Xg, const float* __restrict__ Whh,
    unsigned* estate, float* hT, float* cT,
    const float* __restrict__ dWhh, const float* __restrict__ fhw,
    float* __restrict__ Weff,
    const float* __restrict__ demb, const float* __restrict__ dWih,
    const float* __restrict__ dbih, const float* __restrict__ dbhh,
    const int* __restrict__ tok, float* __restrict__ XB,
    const float* __restrict__ outw, unsigned* __restrict__ wB,
    const float* __restrict__ fhb, const float* __restrict__ dcemb,
    const int* __restrict__ condp, float* __restrict__ cvec,
    int do_xdec, int do_cvtb)
{
  __shared__ SmU sm;
  const int tid=threadIdx.x, lane=tid&63, wv=tid>>6;
  const int bid=blockIdx.x;

  if(bid>=EB){
    int cond=condp[0];
    int n_x=do_xdec?512:0, n_c=do_cvtb?64:0;
    int total=16+256+n_x+n_c;
    for(int u=bid-EB; u<total; u+=FGRID-EB){
      if(u<16) dconst_unit(u,dWhh,fhb,dcemb,cond,cvec,tid);
      else if(u<272) weff_unit(u-16,dWhh,fhw,Weff,sm,tid);
      else if(u<272+n_x) xdec_unit(u-272,demb,dWih,dbih,dbhh,tok,XB,sm,tid);
      else cvtb_unit(u-272-n_x,outw,wB,tid);
      __syncthreads();
    }
    return;
  }

  // -------- encoder scan (r9 fp32 body; channel-spread state) --------
  const int wid=bid*8+wv;
  const int j0=wid*2, j1=j0+1;
  float w[8][16];
#pragma unroll
  for(int q=0;q<4;q++)
#pragma unroll
    for(int jj=0;jj<2;jj++){
      const float* p=Whh+(size_t)(q*HCd+j0+jj)*HCd+lane;
#pragma unroll
      for(int e=0;e<16;e++) w[q*2+jj][e]=p[(size_t)e*64];
    }
  float xg[8];
#pragma unroll
  for(int r=0;r<8;r++) xg[r]=Xg[(r>>1)*HCd+j0+(r&1)];
  float c0=0.f,c1=0.f;
  const int i0=tid*2, i1=i0+1;

  for(int s=1;s<=NSE;s++){
    uint2v v;
    unsigned* src=estate+((s-1)&1)*SLOT;
    if(s==1){ v.x=src[tid*SS]; v.y=src[tid*SS+1]; }
    else{
      const unsigned expp=(unsigned)(((s-1)>>1)&1);
      for(;;){
        v=ld_uc2(src+tid*SS);
        if((((v.x^expp)|(v.y^expp))&1u)==0u) break;
        __builtin_amdgcn_s_sleep(1);
      }
    }
    float* hl=sm.u.hlds[(s-1)&1];
    hl[i0]=__uint_as_float(v.x); hl[i1]=__uint_as_float(v.y);
    __syncthreads();
    if(s==1){ c0=hl[j0]; c1=hl[j1]; }   // h0 == c0
    float hseg[16];
#pragma unroll
    for(int e=0;e<16;e++) hseg[e]=hl[lane+64*e];
    float d[8];
#pragma unroll
    for(int r=0;r<8;r++){ float sacc=0.f;
#pragma unroll
      for(int e=0;e<16;e++) sacc+=w[r][e]*hseg[e];
      d[r]=sacc; }
#pragma unroll
    for(int r=0;r<8;r++) d[r]=redl0(d[r]);
    float gi0=d[0]+xg[0], gi1=d[1]+xg[1];
    float gf0=d[2]+xg[2], gf1=d[3]+xg[3];
    float gg0=d[4]+xg[4], gg1=d[5]+xg[5];
    float go0=d[6]+xg[6], go1=d[7]+xg[7];
    if(s<NSE){
      const float* px=Xg+(size_t)s*G4;
#pragma unroll
      for(int r=0;r<8;r++) xg[r]=px[(r>>1)*HCd+j0+(r&1)];
    }
    c0=sigmoidf_(gf0)*c0+sigmoidf_(gi0)*tanhf(gg0);
    float h0=sigmoidf_(go0)*tanhf(c0);
    c1=sigmoidf_(gf1)*c1+sigmoidf_(gi1)*tanhf(gg1);
    float h1=sigmoidf_(go1)*tanhf(c1);
    unsigned wpar=(unsigned)((s>>1)&1);
    if(lane==0){
      uint2v pk;
      pk.x=(__float_as_uint(h0)&~1u)|wpar;
      pk.y=(__float_as_uint(h1)&~1u)|wpar;
      st_uc2(estate+(s&1)*SLOT+wid*SS,pk);
      if(s==NSE){ hT[j0]=h0; hT[j1]=h1; cT[j0]=c0; cT[j1]=c1; }
    }
  }
}

// ---------------- VAE heads ----------------
__global__ __launch_bounds__(256) void k_head(
    const float* __restrict__ hT, const float* __restrict__ cT,
    const float* __restrict__ mhw, const float* __restrict__ mhb,
    const float* __restrict__ lhw, const float* __restrict__ lhb,
    const float* __restrict__ mcw, const float* __restrict__ mcb,
    const float* __restrict__ lcw, const float* __restrict__ lcb,
    const float* __restrict__ eps_h, const float* __restrict__ eps_c,
    const float* __restrict__ cemb, const int* __restrict__ condp,
    float* zh, float* zc, float* klh, float* klc)
{
  int i=blockIdx.x;
  int tid=threadIdx.x, lane=tid&63, wv=tid>>6;
  __shared__ float sm[4];
  const float* Wm=(wv==0)?mhw:(wv==1)?lhw:(wv==2)?mcw:lcw;
  const float* vec=(wv<2)?hT:cT;
  const float* row=Wm+(size_t)i*HCd;
  float s=0.f;
  for(int k=lane;k<HCd;k+=64) s+=row[k]*vec[k];
  s=wave_reduce(s);
  if(lane==0) sm[wv]=s;
  __syncthreads();
  if(tid==0){
    float mh=sm[0]+mhb[i], lh=sm[1]+lhb[i];
    float mc=sm[2]+mcb[i], lc=sm[3]+lcb[i];
    zh[i]=eps_h[i]*expf(lh*0.5f)+mh;
    zc[i]=eps_c[i]*expf(lc*0.5f)+mc;
    klh[i]=0.5f*(mh*mh+expf(lh)-1.f-lh);
    klc[i]=0.5f*(mc*mc+expf(lc)-1.f-lc);
    if(i<Cc){
      float cd=cemb[condp[0]*Cc+i];
      zh[Hh+i]=cd; zc[Hh+i]=cd;
    }
  }
}

// decoder step 1: writes S1 (fp32, parity 0) into dstate slot1 (strided) + Hmat row 0
__global__ __launch_bounds__(256) void k_dec0(
    const float* __restrict__ Xg, const float* __restrict__ WhhO,
    const float* __restrict__ zh, const float* __restrict__ zc,
    unsigned* dstate1, float* Hmat)
{
  int tid=threadIdx.x, lane=tid&63, wv=tid>>6;
  int j=blockIdx.x*4+wv;
  float hseg[16];
#pragma unroll
  for(int e=0;e<16;e++) hseg[e]=zh[lane+64*e];
  float g[4];
#pragma unroll
  for(int q=0;q<4;q++){
    const float* p=WhhO+(size_t)(q*HCd+j)*HCd+lane;
    float s=0.f;
#pragma unroll
    for(int e=0;e<16;e++) s+=p[(size_t)e*64]*hseg[e];
    s=wave_reduce(s);
    g[q]=s+Xg[q*HCd+j];
  }
  float cc=zc[j];
  float cn=sigmoidf_(g[1])*cc+sigmoidf_(g[0])*tanhf(g[2]);
  float hn=sigmoidf_(g[3])*tanhf(cn);
  if(lane==0){
    unsigned* base=dstate1+(j>>1)*SS+(j&1)*2;
    base[0]=__float_as_uint(hn)&~1u;
    base[1]=__float_as_uint(cn)&~1u;
    Hmat[j]=hn;
  }
}

// LDS union for fused decoder: scan vs helper
struct SmD {
  union {
    struct { float hl[2][HCd]; float cl[2][HCd]; } scan;
    struct { ushort As[128*32]; ushort Bs[256*32];
             float smM[128][4]; float smL[128][4]; int tgt[128]; } h;
  } u;
};

// ---------------- Fused decoder: scan (0..63) + streaming logits helpers ----------------
__global__ __launch_bounds__(ET) void k_decF(
    const float* __restrict__ Xg, const float* __restrict__ Weff,
    const float* __restrict__ cvec,
    const float* __restrict__ fccw, const float* __restrict__ fccb,
    const float* __restrict__ cemb, const int* __restrict__ condp,
    unsigned* dstate, float* __restrict__ Hmat, unsigned* prog,
    const ushort* __restrict__ wB, const float* __restrict__ outb,
    const int* __restrict__ tok,
    float* __restrict__ pm, float* __restrict__ pl, float* __restrict__ tgtlog)
{
  __shared__ SmD smem;
  const int tid=threadIdx.x, lane=tid&63, wv=tid>>6;
  const int bid=blockIdx.x;

  if(bid<EB){
    // ================= scan (channel-spread state) =================
    const int wid=bid*8+wv;
    const int j0=wid*2, j1=j0+1;
    float w[8][16];
#pragma unroll
    for(int q=0;q<4;q++)
#pragma unroll
      for(int jj=0;jj<2;jj++){
        const float* p=Weff+(size_t)(q*HCd+j0+jj)*HCd+lane;
#pragma unroll
        for(int e=0;e<16;e++) w[q*2+jj][e]=p[(size_t)e*64];
      }
    const bool hasf=(j0<Hh);
    float fcc0[16], fcc1[16];
    if(hasf){
      const float* p0=fccw+(size_t)j0*HCd+lane;
      const float* p1=fccw+(size_t)j1*HCd+lane;
#pragma unroll
      for(int e=0;e<16;e++){ fcc0[e]=p0[(size_t)e*64]; fcc1[e]=p1[(size_t)e*64]; }
    } else {
#pragma unroll
      for(int e=0;e<16;e++){ fcc0[e]=0.f; fcc1[e]=0.f; }
    }
    float fb0=hasf?fccb[j0]:0.f, fb1=hasf?fccb[j1]:0.f;
    int cond=condp[0];
    float cd0=hasf?0.f:cemb[cond*Cc+(j0-Hh)];
    float cd1=hasf?0.f:cemb[cond*Cc+(j1-Hh)];
    float cv[8];
#pragma unroll
    for(int r=0;r<8;r++) cv[r]=cvec[(r>>1)*HCd+j0+(r&1)];
    float xg[8];
    { const float* px=Xg+(size_t)1*G4;
#pragma unroll
      for(int r=0;r<8;r++) xg[r]=px[(r>>1)*HCd+j0+(r&1)]; }
    const int i0=tid*2, i1=i0+1;

    for(int s=2;s<=NSD;s++){
      uint4v v;
      unsigned* st=dstate+((s-1)&1)*SLOT;
      if(s==2){ v=*(const uint4v*)(st+tid*SS); }
      else{
        const unsigned expp=(unsigned)(((s-1)>>1)&1);
        for(;;){
          v=ld_uc4(st+tid*SS);
          if((((v.x^expp)|(v.y^expp)|(v.z^expp)|(v.w^expp))&1u)==0u) break;
          __builtin_amdgcn_s_sleep(1);
        }
      }
      float* hl=smem.u.scan.hl[(s-1)&1]; float* cl=smem.u.scan.cl[(s-1)&1];
      hl[i0]=__uint_as_float(v.x); cl[i0]=__uint_as_float(v.y);
      hl[i1]=__uint_as_float(v.z); cl[i1]=__uint_as_float(v.w);
      __syncthreads();
      if(tid==0) st_uc1(prog+bid*64,(unsigned)(s-2));
      float hseg[16], cseg[16];
#pragma unroll
      for(int e=0;e<16;e++){ hseg[e]=hl[lane+64*e]; cseg[e]=cl[lane+64*e]; }
      float d[8]; float s8=0.f, s9=0.f;
#pragma unroll
      for(int r=0;r<8;r++){ float sacc=0.f;
#pragma unroll
        for(int e=0;e<16;e++) sacc+=w[r][e]*hseg[e];
        d[r]=sacc; }
#pragma unroll
      for(int r=0;r<8;r++) d[r]=redl0(d[r]);
      if(hasf){
#pragma unroll
        for(int e=0;e<16;e++){ s8+=fcc0[e]*cseg[e]; s9+=fcc1[e]*cseg[e]; }
        s8=redl0(s8); s9=redl0(s9);
      }
      float gi0=d[0]+xg[0]+cv[0], gi1=d[1]+xg[1]+cv[1];
      float gf0=d[2]+xg[2]+cv[2], gf1=d[3]+xg[3]+cv[3];
      float gg0=d[4]+xg[4]+cv[4], gg1=d[5]+xg[5]+cv[5];
      float go0=d[6]+xg[6]+cv[6], go1=d[7]+xg[7]+cv[7];
      if(s<NSD){
        const float* px=Xg+(size_t)s*G4;
#pragma unroll
        for(int r=0;r<8;r++) xg[r]=px[(r>>1)*HCd+j0+(r&1)];
      }
      float cc0=hasf?(s8+fb0):cd0;
      float cc1=hasf?(s9+fb1):cd1;
      float cn0=sigmoidf_(gf0)*cc0+sigmoidf_(gi0)*tanhf(gg0);
      float hn0=sigmoidf_(go0)*tanhf(cn0);
      float cn1=sigmoidf_(gf1)*cc1+sigmoidf_(gi1)*tanhf(gg1);
      float hn1=sigmoidf_(go1)*tanhf(cn1);
      unsigned wpar=(unsigned)((s>>1)&1);
      if(lane==0){
        uint4v pk;
        pk.x=(__float_as_uint(hn0)&~1u)|wpar;
        pk.y=(__float_as_uint(cn0)&~1u)|wpar;
        pk.z=(__float_as_uint(hn1)&~1u)|wpar;
        pk.w=(__float_as_uint(cn1)&~1u)|wpar;
        st_uc4(dstate+(s&1)*SLOT+wid*SS,pk);
        uint2v hm; hm.x=__float_as_uint(hn0); hm.y=__float_as_uint(hn1);
        st_uc2((unsigned*)(Hmat+(size_t)(s-1)*HCd+j0),hm);
      }
    }
    asm volatile("s_waitcnt vmcnt(0)");
    __syncthreads();
    if(tid==0) st_uc1(prog+bid*64,(unsigned)(NSD-1));
    return;
  }

  // ================= helper: 128x256 logits tiles + per-tile softmax partials =================
  const int hb=bid-EB;
  const int wid=tid>>6;
  const int r15=lane&15, g=lane>>4;
  const int wm=wid>>2, wn=wid&3;
  const int srA=tid>>2, shA=tid&3;
  const int srB=tid>>1, shB=tid&1;

  for(int u=hb; u<8*2*NCT; u+=FGRID-EB){
    int chunk=u/(2*NCT), t=u%(2*NCT);
    int rt=t/NCT, ct=t%NCT;
    int m0=chunk*256+rt*128, n0=ct*256;
    unsigned need=(unsigned)((m0+127<NSD)?(m0+127):(NSD-1));
    if(wv==0){
      for(;;){
        unsigned pv=ld_uc1(prog+lane*64);
        if(wave_min_u(pv)>=need) break;
        __builtin_amdgcn_s_sleep(32);
      }
    }
    if(tid<128){
      int grow=m0+tid;
      smem.u.h.tgt[tid]=(grow<NSD)?tok[grow+1]:-1;
    }
    __syncthreads();

    f32x4 acc[4][4]={};
    const float*  aptr=Hmat+(size_t)(m0+srA)*HCd + shA*8;
    const ushort* bptr=wB  +(size_t)(n0+srB)*HCd + shB*16;
    bool aok=(m0+srA)<NSD;
    for(int k0=0;k0<HCd;k0+=32){
      float4 va0={0,0,0,0}, va1={0,0,0,0};
      if(aok){ va0=*(const float4*)(aptr+k0); va1=*(const float4*)(aptr+k0+4); }
      uint4v pa={pk_bf16(va0.x,va0.y),pk_bf16(va0.z,va0.w),pk_bf16(va1.x,va1.y),pk_bf16(va1.z,va1.w)};
      int sxA=(srA>>1)&3;
      *(uint4v*)&smem.u.h.As[srA*32+(shA^sxA)*8]=pa;
      uint4v qb0=*(const uint4v*)(bptr+k0);
      uint4v qb1=*(const uint4v*)(bptr+k0+8);
      int sxB=(srB>>1)&3;
      int u0=(shB*2+0)^sxB, u1=(shB*2+1)^sxB;
      *(uint4v*)&smem.u.h.Bs[srB*32+u0*8]=qb0;
      *(uint4v*)&smem.u.h.Bs[srB*32+u1*8]=qb1;
      __syncthreads();
      bf16x8 af[4], bf[4];
#pragma unroll
      for(int i=0;i<4;i++){
        int ra=wm*64+i*16+r15;
        af[i]=*(const bf16x8*)&smem.u.h.As[ra*32+((g^((ra>>1)&3))<<3)];
        int rb=wn*64+i*16+r15;
        bf[i]=*(const bf16x8*)&smem.u.h.Bs[rb*32+((g^((rb>>1)&3))<<3)];
      }
#pragma unroll
      for(int i=0;i<4;i++)
#pragma unroll
        for(int j=0;j<4;j++)
          acc[i][j]=__builtin_amdgcn_mfma_f32_16x16x32_bf16(af[i],bf[j],acc[i][j],0,0,0);
      __syncthreads();
    }
    float bj[4];
#pragma unroll
    for(int j=0;j<4;j++) bj[j]=outb[n0+wn*64+j*16+r15];
#pragma unroll
    for(int i=0;i<4;i++)
#pragma unroll
    for(int r=0;r<4;r++){
      int rloc=wm*64+i*16+g*4+r;
      int tg=smem.u.h.tgt[rloc];
      float vv[4];
#pragma unroll
      for(int j=0;j<4;j++){
        vv[j]=acc[i][j][r]+bj[j];
        if(n0+wn*64+j*16+r15==tg) tgtlog[m0+rloc]=vv[j];
      }
      float mloc=fmaxf(fmaxf(vv[0],vv[1]),fmaxf(vv[2],vv[3]));
      float lloc=__expf(vv[0]-mloc)+__expf(vv[1]-mloc)+__expf(vv[2]-mloc)+__expf(vv[3]-mloc);
#pragma unroll
      for(int o=1;o<16;o<<=1){
        float mo=__shfl_xor(mloc,o,64), lo=__shfl_xor(lloc,o,64);
        float mn=fmaxf(mloc,mo);
        lloc=lloc*__expf(mloc-mn)+lo*__expf(mo-mn);
        mloc=mn;
      }
      if(r15==0){ smem.u.h.smM[rloc][wn]=mloc; smem.u.h.smL[rloc][wn]=lloc; }
    }
    __syncthreads();
    if(tid<128){
      int grow=m0+tid;
      if(grow<NSD){
        float M=-3e38f;
#pragma unroll
        for(int q2=0;q2<4;q2++) M=fmaxf(M,smem.u.h.smM[tid][q2]);
        float L=0.f;
#pragma unroll
        for(int q2=0;q2<4;q2++) L+=smem.u.h.smL[tid][q2]*__expf(smem.u.h.smM[tid][q2]-M);
        pm[(size_t)grow*NCT+ct]=M;
        pl[(size_t)grow*NCT+ct]=L;
      }
    }
    __syncthreads();
  }
}

// merge col-tile partials -> ce[row]
__global__ __launch_bounds__(256) void k_cemerge(const float* __restrict__ pm,
    const float* __restrict__ pl, const float* __restrict__ tgtlog,
    float* __restrict__ ce)
{
  int grow=blockIdx.x*256+threadIdx.x;
  if(grow>=NSD) return;
  float M=-3e38f;
  for(int c=0;c<NCT;c++) M=fmaxf(M,pm[(size_t)grow*NCT+c]);
  float L=0.f;
  for(int c=0;c<NCT;c++) L+=pl[(size_t)grow*NCT+c]*__expf(pm[(size_t)grow*NCT+c]-M);
  ce[grow]=M+logf(L)-tgtlog[grow];
}

// ---------------- fallback decoder scan (standalone, strided state) ----------------
__global__ __launch_bounds__(ET,2) void k_dec9(
    const float* __restrict__ Xg, const float* __restrict__ Weff,
    const float* __restrict__ cvec,
    const float* __restrict__ fccw, const float* __restrict__ fccb,
    const float* __restrict__ cemb, const int* __restrict__ condp,
    unsigned* dstate, float* __restrict__ Hmat)
{
  __shared__ float hlds[2][HCd];
  __shared__ float clds[2][HCd];
  const int tid=threadIdx.x, lane=tid&63, wv=tid>>6;
  const int wid=blockIdx.x*8+wv;
  const int j0=wid*2, j1=j0+1;
  float w[8][16];
#pragma unroll
  for(int q=0;q<4;q++)
#pragma unroll
    for(int jj=0;jj<2;jj++){
      const float* p=Weff+(size_t)(q*HCd+j0+jj)*HCd+lane;
#pragma unroll
      for(int e=0;e<16;e++) w[q*2+jj][e]=p[(size_t)e*64];
    }
  const bool hasf=(j0<Hh);
  float fcc0[16], fcc1[16];
  if(hasf){
    const float* p0=fccw+(size_t)j0*HCd+lane;
    const float* p1=fccw+(size_t)j1*HCd+lane;
#pragma unroll
    for(int e=0;e<16;e++){ fcc0[e]=p0[(size_t)e*64]; fcc1[e]=p1[(size_t)e*64]; }
  } else {
#pragma unroll
    for(int e=0;e<16;e++){ fcc0[e]=0.f; fcc1[e]=0.f; }
  }
  float fb0=hasf?fccb[j0]:0.f, fb1=hasf?fccb[j1]:0.f;
  int cond=condp[0];
  float cd0=hasf?0.f:cemb[cond*Cc+(j0-Hh)];
  float cd1=hasf?0.f:cemb[cond*Cc+(j1-Hh)];
  float cv[8];
#pragma unroll
  for(int r=0;r<8;r++) cv[r]=cvec[(r>>1)*HCd+j0+(r&1)];
  float xg[8];
  { const float* px=Xg+(size_t)1*G4;
#pragma unroll
    for(int r=0;r<8;r++) xg[r]=px[(r>>1)*HCd+j0+(r&1)]; }
  const int i0=tid*2, i1=i0+1;

  for(int s=2;s<=NSD;s++){
    uint4v v;
    unsigned* st=dstate+((s-1)&1)*SLOT;
    if(s==2){ v=*(const uint4v*)(st+tid*SS); }
    else{
      const unsigned expp=(unsigned)(((s-1)>>1)&1);
      for(;;){
        v=ld_uc4(st+tid*SS);
        if((((v.x^expp)|(v.y^expp)|(v.z^expp)|(v.w^expp))&1u)==0u) break;
        __builtin_amdgcn_s_sleep(1);
      }
    }
    float* hl=hlds[(s-1)&1]; float* cl=clds[(s-1)&1];
    hl[i0]=__uint_as_float(v.x); cl[i0]=__uint_as_float(v.y);
    hl[i1]=__uint_as_float(v.z); cl[i1]=__uint_as_float(v.w);
    __syncthreads();
    float hseg[16], cseg[16];
#pragma unroll
    for(int e=0;e<16;e++){ hseg[e]=hl[lane+64*e]; cseg[e]=cl[lane+64*e]; }
    float d[8]; float s8=0.f, s9=0.f;
#pragma unroll
    for(int r=0;r<8;r++){ float sacc=0.f;
#pragma unroll
      for(int e=0;e<16;e++) sacc+=w[r][e]*hseg[e];
      d[r]=sacc; }
#pragma unroll
    for(int r=0;r<8;r++) d[r]=redl0(d[r]);
    if(hasf){
#pragma unroll
      for(int e=0;e<16;e++){ s8+=fcc0[e]*cseg[e]; s9+=fcc1[e]*cseg[e]; }
      s8=redl0(s8); s9=redl0(s9);
    }
    float gi0=d[0]+xg[0]+cv[0], gi1=d[1]+xg[1]+cv[1];
    float gf0=d[2]+xg[2]+cv[2], gf1=d[3]+xg[3]+cv[3];
    float gg0=d[4]+xg[4]+cv[4], gg1=d[5]+xg[5]+cv[5];
    float go0=d[6]+xg[6]+cv[6], go1=d[7]+xg[7]+cv[7];
    if(s<NSD){
      const float* px=Xg+(size_t)s*G4;
#pragma unroll
      for(int r=0;r<8;r++) xg[r]=px[(r>>1)*HCd+j0+(r&1)];
    }
    float cc0=hasf?(s8+fb0):cd0;
    float cc1=hasf?(s9+fb1):cd1;
    float cn0=sigmoidf_(gf0)*cc0+sigmoidf_(gi0)*tanhf(gg0);
    float hn0=sigmoidf_(go0)*tanhf(cn0);
    float cn1=sigmoidf_(gf1)*cc1+sigmoidf_(gi1)*tanhf(gg1);
    float hn1=sigmoidf_(go1)*tanhf(cn1);
    unsigned wpar=(unsigned)((s>>1)&1);
    if(lane==0){
      uint4v pk;
      pk.x=(__float_as_uint(hn0)&~1u)|wpar;
      pk.y=(__float_as_uint(cn0)&~1u)|wpar;
      pk.z=(__float_as_uint(hn1)&~1u)|wpar;
      pk.w=(__float_as_uint(cn1)&~1u)|wpar;
      st_uc4(dstate+(s&1)*SLOT+wid*SS,pk);
      Hmat[(size_t)(s-1)*HCd+j0]=hn0; Hmat[(size_t)(s-1)*HCd+j1]=hn1;
    }
  }
}

// fallback logits GEMM (in-kernel B conversion)
__global__ __launch_bounds__(256) void k_gemm_mfma(
    const float* __restrict__ A, const float* __restrict__ B,
    const float* __restrict__ bias, float* __restrict__ Cm, int M)
{
  __shared__ ushort As[TBM*TBK];
  __shared__ ushort Bs[TBN*TBK];
  int tid=threadIdx.x;
  int m0=blockIdx.x*TBM, n0=blockIdx.y*TBN;
  int wid=tid>>6, lane=tid&63;
  int wm=wid>>1, wn=wid&1;
  int r15=lane&15, g=lane>>4;
  f32x4 acc[4][4]={};
  int srow=tid>>1, shalf=tid&1;
  const float* aptr=A+(size_t)(m0+srow)*HCd + shalf*16;
  const float* bptr=B+(size_t)(n0+srow)*HCd + shalf*16;
  bool aok=(m0+srow)<M;
  float bj[4];
#pragma unroll
  for(int j=0;j<4;j++) bj[j]=bias[n0+wn*64+j*16+r15];
  for(int k0=0;k0<HCd;k0+=TBK){
    float4 va0={0,0,0,0},va1={0,0,0,0},va2={0,0,0,0},va3={0,0,0,0};
    if(aok){
      va0=*(const float4*)(aptr+k0);   va1=*(const float4*)(aptr+k0+4);
      va2=*(const float4*)(aptr+k0+8); va3=*(const float4*)(aptr+k0+12);
    }
    float4 vb0=*(const float4*)(bptr+k0),   vb1=*(const float4*)(bptr+k0+4);
    float4 vb2=*(const float4*)(bptr+k0+8), vb3=*(const float4*)(bptr+k0+12);
    uint4v pa0={pk_bf16(va0.x,va0.y),pk_bf16(va0.z,va0.w),pk_bf16(va1.x,va1.y),pk_bf16(va1.z,va1.w)};
    uint4v pa1={pk_bf16(va2.x,va2.y),pk_bf16(va2.z,va2.w),pk_bf16(va3.x,va3.y),pk_bf16(va3.z,va3.w)};
    uint4v pb0={pk_bf16(vb0.x,vb0.y),pk_bf16(vb0.z,vb0.w),pk_bf16(vb1.x,vb1.y),pk_bf16(vb1.z,vb1.w)};
    uint4v pb1={pk_bf16(vb2.x,vb2.y),pk_bf16(vb2.z,vb2.w),pk_bf16(vb3.x,vb3.y),pk_bf16(vb3.z,vb3.w)};
    int sx=(srow>>1)&3;
    int u0=(shalf*2+0)^sx, u1=(shalf*2+1)^sx;
    *(uint4v*)&As[srow*32+u0*8]=pa0; *(uint4v*)&As[srow*32+u1*8]=pa1;
    *(uint4v*)&Bs[srow*32+u0*8]=pb0; *(uint4v*)&Bs[srow*32+u1*8]=pb1;
    __syncthreads();
    bf16x8 af[4], bf[4];
#pragma unroll
    for(int i=0;i<4;i++){
      int ra=wm*64+i*16+r15;
      af[i]=*(const bf16x8*)&As[ra*32+((g^((ra>>1)&3))<<3)];
      int rb=wn*64+i*16+r15;
      bf[i]=*(const bf16x8*)&Bs[rb*32+((g^((rb>>1)&3))<<3)];
    }
#pragma unroll
    for(int i=0;i<4;i++)
#pragma unroll
      for(int j=0;j<4;j++)
        acc[i][j]=__builtin_amdgcn_mfma_f32_16x16x32_bf16(af[i],bf[j],acc[i][j],0,0,0);
    __syncthreads();
  }
#pragma unroll
  for(int i=0;i<4;i++){
    int grow0=m0+wm*64+i*16+g*4;
#pragma unroll
    for(int j=0;j<4;j++){
      int gcol=n0+wn*64+j*16+r15;
#pragma unroll
      for(int r=0;r<4;r++){
        int grow=grow0+r;
        if(grow<M) Cm[(size_t)grow*VSZ+gcol]=acc[i][j][r]+bj[j];
      }
    }
  }
}

// per-row cross-entropy (fallback tail)
__global__ __launch_bounds__(256) void k_ce(const float* __restrict__ logits,
    const int* __restrict__ tok, int base, float* __restrict__ ce)
{
  int r=blockIdx.x;
  const float* row=logits+(size_t)r*VSZ;
  int tid=threadIdx.x, lane=tid&63, wv=tid>>6;
  float m=-1e30f, s=0.f;
  for(int i=tid;i<VSZ;i+=256){
    float v=row[i];
    if(v>m){ s=s*__expf(m-v)+1.f; m=v; }
    else s+=__expf(v-m);
  }
#pragma unroll
  for(int o=32;o;o>>=1){
    float mo=__shfl_xor(m,o,64), so=__shfl_xor(s,o,64);
    float mn=fmaxf(m,mo);
    s=s*__expf(m-mn)+so*__expf(mo-mn);
    m=mn;
  }
  __shared__ float smm[4], sms[4];
  if(lane==0){ smm[wv]=m; sms[wv]=s; }
  __syncthreads();
  if(tid==0){
    float M2=fmaxf(fmaxf(smm[0],smm[1]),fmaxf(smm[2],smm[3]));
    float S2=sms[0]*__expf(smm[0]-M2)+sms[1]*__expf(smm[1]-M2)
            +sms[2]*__expf(smm[2]-M2)+sms[3]*__expf(smm[3]-M2);
    int tgt=tok[base+r+1];
    ce[base+r]=M2+logf(S2)-row[tgt];
  }
}

__global__ __launch_bounds__(256) void k_final(const float* __restrict__ ce,
    const float* __restrict__ klh, const float* __restrict__ klc,
    const float* __restrict__ kldw, float* __restrict__ outp)
{
  int tid=threadIdx.x, lane=tid&63, wv=tid>>6;
  float s0=0,s1=0,s2=0;
  for(int i=tid;i<NSD;i+=256) s0+=ce[i];
  for(int i=tid;i<Hh;i+=256){ s1+=klh[i]; s2+=klc[i]; }
  s0=wave_reduce(s0); s1=wave_reduce(s1); s2=wave_reduce(s2);
  __shared__ float sm[3][4];
  if(lane==0){ sm[0][wv]=s0; sm[1][wv]=s1; sm[2][wv]=s2; }
  __syncthreads();
  if(tid==0){
    float ces=sm[0][0]+sm[0][1]+sm[0][2]+sm[0][3];
    float kh =sm[1][0]+sm[1][1]+sm[1][2]+sm[1][3];
    float kc =sm[2][0]+sm[2][1]+sm[2][2]+sm[2][3];
    float rec=ces/(float)NSD;
    outp[0]=rec+(kh+kc)*kldw[0];
    outp[1]=rec; outp[2]=kh; outp[3]=kc;
  }
}

extern "C" void kernel_launch(void* const* d_in, const int* in_sizes, int n_in,
                              void* d_out, int out_size, void* d_ws, size_t ws_size,
                              hipStream_t stream) {
  const int*   tok   =(const int*)  d_in[0];
  const int*   cond  =(const int*)  d_in[1];
  const float* eps_h =(const float*)d_in[2];
  const float* eps_c =(const float*)d_in[3];
  const float* kldw  =(const float*)d_in[4];
  const float* enc_embed=(const float*)d_in[5];
  const float* enc_cemb =(const float*)d_in[6];
  const float* enc_Wih  =(const float*)d_in[7];
  const float* enc_Whh  =(const float*)d_in[8];
  const float* enc_bih  =(const float*)d_in[9];
  const float* enc_bhh  =(const float*)d_in[10];
  const float* fc_mh_w=(const float*)d_in[11];
  const float* fc_mh_b=(const float*)d_in[12];
  const float* fc_lh_w=(const float*)d_in[13];
  const float* fc_lh_b=(const float*)d_in[14];
  const float* fc_mc_w=(const float*)d_in[15];
  const float* fc_mc_b=(const float*)d_in[16];
  const float* fc_lc_w=(const float*)d_in[17];
  const float* fc_lc_b=(const float*)d_in[18];
  const float* dec_embed=(const float*)d_in[19];
  const float* dec_cemb =(const float*)d_in[20];
  const float* dec_Wih  =(const float*)d_in[21];
  const float* dec_Whh  =(const float*)d_in[22];
  const float* dec_bih  =(const float*)d_in[23];
  const float* dec_bhh  =(const float*)d_in[24];
  const float* fc_h_w=(const float*)d_in[25];
  const float* fc_h_b=(const float*)d_in[26];
  const float* fc_c_w=(const float*)d_in[27];
  const float* fc_c_b=(const float*)d_in[28];
  const float* out_w=(const float*)d_in[29];
  const float* out_b=(const float*)d_in[30];

  float* ws=(float*)d_ws;
  size_t off=0;
  unsigned* prog  =(unsigned*)(ws+off); off+=4096;
  unsigned* estate=(unsigned*)(ws+off); off+=2*SLOT;
  unsigned* dstate=(unsigned*)(ws+off); off+=2*SLOT;
  float* cvec=ws+off; off+=G4;
  float* Weff=ws+off; off+=(size_t)G4*HCd;
  float* hT  =ws+off; off+=HCd;
  float* cT  =ws+off; off+=HCd;
  float* zh  =ws+off; off+=HCd;
  float* zc  =ws+off; off+=HCd;
  float* klh =ws+off; off+=Hh;
  float* klc =ws+off; off+=Hh;
  float* Hmat=ws+off; off+=(size_t)NSD*HCd;
  float* ce  =ws+off; off+=2048;
  float* pm  =ws+off; off+=(size_t)2048*NCT;
  float* pl  =ws+off; off+=(size_t)2048*NCT;
  float* tgtlog=ws+off; off+=2048;
  size_t avail=ws_size/4;
  size_t xa_sz=(size_t)NSE*G4, xb_sz=(size_t)NSD*G4;
  size_t wb_sz=(size_t)VSZ*HCd/2;
  float* XA=ws+off;
  bool dual=(off+xa_sz+xb_sz)<=avail;
  float* XB=dual?(XA+xa_sz):XA;
  bool wbok=dual && (off+xa_sz+xb_sz+wb_sz)<=avail;
  unsigned* wB=(unsigned*)(XB+xb_sz);
  size_t region=(avail>off)?(avail-off):0;
  int chunk=256;
  if(!dual){
    if((size_t)chunk*VSZ>region){ chunk=(int)(region/(size_t)VSZ); if(chunk<1)chunk=1; }
  }
  float* lbuf=XA;

  k_init13<<<1,256,0,stream>>>(prog,estate,dstate,enc_cemb,cond);
  { dim3 g((NSE+GBM-1)/GBM, G4/GBN);
    k_xgemm<<<g,256,0,stream>>>(enc_embed,enc_Wih,enc_bih,enc_bhh,tok,1,NSE,XA); }
  k_encF<<<FGRID,ET,0,stream>>>(XA,enc_Whh,estate,hT,cT,
                                dec_Whh,fc_h_w,Weff,
                                dec_embed,dec_Wih,dec_bih,dec_bhh,tok,XB,
                                out_w,wB,fc_h_b,dec_cemb,cond,cvec,
                                dual?1:0, wbok?1:0);
  k_head<<<Hh,256,0,stream>>>(hT,cT,fc_mh_w,fc_mh_b,fc_lh_w,fc_lh_b,
                              fc_mc_w,fc_mc_b,fc_lc_w,fc_lc_b,
                              eps_h,eps_c,dec_cemb,cond,zh,zc,klh,klc);
  if(!dual){
    dim3 g((NSD+TBM-1)/TBM, G4/TBN);
    k_xgemm_mfma<<<g,256,0,stream>>>(dec_embed,dec_Wih,dec_bih,dec_bhh,tok,NSD,XB);
  }
  k_dec0<<<256,256,0,stream>>>(XB,dec_Whh,zh,zc,dstate+SLOT,Hmat);
  if(dual&&wbok){
    k_decF<<<FGRID,ET,0,stream>>>(XB,Weff,cvec,fc_c_w,fc_c_b,dec_cemb,cond,
                                  dstate,Hmat,prog,(const ushort*)wB,out_b,tok,
                                  pm,pl,tgtlog);
    k_cemerge<<<(NSD+255)/256,256,0,stream>>>(pm,pl,tgtlog,ce);
  } else {
    k_dec9<<<EB,ET,0,stream>>>(XB,Weff,cvec,fc_c_w,fc_c_b,dec_cemb,cond,dstate,Hmat);
    for(int base=0;base<NSD;base+=chunk){
      int rows=NSD-base; if(rows>chunk) rows=chunk;
      dim3 g((rows+TBM-1)/TBM, VSZ/TBN);
      k_gemm_mfma<<<g,256,0,stream>>>(Hmat+(size_t)base*HCd,out_w,out_b,lbuf,rows);
      k_ce<<<rows,256,0,stream>>>(lbuf,tok,base,ce);
    }
  }
  k_final<<<1,256,0,stream>>>(ce,klh,klc,kldw,(float*)d_out);
}